// Round 1
// baseline (2439.901 us; speedup 1.0000x reference)
//
#include <hip/hip_runtime.h>
#include <math.h>

constexpr int NODES = 2048;
constexpr int BG = 8;
constexpr int SG = 256;
constexpr int DIN = 4096;
constexpr int HIDC = 512;
constexpr int NHEAD = 8;
constexpr int HCH = 64;
constexpr int EDGES = 32768;
constexpr int LLAY = 2;
constexpr int ACT_N = 5;
constexpr int H4C = 128;
constexpr int ECAP = 192;

__device__ __forceinline__ float wave_sum(float v) {
#pragma unroll
  for (int o = 32; o; o >>= 1) v += __shfl_xor(v, o);
  return v;
}
__device__ __forceinline__ float wave_max(float v) {
#pragma unroll
  for (int o = 32; o; o >>= 1) v = fmaxf(v, __shfl_xor(v, o));
  return v;
}
// block reduce; sh must have >= blockDim.x/64 floats; callable repeatedly
__device__ __forceinline__ float blk_sum(float v, float* sh) {
  v = wave_sum(v);
  int nw = blockDim.x >> 6;
  __syncthreads();
  if ((threadIdx.x & 63) == 0) sh[threadIdx.x >> 6] = v;
  __syncthreads();
  float s = 0.f;
  for (int k = 0; k < nw; k++) s += sh[k];
  return s;
}
__device__ __forceinline__ float gelu_f(float x) {
  return 0.5f * x * (1.f + erff(x * 0.70710678118654752f));
}

// ---------------- RWSE ----------------
__global__ void scatter_adj(const int* __restrict__ ei, float* __restrict__ T) {
  int e = blockIdx.x * 256 + threadIdx.x;
  if (e < EDGES) {
    int s = ei[e], d = ei[EDGES + e];
    T[(size_t)s * NODES + d] = 1.f;
  }
}

__global__ __launch_bounds__(256) void rownorm(float* __restrict__ T, float* __restrict__ rwse) {
  int i = blockIdx.x, t = threadIdx.x;
  size_t base = (size_t)i * NODES;
  float s = 0.f;
  for (int k = t; k < NODES; k += 256) s += T[base + k];
  __shared__ float sh[8];
  float deg = blk_sum(s, sh);
  float inv = deg > 0.f ? 1.f / deg : 1.f;
  for (int k = t; k < NODES; k += 256) {
    float v = T[base + k] * inv;
    T[base + k] = v;
    if (k == i) rwse[(size_t)i * 8 + 0] = v;  // diag(T^1)
  }
}

__global__ void diag_copy(const float* __restrict__ P, float* __restrict__ rwse, int col) {
  int i = blockIdx.x * 256 + threadIdx.x;
  if (i < NODES) rwse[(size_t)i * 8 + col] = P[(size_t)i * (NODES + 1)];
}

__global__ __launch_bounds__(256) void diag_dot(const float* __restrict__ A,
                                                const float* __restrict__ Bm,
                                                float* __restrict__ rwse, int col) {
  int i = blockIdx.x, t = threadIdx.x;
  float s = 0.f;
  for (int j = t; j < NODES; j += 256)
    s += A[(size_t)i * NODES + j] * Bm[(size_t)j * NODES + i];
  __shared__ float sh[8];
  float d = blk_sum(s, sh);
  if (t == 0) rwse[(size_t)i * 8 + col] = d;
}

// ---------------- generic fp32 GEMM: C = A[MxK] @ B[KxN] (+bias)(+=C)(gelu) ----
__global__ __launch_bounds__(256) void gemm_f32(const float* __restrict__ A,
                                                const float* __restrict__ B,
                                                float* __restrict__ C,
                                                const float* __restrict__ bias,
                                                int M, int K, int Nd, int acc, int act) {
  __shared__ float As[16][68];
  __shared__ float Bs[16][68];
  int tid = threadIdx.x;
  int tx = tid & 15, ty = tid >> 4;
  int bm = blockIdx.y * 64, bn = blockIdx.x * 64;
  float accr[4][4];
#pragma unroll
  for (int i = 0; i < 4; i++)
#pragma unroll
    for (int j = 0; j < 4; j++) accr[i][j] = 0.f;

  for (int kt = 0; kt < K; kt += 16) {
#pragma unroll
    for (int i = 0; i < 4; i++) {
      int idx = tid + i * 256;
      As[idx & 15][idx >> 4] = A[(size_t)(bm + (idx >> 4)) * K + kt + (idx & 15)];
      Bs[idx >> 6][idx & 63] = B[(size_t)(kt + (idx >> 6)) * Nd + bn + (idx & 63)];
    }
    __syncthreads();
#pragma unroll
    for (int k = 0; k < 16; k++) {
      float ar[4], br[4];
      *(float4*)ar = *(const float4*)&As[k][ty * 4];
      *(float4*)br = *(const float4*)&Bs[k][tx * 4];
#pragma unroll
      for (int ii = 0; ii < 4; ii++)
#pragma unroll
        for (int jj = 0; jj < 4; jj++) accr[ii][jj] += ar[ii] * br[jj];
    }
    __syncthreads();
  }
#pragma unroll
  for (int ii = 0; ii < 4; ii++) {
    int m = bm + ty * 4 + ii;
#pragma unroll
    for (int jj = 0; jj < 4; jj++) {
      int n = bn + tx * 4 + jj;
      float v = accr[ii][jj];
      if (bias) v += bias[n];
      if (acc) v += C[(size_t)m * Nd + n];
      if (act) v = gelu_f(v);
      C[(size_t)m * Nd + n] = v;
    }
  }
}

// ---------------- rwse projection: r = gelu(LN(rwse@W + b)) ----------------
__global__ __launch_bounds__(128) void rwse_proj(const float* __restrict__ rwse,
                                                 const float* __restrict__ W,
                                                 const float* __restrict__ bb,
                                                 const float* __restrict__ g,
                                                 const float* __restrict__ bt,
                                                 float* __restrict__ r) {
  int i = blockIdx.x, j = threadIdx.x;
  float s = bb[j];
#pragma unroll
  for (int k = 0; k < 8; k++) s += rwse[(size_t)i * 8 + k] * W[k * H4C + j];
  __shared__ float sh[8];
  float sum = blk_sum(s, sh);
  float mu = sum * (1.f / 128.f);
  float d = s - mu;
  float var = blk_sum(d * d, sh) * (1.f / 128.f);
  float rstd = rsqrtf(var + 1e-5f);
  r[(size_t)i * H4C + j] = gelu_f(d * rstd * g[j] + bt[j]);
}

// ---------------- rowwise LN over 512 (optional residual, optional gelu) ----
__global__ __launch_bounds__(256) void ln512(const float* __restrict__ x,
                                             const float* __restrict__ res,
                                             const float* __restrict__ g,
                                             const float* __restrict__ b,
                                             float* __restrict__ y, int do_gelu) {
  int i = blockIdx.x, t = threadIdx.x;
  size_t base = (size_t)i * 512;
  float v0 = x[base + t], v1 = x[base + 256 + t];
  if (res) { v0 += res[base + t]; v1 += res[base + 256 + t]; }
  __shared__ float sh[8];
  float s = blk_sum(v0 + v1, sh);
  float mu = s * (1.f / 512.f);
  float d0 = v0 - mu, d1 = v1 - mu;
  float var = blk_sum(d0 * d0 + d1 * d1, sh) * (1.f / 512.f);
  float rstd = rsqrtf(var + 1e-5f);
  float o0 = d0 * rstd * g[t] + b[t];
  float o1 = d1 * rstd * g[t + 256] + b[t + 256];
  if (do_gelu) { o0 = gelu_f(o0); o1 = gelu_f(o1); }
  y[base + t] = o0;
  y[base + 256 + t] = o1;
}

// ---------------- GAT: CSR build ----------------
__global__ void fill_edges(const int* __restrict__ ei, int* __restrict__ cnt,
                           int* __restrict__ elist) {
  int e = blockIdx.x * 256 + threadIdx.x;
  if (e < EDGES + NODES) {
    int d = e < EDGES ? ei[EDGES + e] : e - EDGES;
    int p = atomicAdd(&cnt[d], 1);
    if (p < ECAP) elist[(size_t)d * ECAP + p] = e;
  }
}

__global__ void ea_reduce(const float* __restrict__ ea, float* __restrict__ sums) {
  int tid = blockIdx.x * blockDim.x + threadIdx.x;
  int stride = gridDim.x * blockDim.x;
  float s0 = 0.f, s1 = 0.f;
  for (int e = tid; e < EDGES; e += stride) { s0 += ea[2 * e]; s1 += ea[2 * e + 1]; }
  s0 = wave_sum(s0);
  s1 = wave_sum(s1);
  if ((threadIdx.x & 63) == 0) { atomicAdd(&sums[0], s0); atomicAdd(&sums[1], s1); }
}

// one block per dst node; wave = head, lane = channel
__global__ __launch_bounds__(512) void gat_kernel(
    const float* __restrict__ xl, const float* __restrict__ xr,
    const float* __restrict__ eattr, const float* __restrict__ easum,
    const float* __restrict__ We, const float* __restrict__ att,
    const float* __restrict__ bias, const int* __restrict__ cnt,
    const int* __restrict__ elist, const int* __restrict__ ei,
    float* __restrict__ out) {
  int i = blockIdx.x;
  int tid = threadIdx.x;
  int h = tid >> 6, c = tid & 63;
  int m_cnt = cnt[i];
  if (m_cnt > ECAP) m_cnt = ECAP;
  const float inv_e = 1.f / (float)EDGES;
  float we0 = We[tid], we1 = We[512 + tid];
  float attv = att[tid];
  float xrv = xr[(size_t)i * 512 + tid];
  float ea_m0 = easum[0] * inv_e, ea_m1 = easum[1] * inv_e;
  __shared__ float logits[NHEAD][ECAP];
  const int* el = elist + (size_t)i * ECAP;
  for (int e = 0; e < m_cnt; e++) {
    int eid = el[e];
    int s;
    float a0, a1;
    if (eid < EDGES) { s = ei[eid]; a0 = eattr[2 * eid]; a1 = eattr[2 * eid + 1]; }
    else { s = i; a0 = ea_m0; a1 = ea_m1; }
    float mval = xl[(size_t)s * 512 + tid] + xrv + a0 * we0 + a1 * we1;
    mval = mval > 0.f ? mval : 0.2f * mval;  // leaky_relu(0.2)
    float lg = wave_sum(mval * attv);
    if (c == 0) logits[h][e] = lg;
  }
  float mx = -1e30f;
  for (int e = c; e < m_cnt; e += 64) mx = fmaxf(mx, logits[h][e]);
  mx = wave_max(mx);
  float den = 0.f;
  for (int e = c; e < m_cnt; e += 64) den += expf(logits[h][e] - mx);
  den = wave_sum(den) + 1e-16f;
  float acc = 0.f;
  for (int e = 0; e < m_cnt; e++) {
    int eid = el[e];
    int s = eid < EDGES ? ei[eid] : i;
    float alpha = expf(logits[h][e] - mx) / den;
    acc += alpha * xl[(size_t)s * 512 + tid];
  }
  out[(size_t)i * 512 + tid] = acc + bias[tid];
}

// ---------------- block-diagonal MHA: one block per (graph, head) ----------
__global__ __launch_bounds__(256) void mha_attn(const float* __restrict__ qkv,
                                                float* __restrict__ o) {
  __shared__ float Ks[SG][HCH];  // 64 KiB
  int bh = blockIdx.x;
  int b = bh >> 3, h = bh & 7;
  int t = threadIdx.x;
  const size_t rowbase = (size_t)(b * SG) * 1536;
  for (int idx = t; idx < SG * HCH; idx += 256) {
    int j = idx >> 6, c = idx & 63;
    Ks[j][c] = qkv[rowbase + (size_t)j * 1536 + 512 + h * 64 + c];
  }
  __syncthreads();
  float q[64];
  const float* qrow = qkv + rowbase + (size_t)t * 1536 + h * 64;
#pragma unroll
  for (int c = 0; c < 64; c++) q[c] = qrow[c];
  float mx = -1e30f;
  for (int j = 0; j < SG; j++) {
    float s = 0.f;
#pragma unroll
    for (int c = 0; c < 64; c++) s += q[c] * Ks[j][c];
    mx = fmaxf(mx, s * 0.125f);
  }
  const float* vbase = qkv + rowbase + 1024 + h * 64;
  float oa[64];
#pragma unroll
  for (int c = 0; c < 64; c++) oa[c] = 0.f;
  float den = 0.f;
  for (int j = 0; j < SG; j++) {
    float s = 0.f;
#pragma unroll
    for (int c = 0; c < 64; c++) s += q[c] * Ks[j][c];
    float p = expf(s * 0.125f - mx);
    den += p;
    const float* vrow = vbase + (size_t)j * 1536;
#pragma unroll
    for (int c = 0; c < 64; c++) oa[c] += p * vrow[c];
  }
  float invden = 1.f / den;
  float* orow = o + (size_t)(b * SG + t) * 512 + h * 64;
#pragma unroll
  for (int c = 0; c < 64; c++) orow[c] = oa[c] * invden;
}

// ---------------- combine ----------------
__global__ void combine_kernel(const float* __restrict__ loc, const float* __restrict__ gl,
                               const float* __restrict__ ap, int l, float* __restrict__ comb) {
  int idx = blockIdx.x * 256 + threadIdx.x;
  float a = 1.f / (1.f + expf(-ap[l]));
  comb[idx] = a * loc[idx] + (1.f - a) * gl[idx];
}

// ---------------- action head ----------------
__global__ __launch_bounds__(512) void head_kernel(
    const float* __restrict__ hfin, const int* __restrict__ cni,
    const float* __restrict__ W1, const float* __restrict__ b1,
    const float* __restrict__ g, const float* __restrict__ bt,
    const float* __restrict__ W2, const float* __restrict__ b2,
    float* __restrict__ out) {
  __shared__ float emb[512];
  __shared__ float z[512];
  __shared__ float sh[8];
  __shared__ float lg[ACT_N];
  int t = threadIdx.x;
  int idx = cni[0];
  emb[t] = hfin[(size_t)idx * 512 + t];
  __syncthreads();
  float s = b1[t];
  for (int k = 0; k < 512; k++) s += emb[k] * W1[(size_t)k * 512 + t];
  float sum = blk_sum(s, sh);
  float mu = sum * (1.f / 512.f);
  float d = s - mu;
  float var = blk_sum(d * d, sh) * (1.f / 512.f);
  z[t] = gelu_f(d * rsqrtf(var + 1e-5f) * g[t] + bt[t]);
  __syncthreads();
  if (t < ACT_N) {
    float l = b2[t];
    for (int k = 0; k < 512; k++) l += z[k] * W2[k * ACT_N + t];
    lg[t] = l;
  }
  __syncthreads();
  if (t == 0) {
    float m2 = lg[0];
    for (int a = 1; a < ACT_N; a++) m2 = fmaxf(m2, lg[a]);
    float den = 0.f;
    float ex[ACT_N];
    for (int a = 0; a < ACT_N; a++) { ex[a] = expf(lg[a] - m2); den += ex[a]; }
    for (int a = 0; a < ACT_N; a++) {
      out[a] = lg[a];
      out[ACT_N + a] = ex[a] / den;
    }
  }
}

extern "C" void kernel_launch(void* const* d_in, const int* in_sizes, int n_in,
                              void* d_out, int out_size, void* d_ws, size_t ws_size,
                              hipStream_t stream) {
  const float* x        = (const float*)d_in[0];
  const float* eattr    = (const float*)d_in[1];
  const float* rwse_W   = (const float*)d_in[2];
  const float* rwse_b   = (const float*)d_in[3];
  const float* rwse_g   = (const float*)d_in[4];
  const float* rwse_bt  = (const float*)d_in[5];
  const float* np_W     = (const float*)d_in[6];
  const float* np_b     = (const float*)d_in[7];
  const float* np_g     = (const float*)d_in[8];
  const float* np_bt    = (const float*)d_in[9];
  const float* gat_Wl   = (const float*)d_in[10];
  const float* gat_bl   = (const float*)d_in[11];
  const float* gat_Wr   = (const float*)d_in[12];
  const float* gat_br   = (const float*)d_in[13];
  const float* gat_We   = (const float*)d_in[14];
  const float* gat_att  = (const float*)d_in[15];
  const float* gat_bias = (const float*)d_in[16];
  const float* n1_g = (const float*)d_in[17];
  const float* n1_b = (const float*)d_in[18];
  const float* mha_inW  = (const float*)d_in[19];
  const float* mha_inb  = (const float*)d_in[20];
  const float* mha_outW = (const float*)d_in[21];
  const float* mha_outb = (const float*)d_in[22];
  const float* alpha_p  = (const float*)d_in[23];
  const float* n2_g = (const float*)d_in[24];
  const float* n2_b = (const float*)d_in[25];
  const float* ffn_W1 = (const float*)d_in[26];
  const float* ffn_b1 = (const float*)d_in[27];
  const float* ffn_W2 = (const float*)d_in[28];
  const float* ffn_b2 = (const float*)d_in[29];
  const float* n3_g = (const float*)d_in[30];
  const float* n3_b = (const float*)d_in[31];
  const float* ah_W1 = (const float*)d_in[32];
  const float* ah_b1 = (const float*)d_in[33];
  const float* ah_g  = (const float*)d_in[34];
  const float* ah_bt = (const float*)d_in[35];
  const float* ah_W2 = (const float*)d_in[36];
  const float* ah_b2 = (const float*)d_in[37];
  const int* edge_index = (const int*)d_in[38];
  const int* cni        = (const int*)d_in[39];
  (void)in_sizes; (void)n_in; (void)out_size; (void)ws_size;

  char* wsp = (char*)d_ws;
  size_t off = 0;
  auto alloc = [&](size_t bytes) -> char* {
    char* p = wsp + off;
    off += (bytes + 255) & ~(size_t)255;
    return p;
  };
  const size_t NNb = (size_t)NODES * NODES * 4;
  float* T  = (float*)alloc(NNb);
  float* P2 = (float*)alloc(NNb);
  float* P3 = (float*)alloc(NNb);
  float* P4 = T;  // T dead after P3 (diag(T) already captured in rownorm)
  // layer-phase aliases into the big regions (all N^2 data dead by then)
  float* xl   = T;
  float* xr   = T + (size_t)NODES * 512;
  float* gout = T + (size_t)NODES * 1024;
  float* attO = T + (size_t)NODES * 1536;
  float* ffmid = P2;                                  // N*2048 == N*N exactly
  float* qkvb  = P3;                                  // N*1536
  float* ffb   = P3 + (size_t)NODES * 1536;           // N*512 tail of P3 region
  float* rwse = (float*)alloc((size_t)NODES * 8 * 4);
  float* rbuf = (float*)alloc((size_t)NODES * H4C * 4);
  float* h0 = (float*)alloc((size_t)NODES * 512 * 4);
  float* h1 = (float*)alloc((size_t)NODES * 512 * 4);
  float* localb = (float*)alloc((size_t)NODES * 512 * 4);
  float* gbuf   = (float*)alloc((size_t)NODES * 512 * 4);
  float* comb   = (float*)alloc((size_t)NODES * 512 * 4);
  int* cnt   = (int*)alloc((size_t)NODES * 4);
  int* elist = (int*)alloc((size_t)NODES * ECAP * 4);
  float* easum = (float*)alloc(8);

  // ---- RWSE: T, T^2, T^3, T^4 + diag dots ----
  hipMemsetAsync(T, 0, NNb, stream);
  scatter_adj<<<EDGES / 256, 256, 0, stream>>>(edge_index, T);
  rownorm<<<NODES, 256, 0, stream>>>(T, rwse);
  dim3 gNN(NODES / 64, NODES / 64);
  gemm_f32<<<gNN, 256, 0, stream>>>(T, T, P2, nullptr, NODES, NODES, NODES, 0, 0);
  gemm_f32<<<gNN, 256, 0, stream>>>(T, P2, P3, nullptr, NODES, NODES, NODES, 0, 0);
  diag_copy<<<NODES / 256, 256, 0, stream>>>(P2, rwse, 1);
  diag_copy<<<NODES / 256, 256, 0, stream>>>(P3, rwse, 2);
  gemm_f32<<<gNN, 256, 0, stream>>>(P2, P2, P4, nullptr, NODES, NODES, NODES, 0, 0);
  diag_copy<<<NODES / 256, 256, 0, stream>>>(P4, rwse, 3);
  diag_dot<<<NODES, 256, 0, stream>>>(P2, P3, rwse, 4);
  diag_dot<<<NODES, 256, 0, stream>>>(P3, P3, rwse, 5);
  diag_dot<<<NODES, 256, 0, stream>>>(P3, P4, rwse, 6);
  diag_dot<<<NODES, 256, 0, stream>>>(P4, P4, rwse, 7);
  rwse_proj<<<NODES, 128, 0, stream>>>(rwse, rwse_W, rwse_b, rwse_g, rwse_bt, rbuf);

  // ---- node projection: h = gelu(LN(concat(x, r) @ np_W + np_b)) ----
  dim3 gNP(512 / 64, NODES / 64);
  gemm_f32<<<gNP, 256, 0, stream>>>(x, np_W, h0, np_b, NODES, DIN, 512, 0, 0);
  gemm_f32<<<gNP, 256, 0, stream>>>(rbuf, np_W + (size_t)DIN * 512, h0, nullptr,
                                    NODES, H4C, 512, 1, 0);
  ln512<<<NODES, 256, 0, stream>>>(h0, nullptr, np_g, np_bt, h1, 1);

  // ---- GAT CSR + edge-attr mean ----
  hipMemsetAsync(cnt, 0, NODES * 4, stream);
  fill_edges<<<(EDGES + NODES) / 256, 256, 0, stream>>>(edge_index, cnt, elist);
  hipMemsetAsync(easum, 0, 8, stream);
  ea_reduce<<<64, 256, 0, stream>>>(eattr, easum);

  float* hin = h1;
  float* hout = h0;
  for (int l = 0; l < LLAY; l++) {
    gemm_f32<<<gNP, 256, 0, stream>>>(hin, gat_Wl + (size_t)l * 512 * 512, xl,
                                      gat_bl + l * 512, NODES, 512, 512, 0, 0);
    gemm_f32<<<gNP, 256, 0, stream>>>(hin, gat_Wr + (size_t)l * 512 * 512, xr,
                                      gat_br + l * 512, NODES, 512, 512, 0, 0);
    gat_kernel<<<NODES, 512, 0, stream>>>(xl, xr, eattr, easum, gat_We + l * 1024,
                                          gat_att + l * 512, gat_bias + l * 512,
                                          cnt, elist, edge_index, gout);
    ln512<<<NODES, 256, 0, stream>>>(gout, nullptr, n1_g + l * 512, n1_b + l * 512,
                                     localb, 0);
    dim3 gQKV(1536 / 64, NODES / 64);
    gemm_f32<<<gQKV, 256, 0, stream>>>(hin, mha_inW + (size_t)l * 512 * 1536, qkvb,
                                       mha_inb + l * 1536, NODES, 512, 1536, 0, 0);
    mha_attn<<<BG * NHEAD, 256, 0, stream>>>(qkvb, attO);
    gemm_f32<<<gNP, 256, 0, stream>>>(attO, mha_outW + (size_t)l * 512 * 512, gbuf,
                                      mha_outb + l * 512, NODES, 512, 512, 0, 0);
    ln512<<<NODES, 256, 0, stream>>>(gbuf, nullptr, n2_g + l * 512, n2_b + l * 512,
                                     gbuf, 0);
    combine_kernel<<<NODES * 512 / 256, 256, 0, stream>>>(localb, gbuf, alpha_p, l, comb);
    dim3 gF1(2048 / 64, NODES / 64);
    gemm_f32<<<gF1, 256, 0, stream>>>(comb, ffn_W1 + (size_t)l * 512 * 2048, ffmid,
                                      ffn_b1 + l * 2048, NODES, 512, 2048, 0, 1);
    gemm_f32<<<gNP, 256, 0, stream>>>(ffmid, ffn_W2 + (size_t)l * 2048 * 512, ffb,
                                      ffn_b2 + l * 512, NODES, 2048, 512, 0, 0);
    ln512<<<NODES, 256, 0, stream>>>(ffb, comb, n3_g + l * 512, n3_b + l * 512, hout, 0);
    float* tmp = hin; hin = hout; hout = tmp;
  }

  head_kernel<<<1, 512, 0, stream>>>(hin, cni, ah_W1, ah_b1, ah_g, ah_bt, ah_W2,
                                     ah_b2, (float*)d_out);
}

// Round 2
// 1499.169 us; speedup vs baseline: 1.6275x; 1.6275x over previous
//
#include <hip/hip_runtime.h>
#include <math.h>

constexpr int NODES = 2048;
constexpr int BG = 8;
constexpr int SG = 256;
constexpr int DIN = 4096;
constexpr int NHEAD = 8;
constexpr int EDGES = 32768;
constexpr int LLAY = 2;
constexpr int ACT_N = 5;
constexpr int H4C = 128;
constexpr int ECAP = 192;   // per-dst edge list capacity (GAT)
constexpr int SCAP = 96;    // per-src dedup'd neighbor capacity (RWSE)

typedef unsigned short u16;
typedef unsigned int u32;
typedef short short8 __attribute__((ext_vector_type(8)));
typedef float f32x4 __attribute__((ext_vector_type(4)));

__device__ __forceinline__ float wave_sum(float v) {
#pragma unroll
  for (int o = 32; o; o >>= 1) v += __shfl_xor(v, o);
  return v;
}
__device__ __forceinline__ float wave_max(float v) {
#pragma unroll
  for (int o = 32; o; o >>= 1) v = fmaxf(v, __shfl_xor(v, o));
  return v;
}
__device__ __forceinline__ float blk_sum(float v, float* sh) {
  v = wave_sum(v);
  int nw = blockDim.x >> 6;
  __syncthreads();
  if ((threadIdx.x & 63) == 0) sh[threadIdx.x >> 6] = v;
  __syncthreads();
  float s = 0.f;
  for (int k = 0; k < nw; k++) s += sh[k];
  return s;
}
__device__ __forceinline__ float gelu_f(float x) {
  return 0.5f * x * (1.f + erff(x * 0.70710678118654752f));
}
__device__ __forceinline__ u16 f2bf(float x) {  // round-to-nearest-even bf16
  u32 u = __float_as_uint(x);
  return (u16)((u + 0x7FFFu + ((u >> 16) & 1u)) >> 16);
}
__device__ __forceinline__ float bf2f(u16 h) { return __uint_as_float(((u32)h) << 16); }

// ================= RWSE (sparse path) =================
// dedup bitmap + src-CSR build
__global__ void build_csr(const int* __restrict__ ei, u32* __restrict__ bits,
                          int* __restrict__ scnt, int* __restrict__ slist) {
  int e = blockIdx.x * 256 + threadIdx.x;
  if (e < EDGES) {
    int s = ei[e], d = ei[EDGES + e];
    u32 m = 1u << (d & 31);
    u32 old = atomicOr(&bits[s * 64 + (d >> 5)], m);
    if (!(old & m)) {
      int p = atomicAdd(&scnt[s], 1);
      if (p < SCAP) slist[s * SCAP + p] = d;
    }
  }
}

__global__ void diag_T(const u32* __restrict__ bits, const int* __restrict__ scnt,
                       float* __restrict__ rwse) {
  int i = blockIdx.x * 256 + threadIdx.x;
  if (i < NODES) {
    int deg = min(scnt[i], SCAP);
    int self = (bits[i * 64 + (i >> 5)] >> (i & 31)) & 1;
    rwse[(size_t)i * 8 + 0] = (self && deg > 0) ? 1.f / (float)deg : 0.f;
  }
}

// P2 = T@T via CSR^2, accumulate row in LDS
__global__ __launch_bounds__(256) void spmm_sq(const int* __restrict__ scnt,
                                               const int* __restrict__ slist,
                                               float* __restrict__ P2) {
  int i = blockIdx.x, t = threadIdx.x;
  __shared__ float row[NODES];
  for (int c = t; c < NODES; c += 256) row[c] = 0.f;
  __syncthreads();
  int di = min(scnt[i], SCAP);
  float wi = di > 0 ? 1.f / (float)di : 0.f;
  for (int jj = 0; jj < di; jj++) {
    int j = slist[i * SCAP + jj];
    int dj = min(scnt[j], SCAP);
    if (dj == 0) continue;
    float w = wi / (float)dj;
    for (int kk = t; kk < dj; kk += 256) atomicAdd(&row[slist[j * SCAP + kk]], w);
  }
  __syncthreads();
  for (int c = t; c < NODES; c += 256) P2[(size_t)i * NODES + c] = row[c];
}

// Q = T @ P (row gather over <=SCAP neighbors)
__global__ __launch_bounds__(256) void spmm_gather(const int* __restrict__ scnt,
                                                   const int* __restrict__ slist,
                                                   const float* __restrict__ P,
                                                   float* __restrict__ Q) {
  int i = blockIdx.x, t = threadIdx.x;
  __shared__ int nb[SCAP];
  int di = min(scnt[i], SCAP);
  for (int c = t; c < di; c += 256) nb[c] = slist[i * SCAP + c];
  __syncthreads();
  float wi = di > 0 ? 1.f / (float)di : 0.f;
  for (int c = t; c < NODES; c += 256) {
    float s = 0.f;
    for (int jj = 0; jj < di; jj++) s += P[(size_t)nb[jj] * NODES + c];
    Q[(size_t)i * NODES + c] = s * wi;
  }
}

__global__ void diag_copy(const float* __restrict__ P, float* __restrict__ rwse, int col) {
  int i = blockIdx.x * 256 + threadIdx.x;
  if (i < NODES) rwse[(size_t)i * 8 + col] = P[(size_t)i * (NODES + 1)];
}

__global__ __launch_bounds__(256) void diag_dot(const float* __restrict__ A,
                                                const float* __restrict__ Bm,
                                                float* __restrict__ rwse, int col) {
  int i = blockIdx.x, t = threadIdx.x;
  float s = 0.f;
  for (int j = t; j < NODES; j += 256)
    s += A[(size_t)i * NODES + j] * Bm[(size_t)j * NODES + i];
  __shared__ float sh[8];
  float d = blk_sum(s, sh);
  if (t == 0) rwse[(size_t)i * 8 + col] = d;
}

// ================= split-bf16 conversion =================
// fp32 [M][Ksrc] -> Ah/Al [M][dstStride] at colOff
__global__ void conv_A(const float* __restrict__ src, u16* __restrict__ Ah,
                       u16* __restrict__ Al, int total, int Ksrc, int dstStride,
                       int colOff) {
  int idx = blockIdx.x * 256 + threadIdx.x;
  if (idx >= total) return;
  int m = idx / Ksrc, k = idx - m * Ksrc;
  float v = src[idx];
  u16 h = f2bf(v);
  size_t o = (size_t)m * dstStride + colOff + k;
  Ah[o] = h;
  Al[o] = f2bf(v - bf2f(h));
}

// fp32 W [K][N] -> packed k-major tiles: dst[(k>>5)*N*32 + n*32 + (k&31)]
__global__ void pack_B(const float* __restrict__ W, u16* __restrict__ Bh,
                       u16* __restrict__ Bl, int K, int N) {
  int idx = blockIdx.x * 256 + threadIdx.x;
  if (idx >= K * N) return;
  int k = idx / N, n = idx - k * N;
  float v = W[idx];
  u16 h = f2bf(v);
  size_t o = (size_t)(k >> 5) * N * 32 + (size_t)n * 32 + (k & 31);
  Bh[o] = h;
  Bl[o] = f2bf(v - bf2f(h));
}

// ================= split-bf16 MFMA GEMM =================
// C[M][N] = (Ah+Al)[M][K] @ (Bh+Bl)[K][N] (3-product Markidis), fp32 accum.
// 64x64 tile, 4 waves (2x2), each wave 32x32 = 2x2 frags of 16x16x32 MFMA.
__global__ __launch_bounds__(256) void gemm_split(
    const u16* __restrict__ Ahg, const u16* __restrict__ Alg,
    const u16* __restrict__ Bhg, const u16* __restrict__ Blg,
    float* __restrict__ C, const float* __restrict__ bias,
    int M, int K, int N, int acc, int act) {
  __shared__ __align__(16) u16 Ash[2][64][40];  // [hi/lo][m][k], pad->2-way banks
  __shared__ __align__(16) u16 Bsh[2][64][40];  // [hi/lo][n][k]
  int tid = threadIdx.x;
  int lane = tid & 63, w = tid >> 6;
  int wm = (w >> 1) * 32, wn = (w & 1) * 32;
  int bm = blockIdx.y * 64, bn = blockIdx.x * 64;
  int lr = lane & 15, kk = (lane >> 4) * 8;
  int vrow = tid >> 2, vcol = (tid & 3) * 8;  // staging: 1 ushort8 per plane/thread
  f32x4 accf[2][2] = {};
  const size_t aoff = (size_t)(bm + vrow) * K + vcol;
  const size_t boff = (size_t)(bn + vrow) * 32 + vcol;

  for (int kt = 0; kt < K; kt += 32) {
    short8 va = *(const short8*)(Ahg + aoff + kt);
    short8 vb = *(const short8*)(Alg + aoff + kt);
    size_t bo = (size_t)(kt >> 5) * N * 32 + boff;
    short8 vc = *(const short8*)(Bhg + bo);
    short8 vd = *(const short8*)(Blg + bo);
    __syncthreads();
    *(short8*)&Ash[0][vrow][vcol] = va;
    *(short8*)&Ash[1][vrow][vcol] = vb;
    *(short8*)&Bsh[0][vrow][vcol] = vc;
    *(short8*)&Bsh[1][vrow][vcol] = vd;
    __syncthreads();
    short8 ah[2], al[2], bh[2], bl[2];
#pragma unroll
    for (int i = 0; i < 2; i++) {
      ah[i] = *(const short8*)&Ash[0][wm + i * 16 + lr][kk];
      al[i] = *(const short8*)&Ash[1][wm + i * 16 + lr][kk];
      bh[i] = *(const short8*)&Bsh[0][wn + i * 16 + lr][kk];
      bl[i] = *(const short8*)&Bsh[1][wn + i * 16 + lr][kk];
    }
#pragma unroll
    for (int i = 0; i < 2; i++)
#pragma unroll
      for (int j = 0; j < 2; j++) {
        accf[i][j] = __builtin_amdgcn_mfma_f32_16x16x32_bf16(ah[i], bh[j], accf[i][j], 0, 0, 0);
        accf[i][j] = __builtin_amdgcn_mfma_f32_16x16x32_bf16(ah[i], bl[j], accf[i][j], 0, 0, 0);
        accf[i][j] = __builtin_amdgcn_mfma_f32_16x16x32_bf16(al[i], bh[j], accf[i][j], 0, 0, 0);
      }
  }
  int row0 = (lane >> 4) * 4;
#pragma unroll
  for (int i = 0; i < 2; i++)
#pragma unroll
    for (int j = 0; j < 2; j++) {
      int n = bn + wn + j * 16 + lr;
      float bv = bias ? bias[n] : 0.f;
#pragma unroll
      for (int r = 0; r < 4; r++) {
        int m = bm + wm + i * 16 + row0 + r;
        float v = accf[i][j][r] + bv;
        if (acc) v += C[(size_t)m * N + n];
        if (act) v = gelu_f(v);
        C[(size_t)m * N + n] = v;
      }
    }
}

// ================= small fused kernels (unchanged from r1) =================
__global__ __launch_bounds__(128) void rwse_proj(const float* __restrict__ rwse,
                                                 const float* __restrict__ W,
                                                 const float* __restrict__ bb,
                                                 const float* __restrict__ g,
                                                 const float* __restrict__ bt,
                                                 float* __restrict__ r) {
  int i = blockIdx.x, j = threadIdx.x;
  float s = bb[j];
#pragma unroll
  for (int k = 0; k < 8; k++) s += rwse[(size_t)i * 8 + k] * W[k * H4C + j];
  __shared__ float sh[8];
  float sum = blk_sum(s, sh);
  float mu = sum * (1.f / 128.f);
  float d = s - mu;
  float var = blk_sum(d * d, sh) * (1.f / 128.f);
  r[(size_t)i * H4C + j] = gelu_f(d * rsqrtf(var + 1e-5f) * g[j] + bt[j]);
}

__global__ __launch_bounds__(256) void ln512(const float* __restrict__ x,
                                             const float* __restrict__ res,
                                             const float* __restrict__ g,
                                             const float* __restrict__ b,
                                             float* __restrict__ y, int do_gelu) {
  int i = blockIdx.x, t = threadIdx.x;
  size_t base = (size_t)i * 512;
  float v0 = x[base + t], v1 = x[base + 256 + t];
  if (res) { v0 += res[base + t]; v1 += res[base + 256 + t]; }
  __shared__ float sh[8];
  float s = blk_sum(v0 + v1, sh);
  float mu = s * (1.f / 512.f);
  float d0 = v0 - mu, d1 = v1 - mu;
  float var = blk_sum(d0 * d0 + d1 * d1, sh) * (1.f / 512.f);
  float rstd = rsqrtf(var + 1e-5f);
  float o0 = d0 * rstd * g[t] + b[t];
  float o1 = d1 * rstd * g[t + 256] + b[t + 256];
  if (do_gelu) { o0 = gelu_f(o0); o1 = gelu_f(o1); }
  y[base + t] = o0;
  y[base + 256 + t] = o1;
}

__global__ void fill_edges(const int* __restrict__ ei, int* __restrict__ cnt,
                           int* __restrict__ elist) {
  int e = blockIdx.x * 256 + threadIdx.x;
  if (e < EDGES + NODES) {
    int d = e < EDGES ? ei[EDGES + e] : e - EDGES;
    int p = atomicAdd(&cnt[d], 1);
    if (p < ECAP) elist[(size_t)d * ECAP + p] = e;
  }
}

__global__ void ea_reduce(const float* __restrict__ ea, float* __restrict__ sums) {
  int tid = blockIdx.x * blockDim.x + threadIdx.x;
  int stride = gridDim.x * blockDim.x;
  float s0 = 0.f, s1 = 0.f;
  for (int e = tid; e < EDGES; e += stride) { s0 += ea[2 * e]; s1 += ea[2 * e + 1]; }
  s0 = wave_sum(s0);
  s1 = wave_sum(s1);
  if ((threadIdx.x & 63) == 0) { atomicAdd(&sums[0], s0); atomicAdd(&sums[1], s1); }
}

__global__ __launch_bounds__(512) void gat_kernel(
    const float* __restrict__ xl, const float* __restrict__ xr,
    const float* __restrict__ eattr, const float* __restrict__ easum,
    const float* __restrict__ We, const float* __restrict__ att,
    const float* __restrict__ bias, const int* __restrict__ cnt,
    const int* __restrict__ elist, const int* __restrict__ ei,
    float* __restrict__ out) {
  int i = blockIdx.x;
  int tid = threadIdx.x;
  int h = tid >> 6, c = tid & 63;
  int m_cnt = cnt[i];
  if (m_cnt > ECAP) m_cnt = ECAP;
  const float inv_e = 1.f / (float)EDGES;
  float we0 = We[tid], we1 = We[512 + tid];
  float attv = att[tid];
  float xrv = xr[(size_t)i * 512 + tid];
  float ea_m0 = easum[0] * inv_e, ea_m1 = easum[1] * inv_e;
  __shared__ float logits[NHEAD][ECAP];
  const int* el = elist + (size_t)i * ECAP;
  for (int e = 0; e < m_cnt; e++) {
    int eid = el[e];
    int s;
    float a0, a1;
    if (eid < EDGES) { s = ei[eid]; a0 = eattr[2 * eid]; a1 = eattr[2 * eid + 1]; }
    else { s = i; a0 = ea_m0; a1 = ea_m1; }
    float mval = xl[(size_t)s * 512 + tid] + xrv + a0 * we0 + a1 * we1;
    mval = mval > 0.f ? mval : 0.2f * mval;
    float lg = wave_sum(mval * attv);
    if (c == 0) logits[h][e] = lg;
  }
  float mx = -1e30f;
  for (int e = c; e < m_cnt; e += 64) mx = fmaxf(mx, logits[h][e]);
  mx = wave_max(mx);
  float den = 0.f;
  for (int e = c; e < m_cnt; e += 64) den += expf(logits[h][e] - mx);
  den = wave_sum(den) + 1e-16f;
  float acc = 0.f;
  for (int e = 0; e < m_cnt; e++) {
    int eid = el[e];
    int s = eid < EDGES ? ei[eid] : i;
    float alpha = expf(logits[h][e] - mx) / den;
    acc += alpha * xl[(size_t)s * 512 + tid];
  }
  out[(size_t)i * 512 + tid] = acc + bias[tid];
}

__global__ __launch_bounds__(256) void mha_attn(const float* __restrict__ qkv,
                                                float* __restrict__ o) {
  __shared__ float Ks[SG][64];
  int bh = blockIdx.x;
  int b = bh >> 3, h = bh & 7;
  int t = threadIdx.x;
  const size_t rowbase = (size_t)(b * SG) * 1536;
  for (int idx = t; idx < SG * 64; idx += 256) {
    int j = idx >> 6, c = idx & 63;
    Ks[j][c] = qkv[rowbase + (size_t)j * 1536 + 512 + h * 64 + c];
  }
  __syncthreads();
  float q[64];
  const float* qrow = qkv + rowbase + (size_t)t * 1536 + h * 64;
#pragma unroll
  for (int c = 0; c < 64; c++) q[c] = qrow[c];
  float mx = -1e30f;
  for (int j = 0; j < SG; j++) {
    float s = 0.f;
#pragma unroll
    for (int c = 0; c < 64; c++) s += q[c] * Ks[j][c];
    mx = fmaxf(mx, s * 0.125f);
  }
  const float* vbase = qkv + rowbase + 1024 + h * 64;
  float oa[64];
#pragma unroll
  for (int c = 0; c < 64; c++) oa[c] = 0.f;
  float den = 0.f;
  for (int j = 0; j < SG; j++) {
    float s = 0.f;
#pragma unroll
    for (int c = 0; c < 64; c++) s += q[c] * Ks[j][c];
    float p = expf(s * 0.125f - mx);
    den += p;
    const float* vrow = vbase + (size_t)j * 1536;
#pragma unroll
    for (int c = 0; c < 64; c++) oa[c] += p * vrow[c];
  }
  float invden = 1.f / den;
  float* orow = o + (size_t)(b * SG + t) * 512 + h * 64;
#pragma unroll
  for (int c = 0; c < 64; c++) orow[c] = oa[c] * invden;
}

__global__ void combine_kernel(const float* __restrict__ loc, const float* __restrict__ gl,
                               const float* __restrict__ ap, int l, float* __restrict__ comb) {
  int idx = blockIdx.x * 256 + threadIdx.x;
  float a = 1.f / (1.f + expf(-ap[l]));
  comb[idx] = a * loc[idx] + (1.f - a) * gl[idx];
}

__global__ __launch_bounds__(512) void head_kernel(
    const float* __restrict__ hfin, const int* __restrict__ cni,
    const float* __restrict__ W1, const float* __restrict__ b1,
    const float* __restrict__ g, const float* __restrict__ bt,
    const float* __restrict__ W2, const float* __restrict__ b2,
    float* __restrict__ out) {
  __shared__ float emb[512];
  __shared__ float z[512];
  __shared__ float sh[8];
  __shared__ float lg[ACT_N];
  int t = threadIdx.x;
  int idx = cni[0];
  emb[t] = hfin[(size_t)idx * 512 + t];
  __syncthreads();
  float s = b1[t];
  for (int k = 0; k < 512; k++) s += emb[k] * W1[(size_t)k * 512 + t];
  float sum = blk_sum(s, sh);
  float mu = sum * (1.f / 512.f);
  float d = s - mu;
  float var = blk_sum(d * d, sh) * (1.f / 512.f);
  z[t] = gelu_f(d * rsqrtf(var + 1e-5f) * g[t] + bt[t]);
  __syncthreads();
  if (t < ACT_N) {
    float l = b2[t];
    for (int k = 0; k < 512; k++) l += z[k] * W2[k * ACT_N + t];
    lg[t] = l;
  }
  __syncthreads();
  if (t == 0) {
    float m2 = lg[0];
    for (int a = 1; a < ACT_N; a++) m2 = fmaxf(m2, lg[a]);
    float den = 0.f;
    float ex[ACT_N];
    for (int a = 0; a < ACT_N; a++) { ex[a] = expf(lg[a] - m2); den += ex[a]; }
    for (int a = 0; a < ACT_N; a++) {
      out[a] = lg[a];
      out[ACT_N + a] = ex[a] / den;
    }
  }
}

extern "C" void kernel_launch(void* const* d_in, const int* in_sizes, int n_in,
                              void* d_out, int out_size, void* d_ws, size_t ws_size,
                              hipStream_t stream) {
  const float* x        = (const float*)d_in[0];
  const float* eattr    = (const float*)d_in[1];
  const float* rwse_W   = (const float*)d_in[2];
  const float* rwse_b   = (const float*)d_in[3];
  const float* rwse_g   = (const float*)d_in[4];
  const float* rwse_bt  = (const float*)d_in[5];
  const float* np_W     = (const float*)d_in[6];
  const float* np_b     = (const float*)d_in[7];
  const float* np_g     = (const float*)d_in[8];
  const float* np_bt    = (const float*)d_in[9];
  const float* gat_Wl   = (const float*)d_in[10];
  const float* gat_bl   = (const float*)d_in[11];
  const float* gat_Wr   = (const float*)d_in[12];
  const float* gat_br   = (const float*)d_in[13];
  const float* gat_We   = (const float*)d_in[14];
  const float* gat_att  = (const float*)d_in[15];
  const float* gat_bias = (const float*)d_in[16];
  const float* n1_g = (const float*)d_in[17];
  const float* n1_b = (const float*)d_in[18];
  const float* mha_inW  = (const float*)d_in[19];
  const float* mha_inb  = (const float*)d_in[20];
  const float* mha_outW = (const float*)d_in[21];
  const float* mha_outb = (const float*)d_in[22];
  const float* alpha_p  = (const float*)d_in[23];
  const float* n2_g = (const float*)d_in[24];
  const float* n2_b = (const float*)d_in[25];
  const float* ffn_W1 = (const float*)d_in[26];
  const float* ffn_b1 = (const float*)d_in[27];
  const float* ffn_W2 = (const float*)d_in[28];
  const float* ffn_b2 = (const float*)d_in[29];
  const float* n3_g = (const float*)d_in[30];
  const float* n3_b = (const float*)d_in[31];
  const float* ah_W1 = (const float*)d_in[32];
  const float* ah_b1 = (const float*)d_in[33];
  const float* ah_g  = (const float*)d_in[34];
  const float* ah_bt = (const float*)d_in[35];
  const float* ah_W2 = (const float*)d_in[36];
  const float* ah_b2 = (const float*)d_in[37];
  const int* edge_index = (const int*)d_in[38];
  const int* cni        = (const int*)d_in[39];
  (void)in_sizes; (void)n_in; (void)out_size; (void)ws_size;

  char* wsp = (char*)d_ws;
  size_t off = 0;
  auto alloc = [&](size_t bytes) -> char* {
    char* p = wsp + off;
    off += (bytes + 255) & ~(size_t)255;
    return p;
  };
  const size_t NNb = (size_t)NODES * NODES * 4;
  // arena: [P2 | P3 | P4] during RWSE; reused afterwards:
  //   Ah [0, 17.3MB) | Al [17.3, 34.6MB) ... and for the layer phase
  //   (K<=2048: Ah uses [0,8.4), Al uses [17.3,25.7)):
  //   ffmid at +25,690,112 (16.8MB), qkvb at +34,603,008 (12.6MB) --
  //   qkvb/ffmid overlap but lifetimes are disjoint within a layer.
  char* arena = alloc(3 * NNb);
  float* P2 = (float*)arena;
  float* P3 = (float*)(arena + NNb);
  float* P4 = (float*)(arena + 2 * NNb);
  u16* Ah = (u16*)arena;
  u16* Al = (u16*)(arena + (size_t)NODES * 4224 * 2);
  float* ffmid = (float*)(arena + (size_t)NODES * 4224 * 2 + (size_t)NODES * 2048 * 2);
  float* qkvb  = (float*)(arena + (size_t)NODES * 4224 * 4);
  u16* Bh = (u16*)alloc((size_t)4224 * 512 * 2);
  u16* Bl = (u16*)alloc((size_t)4224 * 512 * 2);
  float* rwse = (float*)alloc((size_t)NODES * 8 * 4);
  float* rbuf = (float*)alloc((size_t)NODES * H4C * 4);
  float* h0   = (float*)alloc((size_t)NODES * 512 * 4);
  float* h1   = (float*)alloc((size_t)NODES * 512 * 4);
  float* xl   = (float*)alloc((size_t)NODES * 512 * 4);   // also reused as ffb
  float* xr   = (float*)alloc((size_t)NODES * 512 * 4);
  float* gout = (float*)alloc((size_t)NODES * 512 * 4);   // LN'd in place -> "local"
  float* attO = (float*)alloc((size_t)NODES * 512 * 4);
  float* gbuf = (float*)alloc((size_t)NODES * 512 * 4);
  float* comb = (float*)alloc((size_t)NODES * 512 * 4);
  u32* bits  = (u32*)alloc((size_t)NODES * 64 * 4);
  int* scnt  = (int*)alloc((size_t)NODES * 4);
  int* slist = (int*)alloc((size_t)NODES * SCAP * 4);
  int* cnt   = (int*)alloc((size_t)NODES * 4);
  int* elist = (int*)alloc((size_t)NODES * ECAP * 4);
  float* easum = (float*)alloc(8);
  float* ffb = xl;

  // ---- RWSE sparse path ----
  hipMemsetAsync(bits, 0, (size_t)NODES * 64 * 4, stream);
  hipMemsetAsync(scnt, 0, NODES * 4, stream);
  build_csr<<<EDGES / 256, 256, 0, stream>>>(edge_index, bits, scnt, slist);
  diag_T<<<NODES / 256, 256, 0, stream>>>(bits, scnt, rwse);
  spmm_sq<<<NODES, 256, 0, stream>>>(scnt, slist, P2);
  diag_copy<<<NODES / 256, 256, 0, stream>>>(P2, rwse, 1);
  spmm_gather<<<NODES, 256, 0, stream>>>(scnt, slist, P2, P3);
  diag_copy<<<NODES / 256, 256, 0, stream>>>(P3, rwse, 2);
  spmm_gather<<<NODES, 256, 0, stream>>>(scnt, slist, P3, P4);
  diag_copy<<<NODES / 256, 256, 0, stream>>>(P4, rwse, 3);
  diag_dot<<<NODES, 256, 0, stream>>>(P2, P3, rwse, 4);
  diag_dot<<<NODES, 256, 0, stream>>>(P3, P3, rwse, 5);
  diag_dot<<<NODES, 256, 0, stream>>>(P3, P4, rwse, 6);
  diag_dot<<<NODES, 256, 0, stream>>>(P4, P4, rwse, 7);
  rwse_proj<<<NODES, 128, 0, stream>>>(rwse, rwse_W, rwse_b, rwse_g, rwse_bt, rbuf);

  // ---- node projection: h = gelu(LN(concat(x, r) @ np_W + np_b)) ----
  // (P2..P4 dead from here; arena becomes Ah/Al/ffmid/qkvb)
  conv_A<<<(NODES * DIN + 255) / 256, 256, 0, stream>>>(x, Ah, Al, NODES * DIN, DIN, 4224, 0);
  conv_A<<<(NODES * H4C + 255) / 256, 256, 0, stream>>>(rbuf, Ah, Al, NODES * H4C, H4C, 4224, DIN);
  pack_B<<<(4224 * 512 + 255) / 256, 256, 0, stream>>>(np_W, Bh, Bl, 4224, 512);
  gemm_split<<<dim3(512 / 64, NODES / 64), 256, 0, stream>>>(Ah, Al, Bh, Bl, h0, np_b,
                                                             NODES, 4224, 512, 0, 0);
  ln512<<<NODES, 256, 0, stream>>>(h0, nullptr, np_g, np_bt, h1, 1);

  // ---- GAT CSR (with duplicate edges kept) + edge-attr mean ----
  hipMemsetAsync(cnt, 0, NODES * 4, stream);
  fill_edges<<<(EDGES + NODES) / 256, 256, 0, stream>>>(edge_index, cnt, elist);
  hipMemsetAsync(easum, 0, 8, stream);
  ea_reduce<<<64, 256, 0, stream>>>(eattr, easum);

  float* hin = h1;
  float* hout = h0;
  dim3 g512(512 / 64, NODES / 64);
  dim3 g1536(1536 / 64, NODES / 64);
  dim3 g2048(2048 / 64, NODES / 64);
  for (int l = 0; l < LLAY; l++) {
    // split(hin) once; reused by Wl, Wr, QKV GEMMs
    conv_A<<<(NODES * 512 + 255) / 256, 256, 0, stream>>>(hin, Ah, Al, NODES * 512, 512, 512, 0);
    pack_B<<<(512 * 512 + 255) / 256, 256, 0, stream>>>(gat_Wl + (size_t)l * 512 * 512, Bh, Bl, 512, 512);
    gemm_split<<<g512, 256, 0, stream>>>(Ah, Al, Bh, Bl, xl, gat_bl + l * 512, NODES, 512, 512, 0, 0);
    pack_B<<<(512 * 512 + 255) / 256, 256, 0, stream>>>(gat_Wr + (size_t)l * 512 * 512, Bh, Bl, 512, 512);
    gemm_split<<<g512, 256, 0, stream>>>(Ah, Al, Bh, Bl, xr, gat_br + l * 512, NODES, 512, 512, 0, 0);
    pack_B<<<(512 * 1536 + 255) / 256, 256, 0, stream>>>(mha_inW + (size_t)l * 512 * 1536, Bh, Bl, 512, 1536);
    gemm_split<<<g1536, 256, 0, stream>>>(Ah, Al, Bh, Bl, qkvb, mha_inb + l * 1536, NODES, 512, 1536, 0, 0);

    gat_kernel<<<NODES, 512, 0, stream>>>(xl, xr, eattr, easum, gat_We + l * 1024,
                                          gat_att + l * 512, gat_bias + l * 512,
                                          cnt, elist, edge_index, gout);
    ln512<<<NODES, 256, 0, stream>>>(gout, nullptr, n1_g + l * 512, n1_b + l * 512, gout, 0);

    mha_attn<<<BG * NHEAD, 256, 0, stream>>>(qkvb, attO);
    conv_A<<<(NODES * 512 + 255) / 256, 256, 0, stream>>>(attO, Ah, Al, NODES * 512, 512, 512, 0);
    pack_B<<<(512 * 512 + 255) / 256, 256, 0, stream>>>(mha_outW + (size_t)l * 512 * 512, Bh, Bl, 512, 512);
    gemm_split<<<g512, 256, 0, stream>>>(Ah, Al, Bh, Bl, gbuf, mha_outb + l * 512, NODES, 512, 512, 0, 0);
    ln512<<<NODES, 256, 0, stream>>>(gbuf, nullptr, n2_g + l * 512, n2_b + l * 512, gbuf, 0);

    combine_kernel<<<NODES * 512 / 256, 256, 0, stream>>>(gout, gbuf, alpha_p, l, comb);

    conv_A<<<(NODES * 512 + 255) / 256, 256, 0, stream>>>(comb, Ah, Al, NODES * 512, 512, 512, 0);
    pack_B<<<(512 * 2048 + 255) / 256, 256, 0, stream>>>(ffn_W1 + (size_t)l * 512 * 2048, Bh, Bl, 512, 2048);
    gemm_split<<<g2048, 256, 0, stream>>>(Ah, Al, Bh, Bl, ffmid, ffn_b1 + l * 2048, NODES, 512, 2048, 0, 1);
    conv_A<<<(NODES * 2048 + 255) / 256, 256, 0, stream>>>(ffmid, Ah, Al, NODES * 2048, 2048, 2048, 0);
    pack_B<<<(2048 * 512 + 255) / 256, 256, 0, stream>>>(ffn_W2 + (size_t)l * 2048 * 512, Bh, Bl, 2048, 512);
    gemm_split<<<g512, 256, 0, stream>>>(Ah, Al, Bh, Bl, ffb, ffn_b2 + l * 512, NODES, 2048, 512, 0, 0);
    ln512<<<NODES, 256, 0, stream>>>(ffb, comb, n3_g + l * 512, n3_b + l * 512, hout, 0);
    float* tmp = hin; hin = hout; hout = tmp;
  }

  head_kernel<<<1, 512, 0, stream>>>(hin, cni, ah_W1, ah_b1, ah_g, ah_bt, ah_W2,
                                     ah_b2, (float*)d_out);
}

// Round 3
// 1186.821 us; speedup vs baseline: 2.0558x; 1.2632x over previous
//
#include <hip/hip_runtime.h>
#include <math.h>

constexpr int NODES = 2048;
constexpr int BG = 8;
constexpr int SG = 256;
constexpr int DIN = 4096;
constexpr int NHEAD = 8;
constexpr int EDGES = 32768;
constexpr int LLAY = 2;
constexpr int ACT_N = 5;
constexpr int H4C = 128;
constexpr int ECAP = 192;   // per-dst edge list capacity (GAT)
constexpr int SCAP = 96;    // per-src dedup'd neighbor capacity (RWSE)

typedef unsigned short u16;
typedef unsigned int u32;
typedef short short8 __attribute__((ext_vector_type(8)));
typedef float f32x4 __attribute__((ext_vector_type(4)));

__device__ __forceinline__ float wave_sum(float v) {
#pragma unroll
  for (int o = 32; o; o >>= 1) v += __shfl_xor(v, o);
  return v;
}
__device__ __forceinline__ float wave_max(float v) {
#pragma unroll
  for (int o = 32; o; o >>= 1) v = fmaxf(v, __shfl_xor(v, o));
  return v;
}
__device__ __forceinline__ float blk_sum(float v, float* sh) {
  v = wave_sum(v);
  int nw = blockDim.x >> 6;
  __syncthreads();
  if ((threadIdx.x & 63) == 0) sh[threadIdx.x >> 6] = v;
  __syncthreads();
  float s = 0.f;
  for (int k = 0; k < nw; k++) s += sh[k];
  return s;
}
__device__ __forceinline__ float gelu_f(float x) {
  return 0.5f * x * (1.f + erff(x * 0.70710678118654752f));
}
__device__ __forceinline__ u16 f2bf(float x) {  // round-to-nearest-even bf16
  u32 u = __float_as_uint(x);
  return (u16)((u + 0x7FFFu + ((u >> 16) & 1u)) >> 16);
}
__device__ __forceinline__ float bf2f(u16 h) { return __uint_as_float(((u32)h) << 16); }

// ================= RWSE (sparse path) =================
__global__ void build_csr(const int* __restrict__ ei, u32* __restrict__ bits,
                          int* __restrict__ scnt, int* __restrict__ slist) {
  int e = blockIdx.x * 256 + threadIdx.x;
  if (e < EDGES) {
    int s = ei[e], d = ei[EDGES + e];
    u32 m = 1u << (d & 31);
    u32 old = atomicOr(&bits[s * 64 + (d >> 5)], m);
    if (!(old & m)) {
      int p = atomicAdd(&scnt[s], 1);
      if (p < SCAP) slist[s * SCAP + p] = d;
    }
  }
}

__global__ void diag_T(const u32* __restrict__ bits, const int* __restrict__ scnt,
                       float* __restrict__ rwse) {
  int i = blockIdx.x * 256 + threadIdx.x;
  if (i < NODES) {
    int deg = min(scnt[i], SCAP);
    int self = (bits[i * 64 + (i >> 5)] >> (i & 31)) & 1;
    rwse[(size_t)i * 8 + 0] = (self && deg > 0) ? 1.f / (float)deg : 0.f;
  }
}

__global__ __launch_bounds__(256) void spmm_sq(const int* __restrict__ scnt,
                                               const int* __restrict__ slist,
                                               float* __restrict__ P2) {
  int i = blockIdx.x, t = threadIdx.x;
  __shared__ float row[NODES];
  for (int c = t; c < NODES; c += 256) row[c] = 0.f;
  __syncthreads();
  int di = min(scnt[i], SCAP);
  float wi = di > 0 ? 1.f / (float)di : 0.f;
  for (int jj = 0; jj < di; jj++) {
    int j = slist[i * SCAP + jj];
    int dj = min(scnt[j], SCAP);
    if (dj == 0) continue;
    float w = wi / (float)dj;
    for (int kk = t; kk < dj; kk += 256) atomicAdd(&row[slist[j * SCAP + kk]], w);
  }
  __syncthreads();
  for (int c = t; c < NODES; c += 256) P2[(size_t)i * NODES + c] = row[c];
}

__global__ __launch_bounds__(256) void spmm_gather(const int* __restrict__ scnt,
                                                   const int* __restrict__ slist,
                                                   const float* __restrict__ P,
                                                   float* __restrict__ Q) {
  int i = blockIdx.x, t = threadIdx.x;
  __shared__ int nb[SCAP];
  int di = min(scnt[i], SCAP);
  for (int c = t; c < di; c += 256) nb[c] = slist[i * SCAP + c];
  __syncthreads();
  float wi = di > 0 ? 1.f / (float)di : 0.f;
  for (int c = t; c < NODES; c += 256) {
    float s = 0.f;
    for (int jj = 0; jj < di; jj++) s += P[(size_t)nb[jj] * NODES + c];
    Q[(size_t)i * NODES + c] = s * wi;
  }
}

__global__ void diag_copy(const float* __restrict__ P, float* __restrict__ rwse, int col) {
  int i = blockIdx.x * 256 + threadIdx.x;
  if (i < NODES) rwse[(size_t)i * 8 + col] = P[(size_t)i * (NODES + 1)];
}

// fused diag dots, tiled+coalesced: d5=P2·P3^T, d6=P3·P3^T, d7=P3·P4^T, d8=P4·P4^T
// grid (32 i-blocks, 8 j-splits); partials -> pbuf[js][i][4]
__global__ __launch_bounds__(256) void diag_tiled(const float* __restrict__ P2,
                                                  const float* __restrict__ P3,
                                                  const float* __restrict__ P4,
                                                  float* __restrict__ pbuf) {
  __shared__ float r2[64][65], r3[64][65], r4[64][65], c3[64][65], c4[64][65];
  __shared__ float red[4][4][64];
  int t = threadIdx.x;
  int i0 = blockIdx.x * 64;
  int js = blockIdx.y;
  int lo = t & 63, hi = t >> 6;
  float d5 = 0, d6 = 0, d7 = 0, d8 = 0;
  for (int jc = 0; jc < 4; jc++) {
    int j0 = js * 256 + jc * 64;
    __syncthreads();
#pragma unroll
    for (int r = 0; r < 16; r++) {
      int a = hi * 16 + r;
      r2[a][lo] = P2[(size_t)(i0 + a) * NODES + j0 + lo];
      r3[a][lo] = P3[(size_t)(i0 + a) * NODES + j0 + lo];
      r4[a][lo] = P4[(size_t)(i0 + a) * NODES + j0 + lo];
      c3[a][lo] = P3[(size_t)(j0 + a) * NODES + i0 + lo];
      c4[a][lo] = P4[(size_t)(j0 + a) * NODES + i0 + lo];
    }
    __syncthreads();
#pragma unroll
    for (int r = 0; r < 16; r++) {
      int jj = hi * 16 + r;
      float p3c = c3[jj][lo], p4c = c4[jj][lo];
      d5 += r2[lo][jj] * p3c;
      d6 += r3[lo][jj] * p3c;
      d7 += r3[lo][jj] * p4c;
      d8 += r4[lo][jj] * p4c;
    }
  }
  red[0][hi][lo] = d5; red[1][hi][lo] = d6; red[2][hi][lo] = d7; red[3][hi][lo] = d8;
  __syncthreads();
  if (hi == 0) {
    int i = i0 + lo;
#pragma unroll
    for (int v = 0; v < 4; v++) {
      float s = red[v][0][lo] + red[v][1][lo] + red[v][2][lo] + red[v][3][lo];
      pbuf[((size_t)js * NODES + i) * 4 + v] = s;
    }
  }
}

__global__ void diag_reduce(const float* __restrict__ pbuf, float* __restrict__ rwse) {
  int i = blockIdx.x * 256 + threadIdx.x;
  if (i >= NODES) return;
#pragma unroll
  for (int v = 0; v < 4; v++) {
    float s = 0.f;
    for (int js = 0; js < 8; js++) s += pbuf[((size_t)js * NODES + i) * 4 + v];
    rwse[(size_t)i * 8 + 4 + v] = s;
  }
}

// ================= split-bf16 conversion =================
__global__ void conv_A(const float* __restrict__ src, u16* __restrict__ Ah,
                       u16* __restrict__ Al, int total, int Ksrc, int dstStride,
                       int colOff) {
  int idx = blockIdx.x * 256 + threadIdx.x;
  if (idx >= total) return;
  int m = idx / Ksrc, k = idx - m * Ksrc;
  float v = src[idx];
  u16 h = f2bf(v);
  size_t o = (size_t)m * dstStride + colOff + k;
  Ah[o] = h;
  Al[o] = f2bf(v - bf2f(h));
}

__global__ void pack_B(const float* __restrict__ W, u16* __restrict__ Bh,
                       u16* __restrict__ Bl, int K, int N) {
  int idx = blockIdx.x * 256 + threadIdx.x;
  if (idx >= K * N) return;
  int k = idx / N, n = idx - k * N;
  float v = W[idx];
  u16 h = f2bf(v);
  size_t o = (size_t)(k >> 5) * N * 32 + (size_t)n * 32 + (k & 31);
  Bh[o] = h;
  Bl[o] = f2bf(v - bf2f(h));
}

// ================= split-bf16 MFMA GEMM =================
__global__ __launch_bounds__(256) void gemm_split(
    const u16* __restrict__ Ahg, const u16* __restrict__ Alg,
    const u16* __restrict__ Bhg, const u16* __restrict__ Blg,
    float* __restrict__ C, const float* __restrict__ bias,
    int M, int K, int N, int acc, int act) {
  __shared__ __align__(16) u16 Ash[2][64][40];
  __shared__ __align__(16) u16 Bsh[2][64][40];
  int tid = threadIdx.x;
  int lane = tid & 63, w = tid >> 6;
  int wm = (w >> 1) * 32, wn = (w & 1) * 32;
  int bm = blockIdx.y * 64, bn = blockIdx.x * 64;
  int lr = lane & 15, kk = (lane >> 4) * 8;
  int vrow = tid >> 2, vcol = (tid & 3) * 8;
  f32x4 accf[2][2] = {};
  const size_t aoff = (size_t)(bm + vrow) * K + vcol;
  const size_t boff = (size_t)(bn + vrow) * 32 + vcol;

  for (int kt = 0; kt < K; kt += 32) {
    short8 va = *(const short8*)(Ahg + aoff + kt);
    short8 vb = *(const short8*)(Alg + aoff + kt);
    size_t bo = (size_t)(kt >> 5) * N * 32 + boff;
    short8 vc = *(const short8*)(Bhg + bo);
    short8 vd = *(const short8*)(Blg + bo);
    __syncthreads();
    *(short8*)&Ash[0][vrow][vcol] = va;
    *(short8*)&Ash[1][vrow][vcol] = vb;
    *(short8*)&Bsh[0][vrow][vcol] = vc;
    *(short8*)&Bsh[1][vrow][vcol] = vd;
    __syncthreads();
    short8 ah[2], al[2], bh[2], bl[2];
#pragma unroll
    for (int i = 0; i < 2; i++) {
      ah[i] = *(const short8*)&Ash[0][wm + i * 16 + lr][kk];
      al[i] = *(const short8*)&Ash[1][wm + i * 16 + lr][kk];
      bh[i] = *(const short8*)&Bsh[0][wn + i * 16 + lr][kk];
      bl[i] = *(const short8*)&Bsh[1][wn + i * 16 + lr][kk];
    }
#pragma unroll
    for (int i = 0; i < 2; i++)
#pragma unroll
      for (int j = 0; j < 2; j++) {
        accf[i][j] = __builtin_amdgcn_mfma_f32_16x16x32_bf16(ah[i], bh[j], accf[i][j], 0, 0, 0);
        accf[i][j] = __builtin_amdgcn_mfma_f32_16x16x32_bf16(ah[i], bl[j], accf[i][j], 0, 0, 0);
        accf[i][j] = __builtin_amdgcn_mfma_f32_16x16x32_bf16(al[i], bh[j], accf[i][j], 0, 0, 0);
      }
  }
  int row0 = (lane >> 4) * 4;
#pragma unroll
  for (int i = 0; i < 2; i++)
#pragma unroll
    for (int j = 0; j < 2; j++) {
      int n = bn + wn + j * 16 + lr;
      float bv = bias ? bias[n] : 0.f;
#pragma unroll
      for (int r = 0; r < 4; r++) {
        int m = bm + wm + i * 16 + row0 + r;
        float v = accf[i][j][r] + bv;
        if (acc) v += C[(size_t)m * N + n];
        if (act) v = gelu_f(v);
        C[(size_t)m * N + n] = v;
      }
    }
}

// ================= small fused kernels =================
__global__ __launch_bounds__(128) void rwse_proj(const float* __restrict__ rwse,
                                                 const float* __restrict__ W,
                                                 const float* __restrict__ bb,
                                                 const float* __restrict__ g,
                                                 const float* __restrict__ bt,
                                                 float* __restrict__ r) {
  int i = blockIdx.x, j = threadIdx.x;
  float s = bb[j];
#pragma unroll
  for (int k = 0; k < 8; k++) s += rwse[(size_t)i * 8 + k] * W[k * H4C + j];
  __shared__ float sh[8];
  float sum = blk_sum(s, sh);
  float mu = sum * (1.f / 128.f);
  float d = s - mu;
  float var = blk_sum(d * d, sh) * (1.f / 128.f);
  r[(size_t)i * H4C + j] = gelu_f(d * rsqrtf(var + 1e-5f) * g[j] + bt[j]);
}

__global__ __launch_bounds__(256) void ln512(const float* __restrict__ x,
                                             const float* __restrict__ res,
                                             const float* __restrict__ g,
                                             const float* __restrict__ b,
                                             float* __restrict__ y, int do_gelu) {
  int i = blockIdx.x, t = threadIdx.x;
  size_t base = (size_t)i * 512;
  float v0 = x[base + t], v1 = x[base + 256 + t];
  if (res) { v0 += res[base + t]; v1 += res[base + 256 + t]; }
  __shared__ float sh[8];
  float s = blk_sum(v0 + v1, sh);
  float mu = s * (1.f / 512.f);
  float d0 = v0 - mu, d1 = v1 - mu;
  float var = blk_sum(d0 * d0 + d1 * d1, sh) * (1.f / 512.f);
  float rstd = rsqrtf(var + 1e-5f);
  float o0 = d0 * rstd * g[t] + b[t];
  float o1 = d1 * rstd * g[t + 256] + b[t + 256];
  if (do_gelu) { o0 = gelu_f(o0); o1 = gelu_f(o1); }
  y[base + t] = o0;
  y[base + 256 + t] = o1;
}

__global__ void fill_edges(const int* __restrict__ ei, int* __restrict__ cnt,
                           int* __restrict__ elist) {
  int e = blockIdx.x * 256 + threadIdx.x;
  if (e < EDGES + NODES) {
    int d = e < EDGES ? ei[EDGES + e] : e - EDGES;
    int p = atomicAdd(&cnt[d], 1);
    if (p < ECAP) elist[(size_t)d * ECAP + p] = e;
  }
}

__global__ void ea_reduce(const float* __restrict__ ea, float* __restrict__ sums) {
  int tid = blockIdx.x * blockDim.x + threadIdx.x;
  int stride = gridDim.x * blockDim.x;
  float s0 = 0.f, s1 = 0.f;
  for (int e = tid; e < EDGES; e += stride) { s0 += ea[2 * e]; s1 += ea[2 * e + 1]; }
  s0 = wave_sum(s0);
  s1 = wave_sum(s1);
  if ((threadIdx.x & 63) == 0) { atomicAdd(&sums[0], s0); atomicAdd(&sums[1], s1); }
}

__global__ __launch_bounds__(512) void gat_kernel(
    const float* __restrict__ xl, const float* __restrict__ xr,
    const float* __restrict__ eattr, const float* __restrict__ easum,
    const float* __restrict__ We, const float* __restrict__ att,
    const float* __restrict__ bias, const int* __restrict__ cnt,
    const int* __restrict__ elist, const int* __restrict__ ei,
    float* __restrict__ out) {
  int i = blockIdx.x;
  int tid = threadIdx.x;
  int h = tid >> 6, c = tid & 63;
  int m_cnt = cnt[i];
  if (m_cnt > ECAP) m_cnt = ECAP;
  const float inv_e = 1.f / (float)EDGES;
  float we0 = We[tid], we1 = We[512 + tid];
  float attv = att[tid];
  float xrv = xr[(size_t)i * 512 + tid];
  float ea_m0 = easum[0] * inv_e, ea_m1 = easum[1] * inv_e;
  __shared__ float logits[NHEAD][ECAP];
  const int* el = elist + (size_t)i * ECAP;
  for (int e = 0; e < m_cnt; e++) {
    int eid = el[e];
    int s;
    float a0, a1;
    if (eid < EDGES) { s = ei[eid]; a0 = eattr[2 * eid]; a1 = eattr[2 * eid + 1]; }
    else { s = i; a0 = ea_m0; a1 = ea_m1; }
    float mval = xl[(size_t)s * 512 + tid] + xrv + a0 * we0 + a1 * we1;
    mval = mval > 0.f ? mval : 0.2f * mval;
    float lg = wave_sum(mval * attv);
    if (c == 0) logits[h][e] = lg;
  }
  float mx = -1e30f;
  for (int e = c; e < m_cnt; e += 64) mx = fmaxf(mx, logits[h][e]);
  mx = wave_max(mx);
  float den = 0.f;
  for (int e = c; e < m_cnt; e += 64) den += expf(logits[h][e] - mx);
  den = wave_sum(den) + 1e-16f;
  float acc = 0.f;
  for (int e = 0; e < m_cnt; e++) {
    int eid = el[e];
    int s = eid < EDGES ? ei[eid] : i;
    float alpha = expf(logits[h][e] - mx) / den;
    acc += alpha * xl[(size_t)s * 512 + tid];
  }
  out[(size_t)i * 512 + tid] = acc + bias[tid];
}

// ======= flash-style block-diag MHA: block=(b,h,32-row q-tile), 4 thr/row ====
__global__ __launch_bounds__(128) void mha_flash(const float* __restrict__ qkv,
                                                 float* __restrict__ o) {
  int bid = blockIdx.x;
  int qt = bid & 7;
  int h = (bid >> 3) & 7;
  int b = bid >> 6;
  int t = threadIdx.x;
  int row = t >> 2, seg = t & 3;
  size_t rowbase = (size_t)(b * SG) * 1536;
  const float* qrow = qkv + rowbase + (size_t)(qt * 32 + row) * 1536 + h * 64 + seg * 16;
  float q[16];
#pragma unroll
  for (int i = 0; i < 4; i++) *(float4*)&q[i * 4] = *(const float4*)&qrow[i * 4];
  const float* kb = qkv + rowbase + 512 + h * 64 + seg * 16;
  const float* vb = qkv + rowbase + 1024 + h * 64 + seg * 16;
  float m = -1e30f, den = 0.f;
  float oa[16];
#pragma unroll
  for (int i = 0; i < 16; i++) oa[i] = 0.f;
  for (int j = 0; j < SG; j++) {
    const float* kr = kb + (size_t)j * 1536;
    float kv[16];
#pragma unroll
    for (int i = 0; i < 4; i++) *(float4*)&kv[i * 4] = *(const float4*)&kr[i * 4];
    float s = 0.f;
#pragma unroll
    for (int i = 0; i < 16; i++) s += q[i] * kv[i];
    s += __shfl_xor(s, 1);
    s += __shfl_xor(s, 2);
    s *= 0.125f;
    const float* vr = vb + (size_t)j * 1536;
    float vv[16];
#pragma unroll
    for (int i = 0; i < 4; i++) *(float4*)&vv[i * 4] = *(const float4*)&vr[i * 4];
    if (s > m) {
      float c = __expf(m - s);
      den *= c;
#pragma unroll
      for (int i = 0; i < 16; i++) oa[i] *= c;
      m = s;
    }
    float p = __expf(s - m);
    den += p;
#pragma unroll
    for (int i = 0; i < 16; i++) oa[i] += p * vv[i];
  }
  float inv = 1.f / den;
  float* orow = o + (size_t)(b * SG + qt * 32 + row) * 512 + h * 64 + seg * 16;
#pragma unroll
  for (int i = 0; i < 4; i++) {
    float4 v4 = make_float4(oa[i * 4] * inv, oa[i * 4 + 1] * inv,
                            oa[i * 4 + 2] * inv, oa[i * 4 + 3] * inv);
    *(float4*)&orow[i * 4] = v4;
  }
}

__global__ void combine_kernel(const float* __restrict__ loc, const float* __restrict__ gl,
                               const float* __restrict__ ap, int l, float* __restrict__ comb) {
  int idx = blockIdx.x * 256 + threadIdx.x;
  float a = 1.f / (1.f + expf(-ap[l]));
  comb[idx] = a * loc[idx] + (1.f - a) * gl[idx];
}

__global__ __launch_bounds__(512) void head_kernel(
    const float* __restrict__ hfin, const int* __restrict__ cni,
    const float* __restrict__ W1, const float* __restrict__ b1,
    const float* __restrict__ g, const float* __restrict__ bt,
    const float* __restrict__ W2, const float* __restrict__ b2,
    float* __restrict__ out) {
  __shared__ float emb[512];
  __shared__ float z[512];
  __shared__ float sh[8];
  __shared__ float lg[ACT_N];
  int t = threadIdx.x;
  int idx = cni[0];
  emb[t] = hfin[(size_t)idx * 512 + t];
  __syncthreads();
  float s = b1[t];
  for (int k = 0; k < 512; k++) s += emb[k] * W1[(size_t)k * 512 + t];
  float sum = blk_sum(s, sh);
  float mu = sum * (1.f / 512.f);
  float d = s - mu;
  float var = blk_sum(d * d, sh) * (1.f / 512.f);
  z[t] = gelu_f(d * rsqrtf(var + 1e-5f) * g[t] + bt[t]);
  __syncthreads();
  if (t < ACT_N) {
    float l = b2[t];
    for (int k = 0; k < 512; k++) l += z[k] * W2[k * ACT_N + t];
    lg[t] = l;
  }
  __syncthreads();
  if (t == 0) {
    float m2 = lg[0];
    for (int a = 1; a < ACT_N; a++) m2 = fmaxf(m2, lg[a]);
    float den = 0.f;
    float ex[ACT_N];
    for (int a = 0; a < ACT_N; a++) { ex[a] = expf(lg[a] - m2); den += ex[a]; }
    for (int a = 0; a < ACT_N; a++) {
      out[a] = lg[a];
      out[ACT_N + a] = ex[a] / den;
    }
  }
}

extern "C" void kernel_launch(void* const* d_in, const int* in_sizes, int n_in,
                              void* d_out, int out_size, void* d_ws, size_t ws_size,
                              hipStream_t stream) {
  const float* x        = (const float*)d_in[0];
  const float* eattr    = (const float*)d_in[1];
  const float* rwse_W   = (const float*)d_in[2];
  const float* rwse_b   = (const float*)d_in[3];
  const float* rwse_g   = (const float*)d_in[4];
  const float* rwse_bt  = (const float*)d_in[5];
  const float* np_W     = (const float*)d_in[6];
  const float* np_b     = (const float*)d_in[7];
  const float* np_g     = (const float*)d_in[8];
  const float* np_bt    = (const float*)d_in[9];
  const float* gat_Wl   = (const float*)d_in[10];
  const float* gat_bl   = (const float*)d_in[11];
  const float* gat_Wr   = (const float*)d_in[12];
  const float* gat_br   = (const float*)d_in[13];
  const float* gat_We   = (const float*)d_in[14];
  const float* gat_att  = (const float*)d_in[15];
  const float* gat_bias = (const float*)d_in[16];
  const float* n1_g = (const float*)d_in[17];
  const float* n1_b = (const float*)d_in[18];
  const float* mha_inW  = (const float*)d_in[19];
  const float* mha_inb  = (const float*)d_in[20];
  const float* mha_outW = (const float*)d_in[21];
  const float* mha_outb = (const float*)d_in[22];
  const float* alpha_p  = (const float*)d_in[23];
  const float* n2_g = (const float*)d_in[24];
  const float* n2_b = (const float*)d_in[25];
  const float* ffn_W1 = (const float*)d_in[26];
  const float* ffn_b1 = (const float*)d_in[27];
  const float* ffn_W2 = (const float*)d_in[28];
  const float* ffn_b2 = (const float*)d_in[29];
  const float* n3_g = (const float*)d_in[30];
  const float* n3_b = (const float*)d_in[31];
  const float* ah_W1 = (const float*)d_in[32];
  const float* ah_b1 = (const float*)d_in[33];
  const float* ah_g  = (const float*)d_in[34];
  const float* ah_bt = (const float*)d_in[35];
  const float* ah_W2 = (const float*)d_in[36];
  const float* ah_b2 = (const float*)d_in[37];
  const int* edge_index = (const int*)d_in[38];
  const int* cni        = (const int*)d_in[39];
  (void)in_sizes; (void)n_in; (void)out_size; (void)ws_size;

  char* wsp = (char*)d_ws;
  size_t off = 0;
  auto alloc = [&](size_t bytes) -> char* {
    char* p = wsp + off;
    off += (bytes + 255) & ~(size_t)255;
    return p;
  };
  const size_t NNb = (size_t)NODES * NODES * 4;
  char* arena = alloc(3 * NNb);
  float* P2 = (float*)arena;
  float* P3 = (float*)(arena + NNb);
  float* P4 = (float*)(arena + 2 * NNb);
  u16* Ah = (u16*)arena;
  u16* Al = (u16*)(arena + (size_t)NODES * 4224 * 2);
  float* ffmid = (float*)(arena + (size_t)NODES * 4224 * 2 + (size_t)NODES * 2048 * 2);
  float* qkvb  = (float*)(arena + (size_t)NODES * 4224 * 4);
  u16* Bh = (u16*)alloc((size_t)4224 * 512 * 2);
  u16* Bl = (u16*)alloc((size_t)4224 * 512 * 2);
  float* rwse = (float*)alloc((size_t)NODES * 8 * 4);
  float* rbuf = (float*)alloc((size_t)NODES * H4C * 4);
  float* h0   = (float*)alloc((size_t)NODES * 512 * 4);
  float* h1   = (float*)alloc((size_t)NODES * 512 * 4);
  float* xl   = (float*)alloc((size_t)NODES * 512 * 4);
  float* xr   = (float*)alloc((size_t)NODES * 512 * 4);
  float* gout = (float*)alloc((size_t)NODES * 512 * 4);
  float* attO = (float*)alloc((size_t)NODES * 512 * 4);
  float* gbuf = (float*)alloc((size_t)NODES * 512 * 4);
  float* comb = (float*)alloc((size_t)NODES * 512 * 4);
  u32* bits  = (u32*)alloc((size_t)NODES * 64 * 4);
  int* scnt  = (int*)alloc((size_t)NODES * 4);
  int* slist = (int*)alloc((size_t)NODES * SCAP * 4);
  int* cnt   = (int*)alloc((size_t)NODES * 4);
  int* elist = (int*)alloc((size_t)NODES * ECAP * 4);
  float* easum = (float*)alloc(8);
  float* pbuf  = (float*)alloc((size_t)8 * NODES * 4 * 4);
  float* ffb = xl;

  // ---- RWSE sparse path ----
  hipMemsetAsync(bits, 0, (size_t)NODES * 64 * 4, stream);
  hipMemsetAsync(scnt, 0, NODES * 4, stream);
  build_csr<<<EDGES / 256, 256, 0, stream>>>(edge_index, bits, scnt, slist);
  diag_T<<<NODES / 256, 256, 0, stream>>>(bits, scnt, rwse);
  spmm_sq<<<NODES, 256, 0, stream>>>(scnt, slist, P2);
  diag_copy<<<NODES / 256, 256, 0, stream>>>(P2, rwse, 1);
  spmm_gather<<<NODES, 256, 0, stream>>>(scnt, slist, P2, P3);
  diag_copy<<<NODES / 256, 256, 0, stream>>>(P3, rwse, 2);
  spmm_gather<<<NODES, 256, 0, stream>>>(scnt, slist, P3, P4);
  diag_copy<<<NODES / 256, 256, 0, stream>>>(P4, rwse, 3);
  diag_tiled<<<dim3(NODES / 64, 8), 256, 0, stream>>>(P2, P3, P4, pbuf);
  diag_reduce<<<NODES / 256, 256, 0, stream>>>(pbuf, rwse);
  rwse_proj<<<NODES, 128, 0, stream>>>(rwse, rwse_W, rwse_b, rwse_g, rwse_bt, rbuf);

  // ---- node projection ----
  conv_A<<<(NODES * DIN + 255) / 256, 256, 0, stream>>>(x, Ah, Al, NODES * DIN, DIN, 4224, 0);
  conv_A<<<(NODES * H4C + 255) / 256, 256, 0, stream>>>(rbuf, Ah, Al, NODES * H4C, H4C, 4224, DIN);
  pack_B<<<(4224 * 512 + 255) / 256, 256, 0, stream>>>(np_W, Bh, Bl, 4224, 512);
  gemm_split<<<dim3(512 / 64, NODES / 64), 256, 0, stream>>>(Ah, Al, Bh, Bl, h0, np_b,
                                                             NODES, 4224, 512, 0, 0);
  ln512<<<NODES, 256, 0, stream>>>(h0, nullptr, np_g, np_bt, h1, 1);

  // ---- GAT CSR + edge-attr mean ----
  hipMemsetAsync(cnt, 0, NODES * 4, stream);
  fill_edges<<<(EDGES + NODES) / 256, 256, 0, stream>>>(edge_index, cnt, elist);
  hipMemsetAsync(easum, 0, 8, stream);
  ea_reduce<<<64, 256, 0, stream>>>(eattr, easum);

  float* hin = h1;
  float* hout = h0;
  dim3 g512(512 / 64, NODES / 64);
  dim3 g1536(1536 / 64, NODES / 64);
  dim3 g2048(2048 / 64, NODES / 64);
  for (int l = 0; l < LLAY; l++) {
    conv_A<<<(NODES * 512 + 255) / 256, 256, 0, stream>>>(hin, Ah, Al, NODES * 512, 512, 512, 0);
    pack_B<<<(512 * 512 + 255) / 256, 256, 0, stream>>>(gat_Wl + (size_t)l * 512 * 512, Bh, Bl, 512, 512);
    gemm_split<<<g512, 256, 0, stream>>>(Ah, Al, Bh, Bl, xl, gat_bl + l * 512, NODES, 512, 512, 0, 0);
    pack_B<<<(512 * 512 + 255) / 256, 256, 0, stream>>>(gat_Wr + (size_t)l * 512 * 512, Bh, Bl, 512, 512);
    gemm_split<<<g512, 256, 0, stream>>>(Ah, Al, Bh, Bl, xr, gat_br + l * 512, NODES, 512, 512, 0, 0);
    pack_B<<<(512 * 1536 + 255) / 256, 256, 0, stream>>>(mha_inW + (size_t)l * 512 * 1536, Bh, Bl, 512, 1536);
    gemm_split<<<g1536, 256, 0, stream>>>(Ah, Al, Bh, Bl, qkvb, mha_inb + l * 1536, NODES, 512, 1536, 0, 0);

    gat_kernel<<<NODES, 512, 0, stream>>>(xl, xr, eattr, easum, gat_We + l * 1024,
                                          gat_att + l * 512, gat_bias + l * 512,
                                          cnt, elist, edge_index, gout);
    ln512<<<NODES, 256, 0, stream>>>(gout, nullptr, n1_g + l * 512, n1_b + l * 512, gout, 0);

    mha_flash<<<BG * NHEAD * 8, 128, 0, stream>>>(qkvb, attO);
    conv_A<<<(NODES * 512 + 255) / 256, 256, 0, stream>>>(attO, Ah, Al, NODES * 512, 512, 512, 0);
    pack_B<<<(512 * 512 + 255) / 256, 256, 0, stream>>>(mha_outW + (size_t)l * 512 * 512, Bh, Bl, 512, 512);
    gemm_split<<<g512, 256, 0, stream>>>(Ah, Al, Bh, Bl, gbuf, mha_outb + l * 512, NODES, 512, 512, 0, 0);
    ln512<<<NODES, 256, 0, stream>>>(gbuf, nullptr, n2_g + l * 512, n2_b + l * 512, gbuf, 0);

    combine_kernel<<<NODES * 512 / 256, 256, 0, stream>>>(gout, gbuf, alpha_p, l, comb);

    conv_A<<<(NODES * 512 + 255) / 256, 256, 0, stream>>>(comb, Ah, Al, NODES * 512, 512, 512, 0);
    pack_B<<<(512 * 2048 + 255) / 256, 256, 0, stream>>>(ffn_W1 + (size_t)l * 512 * 2048, Bh, Bl, 512, 2048);
    gemm_split<<<g2048, 256, 0, stream>>>(Ah, Al, Bh, Bl, ffmid, ffn_b1 + l * 2048, NODES, 512, 2048, 0, 1);
    conv_A<<<(NODES * 2048 + 255) / 256, 256, 0, stream>>>(ffmid, Ah, Al, NODES * 2048, 2048, 2048, 0);
    pack_B<<<(2048 * 512 + 255) / 256, 256, 0, stream>>>(ffn_W2 + (size_t)l * 2048 * 512, Bh, Bl, 2048, 512);
    gemm_split<<<g512, 256, 0, stream>>>(Ah, Al, Bh, Bl, ffb, ffn_b2 + l * 512, NODES, 2048, 512, 0, 0);
    ln512<<<NODES, 256, 0, stream>>>(ffb, comb, n3_g + l * 512, n3_b + l * 512, hout, 0);
    float* tmp = hin; hin = hout; hout = tmp;
  }

  head_kernel<<<1, 512, 0, stream>>>(hin, cni, ah_W1, ah_b1, ah_g, ah_bt, ah_W2,
                                     ah_b2, (float*)d_out);
}

// Round 4
// 914.456 us; speedup vs baseline: 2.6681x; 1.2978x over previous
//
#include <hip/hip_runtime.h>
#include <math.h>

constexpr int NODES = 2048;
constexpr int BG = 8;
constexpr int SG = 256;
constexpr int DIN = 4096;
constexpr int NHEAD = 8;
constexpr int EDGES = 32768;
constexpr int LLAY = 2;
constexpr int ACT_N = 5;
constexpr int H4C = 128;
constexpr int ECAP = 192;   // per-dst edge list capacity (GAT)
constexpr int SCAP = 96;    // per-src dedup'd neighbor capacity (RWSE)

typedef unsigned short u16;
typedef unsigned int u32;
typedef short short8 __attribute__((ext_vector_type(8)));
typedef float f32x4 __attribute__((ext_vector_type(4)));

__device__ __forceinline__ float wave_sum(float v) {
#pragma unroll
  for (int o = 32; o; o >>= 1) v += __shfl_xor(v, o);
  return v;
}
__device__ __forceinline__ float wave_max(float v) {
#pragma unroll
  for (int o = 32; o; o >>= 1) v = fmaxf(v, __shfl_xor(v, o));
  return v;
}
__device__ __forceinline__ float blk_sum(float v, float* sh) {
  v = wave_sum(v);
  int nw = blockDim.x >> 6;
  __syncthreads();
  if ((threadIdx.x & 63) == 0) sh[threadIdx.x >> 6] = v;
  __syncthreads();
  float s = 0.f;
  for (int k = 0; k < nw; k++) s += sh[k];
  return s;
}
__device__ __forceinline__ float gelu_f(float x) {
  return 0.5f * x * (1.f + erff(x * 0.70710678118654752f));
}
__device__ __forceinline__ u16 f2bf(float x) {  // round-to-nearest-even bf16
  u32 u = __float_as_uint(x);
  return (u16)((u + 0x7FFFu + ((u >> 16) & 1u)) >> 16);
}
__device__ __forceinline__ float bf2f(u16 h) { return __uint_as_float(((u32)h) << 16); }

// ================= RWSE (sparse path) =================
__global__ void build_csr(const int* __restrict__ ei, u32* __restrict__ bits,
                          int* __restrict__ scnt, int* __restrict__ slist) {
  int e = blockIdx.x * 256 + threadIdx.x;
  if (e < EDGES) {
    int s = ei[e], d = ei[EDGES + e];
    u32 m = 1u << (d & 31);
    u32 old = atomicOr(&bits[s * 64 + (d >> 5)], m);
    if (!(old & m)) {
      int p = atomicAdd(&scnt[s], 1);
      if (p < SCAP) slist[s * SCAP + p] = d;
    }
  }
}

__global__ void diag_T(const u32* __restrict__ bits, const int* __restrict__ scnt,
                       float* __restrict__ rwse) {
  int i = blockIdx.x * 256 + threadIdx.x;
  if (i < NODES) {
    int deg = min(scnt[i], SCAP);
    int self = (bits[i * 64 + (i >> 5)] >> (i & 31)) & 1;
    rwse[(size_t)i * 8 + 0] = (self && deg > 0) ? 1.f / (float)deg : 0.f;
  }
}

__global__ __launch_bounds__(256) void spmm_sq(const int* __restrict__ scnt,
                                               const int* __restrict__ slist,
                                               float* __restrict__ P2) {
  int i = blockIdx.x, t = threadIdx.x;
  __shared__ float row[NODES];
  for (int c = t; c < NODES; c += 256) row[c] = 0.f;
  __syncthreads();
  int di = min(scnt[i], SCAP);
  float wi = di > 0 ? 1.f / (float)di : 0.f;
  for (int jj = 0; jj < di; jj++) {
    int j = slist[i * SCAP + jj];
    int dj = min(scnt[j], SCAP);
    if (dj == 0) continue;
    float w = wi / (float)dj;
    for (int kk = t; kk < dj; kk += 256) atomicAdd(&row[slist[j * SCAP + kk]], w);
  }
  __syncthreads();
  for (int c = t; c < NODES; c += 256) P2[(size_t)i * NODES + c] = row[c];
}

__global__ __launch_bounds__(256) void spmm_gather(const int* __restrict__ scnt,
                                                   const int* __restrict__ slist,
                                                   const float* __restrict__ P,
                                                   float* __restrict__ Q) {
  int i = blockIdx.x, t = threadIdx.x;
  __shared__ int nb[SCAP];
  int di = min(scnt[i], SCAP);
  for (int c = t; c < di; c += 256) nb[c] = slist[i * SCAP + c];
  __syncthreads();
  float wi = di > 0 ? 1.f / (float)di : 0.f;
  for (int c = t; c < NODES; c += 256) {
    float s = 0.f;
    for (int jj = 0; jj < di; jj++) s += P[(size_t)nb[jj] * NODES + c];
    Q[(size_t)i * NODES + c] = s * wi;
  }
}

__global__ void diag_copy(const float* __restrict__ P, float* __restrict__ rwse, int col) {
  int i = blockIdx.x * 256 + threadIdx.x;
  if (i < NODES) rwse[(size_t)i * 8 + col] = P[(size_t)i * (NODES + 1)];
}

// fused diag dots, tiled+coalesced
__global__ __launch_bounds__(256) void diag_tiled(const float* __restrict__ P2,
                                                  const float* __restrict__ P3,
                                                  const float* __restrict__ P4,
                                                  float* __restrict__ pbuf) {
  __shared__ float r2[64][65], r3[64][65], r4[64][65], c3[64][65], c4[64][65];
  __shared__ float red[4][4][64];
  int t = threadIdx.x;
  int i0 = blockIdx.x * 64;
  int js = blockIdx.y;
  int lo = t & 63, hi = t >> 6;
  float d5 = 0, d6 = 0, d7 = 0, d8 = 0;
  for (int jc = 0; jc < 4; jc++) {
    int j0 = js * 256 + jc * 64;
    __syncthreads();
#pragma unroll
    for (int r = 0; r < 16; r++) {
      int a = hi * 16 + r;
      r2[a][lo] = P2[(size_t)(i0 + a) * NODES + j0 + lo];
      r3[a][lo] = P3[(size_t)(i0 + a) * NODES + j0 + lo];
      r4[a][lo] = P4[(size_t)(i0 + a) * NODES + j0 + lo];
      c3[a][lo] = P3[(size_t)(j0 + a) * NODES + i0 + lo];
      c4[a][lo] = P4[(size_t)(j0 + a) * NODES + i0 + lo];
    }
    __syncthreads();
#pragma unroll
    for (int r = 0; r < 16; r++) {
      int jj = hi * 16 + r;
      float p3c = c3[jj][lo], p4c = c4[jj][lo];
      d5 += r2[lo][jj] * p3c;
      d6 += r3[lo][jj] * p3c;
      d7 += r3[lo][jj] * p4c;
      d8 += r4[lo][jj] * p4c;
    }
  }
  red[0][hi][lo] = d5; red[1][hi][lo] = d6; red[2][hi][lo] = d7; red[3][hi][lo] = d8;
  __syncthreads();
  if (hi == 0) {
    int i = i0 + lo;
#pragma unroll
    for (int v = 0; v < 4; v++) {
      float s = red[v][0][lo] + red[v][1][lo] + red[v][2][lo] + red[v][3][lo];
      pbuf[((size_t)js * NODES + i) * 4 + v] = s;
    }
  }
}

__global__ void diag_reduce(const float* __restrict__ pbuf, float* __restrict__ rwse) {
  int i = blockIdx.x * 256 + threadIdx.x;
  if (i >= NODES) return;
#pragma unroll
  for (int v = 0; v < 4; v++) {
    float s = 0.f;
    for (int js = 0; js < 8; js++) s += pbuf[((size_t)js * NODES + i) * 4 + v];
    rwse[(size_t)i * 8 + 4 + v] = s;
  }
}

// ================= split-bf16 conversion =================
__global__ void conv_A(const float* __restrict__ src, u16* __restrict__ Ah,
                       u16* __restrict__ Al, int total, int Ksrc, int dstStride,
                       int colOff) {
  int idx = blockIdx.x * 256 + threadIdx.x;
  if (idx >= total) return;
  int m = idx / Ksrc, k = idx - m * Ksrc;
  float v = src[idx];
  u16 h = f2bf(v);
  size_t o = (size_t)m * dstStride + colOff + k;
  Ah[o] = h;
  Al[o] = f2bf(v - bf2f(h));
}

__global__ void pack_B(const float* __restrict__ W, u16* __restrict__ Bh,
                       u16* __restrict__ Bl, int K, int N) {
  int idx = blockIdx.x * 256 + threadIdx.x;
  if (idx >= K * N) return;
  int k = idx / N, n = idx - k * N;
  float v = W[idx];
  u16 h = f2bf(v);
  size_t o = (size_t)(k >> 5) * N * 32 + (size_t)n * 32 + (k & 31);
  Bh[o] = h;
  Bl[o] = f2bf(v - bf2f(h));
}

// ================= split-bf16 MFMA GEMM =================
__global__ __launch_bounds__(256) void gemm_split(
    const u16* __restrict__ Ahg, const u16* __restrict__ Alg,
    const u16* __restrict__ Bhg, const u16* __restrict__ Blg,
    float* __restrict__ C, const float* __restrict__ bias,
    int M, int K, int N, int acc, int act) {
  __shared__ __align__(16) u16 Ash[2][64][40];
  __shared__ __align__(16) u16 Bsh[2][64][40];
  int tid = threadIdx.x;
  int lane = tid & 63, w = tid >> 6;
  int wm = (w >> 1) * 32, wn = (w & 1) * 32;
  int bm = blockIdx.y * 64, bn = blockIdx.x * 64;
  int lr = lane & 15, kk = (lane >> 4) * 8;
  int vrow = tid >> 2, vcol = (tid & 3) * 8;
  f32x4 accf[2][2] = {};
  const size_t aoff = (size_t)(bm + vrow) * K + vcol;
  const size_t boff = (size_t)(bn + vrow) * 32 + vcol;

  for (int kt = 0; kt < K; kt += 32) {
    short8 va = *(const short8*)(Ahg + aoff + kt);
    short8 vb = *(const short8*)(Alg + aoff + kt);
    size_t bo = (size_t)(kt >> 5) * N * 32 + boff;
    short8 vc = *(const short8*)(Bhg + bo);
    short8 vd = *(const short8*)(Blg + bo);
    __syncthreads();
    *(short8*)&Ash[0][vrow][vcol] = va;
    *(short8*)&Ash[1][vrow][vcol] = vb;
    *(short8*)&Bsh[0][vrow][vcol] = vc;
    *(short8*)&Bsh[1][vrow][vcol] = vd;
    __syncthreads();
    short8 ah[2], al[2], bh[2], bl[2];
#pragma unroll
    for (int i = 0; i < 2; i++) {
      ah[i] = *(const short8*)&Ash[0][wm + i * 16 + lr][kk];
      al[i] = *(const short8*)&Ash[1][wm + i * 16 + lr][kk];
      bh[i] = *(const short8*)&Bsh[0][wn + i * 16 + lr][kk];
      bl[i] = *(const short8*)&Bsh[1][wn + i * 16 + lr][kk];
    }
#pragma unroll
    for (int i = 0; i < 2; i++)
#pragma unroll
      for (int j = 0; j < 2; j++) {
        accf[i][j] = __builtin_amdgcn_mfma_f32_16x16x32_bf16(ah[i], bh[j], accf[i][j], 0, 0, 0);
        accf[i][j] = __builtin_amdgcn_mfma_f32_16x16x32_bf16(ah[i], bl[j], accf[i][j], 0, 0, 0);
        accf[i][j] = __builtin_amdgcn_mfma_f32_16x16x32_bf16(al[i], bh[j], accf[i][j], 0, 0, 0);
      }
  }
  int row0 = (lane >> 4) * 4;
#pragma unroll
  for (int i = 0; i < 2; i++)
#pragma unroll
    for (int j = 0; j < 2; j++) {
      int n = bn + wn + j * 16 + lr;
      float bv = bias ? bias[n] : 0.f;
#pragma unroll
      for (int r = 0; r < 4; r++) {
        int m = bm + wm + i * 16 + row0 + r;
        float v = accf[i][j][r] + bv;
        if (acc) v += C[(size_t)m * N + n];
        if (act) v = gelu_f(v);
        C[(size_t)m * N + n] = v;
      }
    }
}

// ================= small fused kernels =================
__global__ __launch_bounds__(128) void rwse_proj(const float* __restrict__ rwse,
                                                 const float* __restrict__ W,
                                                 const float* __restrict__ bb,
                                                 const float* __restrict__ g,
                                                 const float* __restrict__ bt,
                                                 float* __restrict__ r) {
  int i = blockIdx.x, j = threadIdx.x;
  float s = bb[j];
#pragma unroll
  for (int k = 0; k < 8; k++) s += rwse[(size_t)i * 8 + k] * W[k * H4C + j];
  __shared__ float sh[8];
  float sum = blk_sum(s, sh);
  float mu = sum * (1.f / 128.f);
  float d = s - mu;
  float var = blk_sum(d * d, sh) * (1.f / 128.f);
  r[(size_t)i * H4C + j] = gelu_f(d * rsqrtf(var + 1e-5f) * g[j] + bt[j]);
}

__global__ __launch_bounds__(256) void ln512(const float* __restrict__ x,
                                             const float* __restrict__ res,
                                             const float* __restrict__ g,
                                             const float* __restrict__ b,
                                             float* __restrict__ y, int do_gelu) {
  int i = blockIdx.x, t = threadIdx.x;
  size_t base = (size_t)i * 512;
  float v0 = x[base + t], v1 = x[base + 256 + t];
  if (res) { v0 += res[base + t]; v1 += res[base + 256 + t]; }
  __shared__ float sh[8];
  float s = blk_sum(v0 + v1, sh);
  float mu = s * (1.f / 512.f);
  float d0 = v0 - mu, d1 = v1 - mu;
  float var = blk_sum(d0 * d0 + d1 * d1, sh) * (1.f / 512.f);
  float rstd = rsqrtf(var + 1e-5f);
  float o0 = d0 * rstd * g[t] + b[t];
  float o1 = d1 * rstd * g[t + 256] + b[t + 256];
  if (do_gelu) { o0 = gelu_f(o0); o1 = gelu_f(o1); }
  y[base + t] = o0;
  y[base + 256 + t] = o1;
}

__global__ void fill_edges(const int* __restrict__ ei, int* __restrict__ cnt,
                           int* __restrict__ elist) {
  int e = blockIdx.x * 256 + threadIdx.x;
  if (e < EDGES + NODES) {
    int d = e < EDGES ? ei[EDGES + e] : e - EDGES;
    int p = atomicAdd(&cnt[d], 1);
    if (p < ECAP) elist[(size_t)d * ECAP + p] = e;
  }
}

__global__ void ea_reduce(const float* __restrict__ ea, float* __restrict__ sums) {
  int tid = blockIdx.x * blockDim.x + threadIdx.x;
  int stride = gridDim.x * blockDim.x;
  float s0 = 0.f, s1 = 0.f;
  for (int e = tid; e < EDGES; e += stride) { s0 += ea[2 * e]; s1 += ea[2 * e + 1]; }
  s0 = wave_sum(s0);
  s1 = wave_sum(s1);
  if ((threadIdx.x & 63) == 0) { atomicAdd(&sums[0], s0); atomicAdd(&sums[1], s1); }
}

__global__ __launch_bounds__(512) void gat_kernel(
    const float* __restrict__ xl, const float* __restrict__ xr,
    const float* __restrict__ eattr, const float* __restrict__ easum,
    const float* __restrict__ We, const float* __restrict__ att,
    const float* __restrict__ bias, const int* __restrict__ cnt,
    const int* __restrict__ elist, const int* __restrict__ ei,
    float* __restrict__ out) {
  int i = blockIdx.x;
  int tid = threadIdx.x;
  int h = tid >> 6, c = tid & 63;
  int m_cnt = cnt[i];
  if (m_cnt > ECAP) m_cnt = ECAP;
  const float inv_e = 1.f / (float)EDGES;
  float we0 = We[tid], we1 = We[512 + tid];
  float attv = att[tid];
  float xrv = xr[(size_t)i * 512 + tid];
  float ea_m0 = easum[0] * inv_e, ea_m1 = easum[1] * inv_e;
  __shared__ float logits[NHEAD][ECAP];
  const int* el = elist + (size_t)i * ECAP;
  for (int e = 0; e < m_cnt; e++) {
    int eid = el[e];
    int s;
    float a0, a1;
    if (eid < EDGES) { s = ei[eid]; a0 = eattr[2 * eid]; a1 = eattr[2 * eid + 1]; }
    else { s = i; a0 = ea_m0; a1 = ea_m1; }
    float mval = xl[(size_t)s * 512 + tid] + xrv + a0 * we0 + a1 * we1;
    mval = mval > 0.f ? mval : 0.2f * mval;
    float lg = wave_sum(mval * attv);
    if (c == 0) logits[h][e] = lg;
  }
  float mx = -1e30f;
  for (int e = c; e < m_cnt; e += 64) mx = fmaxf(mx, logits[h][e]);
  mx = wave_max(mx);
  float den = 0.f;
  for (int e = c; e < m_cnt; e += 64) den += expf(logits[h][e] - mx);
  den = wave_sum(den) + 1e-16f;
  float acc = 0.f;
  for (int e = 0; e < m_cnt; e++) {
    int eid = el[e];
    int s = eid < EDGES ? ei[eid] : i;
    float alpha = expf(logits[h][e] - mx) / den;
    acc += alpha * xl[(size_t)s * 512 + tid];
  }
  out[(size_t)i * 512 + tid] = acc + bias[tid];
}

// ======= MFMA block-diag MHA =======
// block = (b, h, q-quarter of 64 rows): grid 256, 4 waves x 16 q-rows.
// K, V^T staged split-bf16 in LDS; S in regs; P (den-folded) via LDS (reuses K).
__global__ __launch_bounds__(256) void mha_mfma(const float* __restrict__ qkv,
                                                float* __restrict__ o) {
  __shared__ __align__(16) u16 Ksh[2][256][72];   // 73728 B; later reused for P
  __shared__ __align__(16) u16 Vt[2][64][264];    // 67584 B  (V^T: [chan][key])
  int bid = blockIdx.x;
  int qq = bid & 3;
  int h = (bid >> 2) & 7;
  int b = bid >> 5;
  int t = threadIdx.x;
  int lane = t & 63, w = t >> 6;
  int lr = lane & 15, g = lane >> 4, kk = g * 8;
  size_t rowbase = (size_t)(b * SG) * 1536;
  const float* Kbase = qkv + rowbase + 512 + h * 64;
  const float* Vbase = qkv + rowbase + 1024 + h * 64;
  // ---- stage K (natural) and V^T (transposed), both split-bf16 ----
  for (int idx = t; idx < SG * 64; idx += 256) {
    int j = idx >> 6, c = idx & 63;
    float kv = Kbase[(size_t)j * 1536 + c];
    u16 khh = f2bf(kv);
    Ksh[0][j][c] = khh;
    Ksh[1][j][c] = f2bf(kv - bf2f(khh));
    float vv = Vbase[(size_t)j * 1536 + c];
    u16 vhh = f2bf(vv);
    Vt[0][c][j] = vhh;
    Vt[1][c][j] = f2bf(vv - bf2f(vhh));
  }
  // ---- Q fragments (this wave's 16 rows), split-bf16 in regs ----
  const float* Qrow = qkv + rowbase + (size_t)(qq * 64 + w * 16 + lr) * 1536 + h * 64;
  short8 qh[2], ql[2];
#pragma unroll
  for (int kt = 0; kt < 2; kt++) {
    float qv[8];
    *(float4*)&qv[0] = *(const float4*)&Qrow[kt * 32 + kk];
    *(float4*)&qv[4] = *(const float4*)&Qrow[kt * 32 + kk + 4];
#pragma unroll
    for (int i = 0; i < 8; i++) {
      u16 hh = f2bf(qv[i]);
      qh[kt][i] = hh;
      ql[kt][i] = f2bf(qv[i] - bf2f(hh));
    }
  }
  __syncthreads();
  // ---- phase 1: S = Q K^T (split, 3 products) ----
  f32x4 S[16];
#pragma unroll
  for (int j = 0; j < 16; j++) {
    f32x4 acc = {};
#pragma unroll
    for (int kt = 0; kt < 2; kt++) {
      short8 bh = *(const short8*)&Ksh[0][j * 16 + lr][kt * 32 + kk];
      short8 bl = *(const short8*)&Ksh[1][j * 16 + lr][kt * 32 + kk];
      acc = __builtin_amdgcn_mfma_f32_16x16x32_bf16(qh[kt], bh, acc, 0, 0, 0);
      acc = __builtin_amdgcn_mfma_f32_16x16x32_bf16(qh[kt], bl, acc, 0, 0, 0);
      acc = __builtin_amdgcn_mfma_f32_16x16x32_bf16(ql[kt], bh, acc, 0, 0, 0);
    }
    S[j] = acc;
  }
  // ---- phase 2: exact softmax per q-row; lane holds rows g*4+r, key j*16+lr ----
  float mx[4], inv[4];
#pragma unroll
  for (int r = 0; r < 4; r++) {
    float m = S[0][r];
#pragma unroll
    for (int j = 1; j < 16; j++) m = fmaxf(m, S[j][r]);
#pragma unroll
    for (int oo = 1; oo < 16; oo <<= 1) m = fmaxf(m, __shfl_xor(m, oo));
    mx[r] = m;
    float d = 0.f;
#pragma unroll
    for (int j = 0; j < 16; j++) d += __expf((S[j][r] - m) * 0.125f);
#pragma unroll
    for (int oo = 1; oo < 16; oo <<= 1) d += __shfl_xor(d, oo);
    inv[r] = 1.f / d;
  }
  __syncthreads();  // all waves done reading K before P overwrites it
  u16* Pb = &Ksh[0][0][0];  // P hi at [row*264+key], lo at +16896
  int row0 = w * 16 + g * 4;
#pragma unroll
  for (int j = 0; j < 16; j++) {
    int key = j * 16 + lr;
#pragma unroll
    for (int r = 0; r < 4; r++) {
      float p = __expf((S[j][r] - mx[r]) * 0.125f) * inv[r];
      u16 hh = f2bf(p);
      Pb[(row0 + r) * 264 + key] = hh;
      Pb[16896 + (row0 + r) * 264 + key] = f2bf(p - bf2f(hh));
    }
  }
  __syncthreads();
  // ---- phase 3: O = P V (split) ----
  f32x4 Oacc[4] = {};
#pragma unroll
  for (int kt = 0; kt < 8; kt++) {
    short8 pah = *(const short8*)&Pb[(w * 16 + lr) * 264 + kt * 32 + kk];
    short8 pal = *(const short8*)&Pb[16896 + (w * 16 + lr) * 264 + kt * 32 + kk];
#pragma unroll
    for (int nf = 0; nf < 4; nf++) {
      short8 vh = *(const short8*)&Vt[0][nf * 16 + lr][kt * 32 + kk];
      short8 vl = *(const short8*)&Vt[1][nf * 16 + lr][kt * 32 + kk];
      Oacc[nf] = __builtin_amdgcn_mfma_f32_16x16x32_bf16(pah, vh, Oacc[nf], 0, 0, 0);
      Oacc[nf] = __builtin_amdgcn_mfma_f32_16x16x32_bf16(pah, vl, Oacc[nf], 0, 0, 0);
      Oacc[nf] = __builtin_amdgcn_mfma_f32_16x16x32_bf16(pal, vh, Oacc[nf], 0, 0, 0);
    }
  }
  float* obase = o + (size_t)(b * SG + qq * 64 + w * 16 + g * 4) * 512 + h * 64;
#pragma unroll
  for (int nf = 0; nf < 4; nf++)
#pragma unroll
    for (int r = 0; r < 4; r++)
      obase[(size_t)r * 512 + nf * 16 + lr] = Oacc[nf][r];
}

__global__ void combine_kernel(const float* __restrict__ loc, const float* __restrict__ gl,
                               const float* __restrict__ ap, int l, float* __restrict__ comb) {
  int idx = blockIdx.x * 256 + threadIdx.x;
  float a = 1.f / (1.f + expf(-ap[l]));
  comb[idx] = a * loc[idx] + (1.f - a) * gl[idx];
}

__global__ __launch_bounds__(512) void head_kernel(
    const float* __restrict__ hfin, const int* __restrict__ cni,
    const float* __restrict__ W1, const float* __restrict__ b1,
    const float* __restrict__ g, const float* __restrict__ bt,
    const float* __restrict__ W2, const float* __restrict__ b2,
    float* __restrict__ out) {
  __shared__ float emb[512];
  __shared__ float z[512];
  __shared__ float sh[8];
  __shared__ float lg[ACT_N];
  int t = threadIdx.x;
  int idx = cni[0];
  emb[t] = hfin[(size_t)idx * 512 + t];
  __syncthreads();
  float s = b1[t];
  for (int k = 0; k < 512; k++) s += emb[k] * W1[(size_t)k * 512 + t];
  float sum = blk_sum(s, sh);
  float mu = sum * (1.f / 512.f);
  float d = s - mu;
  float var = blk_sum(d * d, sh) * (1.f / 512.f);
  z[t] = gelu_f(d * rsqrtf(var + 1e-5f) * g[t] + bt[t]);
  __syncthreads();
  if (t < ACT_N) {
    float l = b2[t];
    for (int k = 0; k < 512; k++) l += z[k] * W2[k * ACT_N + t];
    lg[t] = l;
  }
  __syncthreads();
  if (t == 0) {
    float m2 = lg[0];
    for (int a = 1; a < ACT_N; a++) m2 = fmaxf(m2, lg[a]);
    float den = 0.f;
    float ex[ACT_N];
    for (int a = 0; a < ACT_N; a++) { ex[a] = expf(lg[a] - m2); den += ex[a]; }
    for (int a = 0; a < ACT_N; a++) {
      out[a] = lg[a];
      out[ACT_N + a] = ex[a] / den;
    }
  }
}

extern "C" void kernel_launch(void* const* d_in, const int* in_sizes, int n_in,
                              void* d_out, int out_size, void* d_ws, size_t ws_size,
                              hipStream_t stream) {
  const float* x        = (const float*)d_in[0];
  const float* eattr    = (const float*)d_in[1];
  const float* rwse_W   = (const float*)d_in[2];
  const float* rwse_b   = (const float*)d_in[3];
  const float* rwse_g   = (const float*)d_in[4];
  const float* rwse_bt  = (const float*)d_in[5];
  const float* np_W     = (const float*)d_in[6];
  const float* np_b     = (const float*)d_in[7];
  const float* np_g     = (const float*)d_in[8];
  const float* np_bt    = (const float*)d_in[9];
  const float* gat_Wl   = (const float*)d_in[10];
  const float* gat_bl   = (const float*)d_in[11];
  const float* gat_Wr   = (const float*)d_in[12];
  const float* gat_br   = (const float*)d_in[13];
  const float* gat_We   = (const float*)d_in[14];
  const float* gat_att  = (const float*)d_in[15];
  const float* gat_bias = (const float*)d_in[16];
  const float* n1_g = (const float*)d_in[17];
  const float* n1_b = (const float*)d_in[18];
  const float* mha_inW  = (const float*)d_in[19];
  const float* mha_inb  = (const float*)d_in[20];
  const float* mha_outW = (const float*)d_in[21];
  const float* mha_outb = (const float*)d_in[22];
  const float* alpha_p  = (const float*)d_in[23];
  const float* n2_g = (const float*)d_in[24];
  const float* n2_b = (const float*)d_in[25];
  const float* ffn_W1 = (const float*)d_in[26];
  const float* ffn_b1 = (const float*)d_in[27];
  const float* ffn_W2 = (const float*)d_in[28];
  const float* ffn_b2 = (const float*)d_in[29];
  const float* n3_g = (const float*)d_in[30];
  const float* n3_b = (const float*)d_in[31];
  const float* ah_W1 = (const float*)d_in[32];
  const float* ah_b1 = (const float*)d_in[33];
  const float* ah_g  = (const float*)d_in[34];
  const float* ah_bt = (const float*)d_in[35];
  const float* ah_W2 = (const float*)d_in[36];
  const float* ah_b2 = (const float*)d_in[37];
  const int* edge_index = (const int*)d_in[38];
  const int* cni        = (const int*)d_in[39];
  (void)in_sizes; (void)n_in; (void)out_size; (void)ws_size;

  char* wsp = (char*)d_ws;
  size_t off = 0;
  auto alloc = [&](size_t bytes) -> char* {
    char* p = wsp + off;
    off += (bytes + 255) & ~(size_t)255;
    return p;
  };
  const size_t NNb = (size_t)NODES * NODES * 4;
  char* arena = alloc(3 * NNb);
  float* P2 = (float*)arena;
  float* P3 = (float*)(arena + NNb);
  float* P4 = (float*)(arena + 2 * NNb);
  u16* Ah = (u16*)arena;
  u16* Al = (u16*)(arena + (size_t)NODES * 4224 * 2);
  float* ffmid = (float*)(arena + (size_t)NODES * 4224 * 2 + (size_t)NODES * 2048 * 2);
  float* qkvb  = (float*)(arena + (size_t)NODES * 4224 * 4);
  u16* Bh = (u16*)alloc((size_t)4224 * 512 * 2);
  u16* Bl = (u16*)alloc((size_t)4224 * 512 * 2);
  float* rwse = (float*)alloc((size_t)NODES * 8 * 4);
  float* rbuf = (float*)alloc((size_t)NODES * H4C * 4);
  float* h0   = (float*)alloc((size_t)NODES * 512 * 4);
  float* h1   = (float*)alloc((size_t)NODES * 512 * 4);
  float* xl   = (float*)alloc((size_t)NODES * 512 * 4);
  float* xr   = (float*)alloc((size_t)NODES * 512 * 4);
  float* gout = (float*)alloc((size_t)NODES * 512 * 4);
  float* attO = (float*)alloc((size_t)NODES * 512 * 4);
  float* gbuf = (float*)alloc((size_t)NODES * 512 * 4);
  float* comb = (float*)alloc((size_t)NODES * 512 * 4);
  u32* bits  = (u32*)alloc((size_t)NODES * 64 * 4);
  int* scnt  = (int*)alloc((size_t)NODES * 4);
  int* slist = (int*)alloc((size_t)NODES * SCAP * 4);
  int* cnt   = (int*)alloc((size_t)NODES * 4);
  int* elist = (int*)alloc((size_t)NODES * ECAP * 4);
  float* easum = (float*)alloc(8);
  float* pbuf  = (float*)alloc((size_t)8 * NODES * 4 * 4);
  float* ffb = xl;

  // ---- RWSE sparse path ----
  hipMemsetAsync(bits, 0, (size_t)NODES * 64 * 4, stream);
  hipMemsetAsync(scnt, 0, NODES * 4, stream);
  build_csr<<<EDGES / 256, 256, 0, stream>>>(edge_index, bits, scnt, slist);
  diag_T<<<NODES / 256, 256, 0, stream>>>(bits, scnt, rwse);
  spmm_sq<<<NODES, 256, 0, stream>>>(scnt, slist, P2);
  diag_copy<<<NODES / 256, 256, 0, stream>>>(P2, rwse, 1);
  spmm_gather<<<NODES, 256, 0, stream>>>(scnt, slist, P2, P3);
  diag_copy<<<NODES / 256, 256, 0, stream>>>(P3, rwse, 2);
  spmm_gather<<<NODES, 256, 0, stream>>>(scnt, slist, P3, P4);
  diag_copy<<<NODES / 256, 256, 0, stream>>>(P4, rwse, 3);
  diag_tiled<<<dim3(NODES / 64, 8), 256, 0, stream>>>(P2, P3, P4, pbuf);
  diag_reduce<<<NODES / 256, 256, 0, stream>>>(pbuf, rwse);
  rwse_proj<<<NODES, 128, 0, stream>>>(rwse, rwse_W, rwse_b, rwse_g, rwse_bt, rbuf);

  // ---- node projection ----
  conv_A<<<(NODES * DIN + 255) / 256, 256, 0, stream>>>(x, Ah, Al, NODES * DIN, DIN, 4224, 0);
  conv_A<<<(NODES * H4C + 255) / 256, 256, 0, stream>>>(rbuf, Ah, Al, NODES * H4C, H4C, 4224, DIN);
  pack_B<<<(4224 * 512 + 255) / 256, 256, 0, stream>>>(np_W, Bh, Bl, 4224, 512);
  gemm_split<<<dim3(512 / 64, NODES / 64), 256, 0, stream>>>(Ah, Al, Bh, Bl, h0, np_b,
                                                             NODES, 4224, 512, 0, 0);
  ln512<<<NODES, 256, 0, stream>>>(h0, nullptr, np_g, np_bt, h1, 1);

  // ---- GAT CSR + edge-attr mean ----
  hipMemsetAsync(cnt, 0, NODES * 4, stream);
  fill_edges<<<(EDGES + NODES) / 256, 256, 0, stream>>>(edge_index, cnt, elist);
  hipMemsetAsync(easum, 0, 8, stream);
  ea_reduce<<<64, 256, 0, stream>>>(eattr, easum);

  float* hin = h1;
  float* hout = h0;
  dim3 g512(512 / 64, NODES / 64);
  dim3 g1536(1536 / 64, NODES / 64);
  dim3 g2048(2048 / 64, NODES / 64);
  for (int l = 0; l < LLAY; l++) {
    conv_A<<<(NODES * 512 + 255) / 256, 256, 0, stream>>>(hin, Ah, Al, NODES * 512, 512, 512, 0);
    pack_B<<<(512 * 512 + 255) / 256, 256, 0, stream>>>(gat_Wl + (size_t)l * 512 * 512, Bh, Bl, 512, 512);
    gemm_split<<<g512, 256, 0, stream>>>(Ah, Al, Bh, Bl, xl, gat_bl + l * 512, NODES, 512, 512, 0, 0);
    pack_B<<<(512 * 512 + 255) / 256, 256, 0, stream>>>(gat_Wr + (size_t)l * 512 * 512, Bh, Bl, 512, 512);
    gemm_split<<<g512, 256, 0, stream>>>(Ah, Al, Bh, Bl, xr, gat_br + l * 512, NODES, 512, 512, 0, 0);
    pack_B<<<(512 * 1536 + 255) / 256, 256, 0, stream>>>(mha_inW + (size_t)l * 512 * 1536, Bh, Bl, 512, 1536);
    gemm_split<<<g1536, 256, 0, stream>>>(Ah, Al, Bh, Bl, qkvb, mha_inb + l * 1536, NODES, 512, 1536, 0, 0);

    gat_kernel<<<NODES, 512, 0, stream>>>(xl, xr, eattr, easum, gat_We + l * 1024,
                                          gat_att + l * 512, gat_bias + l * 512,
                                          cnt, elist, edge_index, gout);
    ln512<<<NODES, 256, 0, stream>>>(gout, nullptr, n1_g + l * 512, n1_b + l * 512, gout, 0);

    mha_mfma<<<BG * NHEAD * 4, 256, 0, stream>>>(qkvb, attO);
    conv_A<<<(NODES * 512 + 255) / 256, 256, 0, stream>>>(attO, Ah, Al, NODES * 512, 512, 512, 0);
    pack_B<<<(512 * 512 + 255) / 256, 256, 0, stream>>>(mha_outW + (size_t)l * 512 * 512, Bh, Bl, 512, 512);
    gemm_split<<<g512, 256, 0, stream>>>(Ah, Al, Bh, Bl, gbuf, mha_outb + l * 512, NODES, 512, 512, 0, 0);
    ln512<<<NODES, 256, 0, stream>>>(gbuf, nullptr, n2_g + l * 512, n2_b + l * 512, gbuf, 0);

    combine_kernel<<<NODES * 512 / 256, 256, 0, stream>>>(gout, gbuf, alpha_p, l, comb);

    conv_A<<<(NODES * 512 + 255) / 256, 256, 0, stream>>>(comb, Ah, Al, NODES * 512, 512, 512, 0);
    pack_B<<<(512 * 2048 + 255) / 256, 256, 0, stream>>>(ffn_W1 + (size_t)l * 512 * 2048, Bh, Bl, 512, 2048);
    gemm_split<<<g2048, 256, 0, stream>>>(Ah, Al, Bh, Bl, ffmid, ffn_b1 + l * 2048, NODES, 512, 2048, 0, 1);
    conv_A<<<(NODES * 2048 + 255) / 256, 256, 0, stream>>>(ffmid, Ah, Al, NODES * 2048, 2048, 2048, 0);
    pack_B<<<(2048 * 512 + 255) / 256, 256, 0, stream>>>(ffn_W2 + (size_t)l * 2048 * 512, Bh, Bl, 2048, 512);
    gemm_split<<<g512, 256, 0, stream>>>(Ah, Al, Bh, Bl, ffb, ffn_b2 + l * 512, NODES, 2048, 512, 0, 0);
    ln512<<<NODES, 256, 0, stream>>>(ffb, comb, n3_g + l * 512, n3_b + l * 512, hout, 0);
    float* tmp = hin; hin = hout; hout = tmp;
  }

  head_kernel<<<1, 512, 0, stream>>>(hin, cni, ah_W1, ah_b1, ah_g, ah_bt, ah_W2,
                                     ah_b2, (float*)d_out);
}

// Round 5
// 754.631 us; speedup vs baseline: 3.2332x; 1.2118x over previous
//
#include <hip/hip_runtime.h>
#include <math.h>

constexpr int NODES = 2048;
constexpr int BG = 8;
constexpr int SG = 256;
constexpr int DIN = 4096;
constexpr int NHEAD = 8;
constexpr int EDGES = 32768;
constexpr int LLAY = 2;
constexpr int ACT_N = 5;
constexpr int H4C = 128;
constexpr int ECAP = 192;   // per-dst edge list capacity (GAT)
constexpr int SCAP = 96;    // per-src dedup'd neighbor capacity (RWSE)

typedef unsigned short u16;
typedef unsigned int u32;
typedef unsigned long long u64;
typedef short short8 __attribute__((ext_vector_type(8)));
typedef float f32x4 __attribute__((ext_vector_type(4)));

__device__ __forceinline__ float wave_sum(float v) {
#pragma unroll
  for (int o = 32; o; o >>= 1) v += __shfl_xor(v, o);
  return v;
}
__device__ __forceinline__ float wave_max(float v) {
#pragma unroll
  for (int o = 32; o; o >>= 1) v = fmaxf(v, __shfl_xor(v, o));
  return v;
}
__device__ __forceinline__ float blk_sum(float v, float* sh) {
  v = wave_sum(v);
  int nw = blockDim.x >> 6;
  __syncthreads();
  if ((threadIdx.x & 63) == 0) sh[threadIdx.x >> 6] = v;
  __syncthreads();
  float s = 0.f;
  for (int k = 0; k < nw; k++) s += sh[k];
  return s;
}
__device__ __forceinline__ float gelu_f(float x) {
  return 0.5f * x * (1.f + erff(x * 0.70710678118654752f));
}
__device__ __forceinline__ u16 f2bf(float x) {  // round-to-nearest-even bf16
  u32 u = __float_as_uint(x);
  return (u16)((u + 0x7FFFu + ((u >> 16) & 1u)) >> 16);
}
__device__ __forceinline__ float bf2f(u16 h) { return __uint_as_float(((u32)h) << 16); }

// ================= RWSE (sparse path) =================
__global__ void build_csr(const int* __restrict__ ei, u32* __restrict__ bits,
                          int* __restrict__ scnt, int* __restrict__ slist) {
  int e = blockIdx.x * 256 + threadIdx.x;
  if (e < EDGES) {
    int s = ei[e], d = ei[EDGES + e];
    u32 m = 1u << (d & 31);
    u32 old = atomicOr(&bits[s * 64 + (d >> 5)], m);
    if (!(old & m)) {
      int p = atomicAdd(&scnt[s], 1);
      if (p < SCAP) slist[s * SCAP + p] = d;
    }
  }
}

__global__ void diag_T(const u32* __restrict__ bits, const int* __restrict__ scnt,
                       float* __restrict__ rwse) {
  int i = blockIdx.x * 256 + threadIdx.x;
  if (i < NODES) {
    int deg = min(scnt[i], SCAP);
    int self = (bits[i * 64 + (i >> 5)] >> (i & 31)) & 1;
    rwse[(size_t)i * 8 + 0] = (self && deg > 0) ? 1.f / (float)deg : 0.f;
  }
}

__global__ __launch_bounds__(256) void spmm_sq(const int* __restrict__ scnt,
                                               const int* __restrict__ slist,
                                               float* __restrict__ P2) {
  int i = blockIdx.x, t = threadIdx.x;
  __shared__ float row[NODES];
  for (int c = t; c < NODES; c += 256) row[c] = 0.f;
  __syncthreads();
  int di = min(scnt[i], SCAP);
  float wi = di > 0 ? 1.f / (float)di : 0.f;
  for (int jj = 0; jj < di; jj++) {
    int j = slist[i * SCAP + jj];
    int dj = min(scnt[j], SCAP);
    if (dj == 0) continue;
    float w = wi / (float)dj;
    for (int kk = t; kk < dj; kk += 256) atomicAdd(&row[slist[j * SCAP + kk]], w);
  }
  __syncthreads();
  for (int c = t; c < NODES; c += 256) P2[(size_t)i * NODES + c] = row[c];
}

__global__ __launch_bounds__(256) void spmm_gather(const int* __restrict__ scnt,
                                                   const int* __restrict__ slist,
                                                   const float* __restrict__ P,
                                                   float* __restrict__ Q) {
  int i = blockIdx.x, t = threadIdx.x;
  __shared__ int nb[SCAP];
  int di = min(scnt[i], SCAP);
  for (int c = t; c < di; c += 256) nb[c] = slist[i * SCAP + c];
  __syncthreads();
  float wi = di > 0 ? 1.f / (float)di : 0.f;
  for (int c = t; c < NODES; c += 256) {
    float s = 0.f;
    for (int jj = 0; jj < di; jj++) s += P[(size_t)nb[jj] * NODES + c];
    Q[(size_t)i * NODES + c] = s * wi;
  }
}

__global__ void diag_copy(const float* __restrict__ P, float* __restrict__ rwse, int col) {
  int i = blockIdx.x * 256 + threadIdx.x;
  if (i < NODES) rwse[(size_t)i * 8 + col] = P[(size_t)i * (NODES + 1)];
}

// fused diag dots, tiled+coalesced
__global__ __launch_bounds__(256) void diag_tiled(const float* __restrict__ P2,
                                                  const float* __restrict__ P3,
                                                  const float* __restrict__ P4,
                                                  float* __restrict__ pbuf) {
  __shared__ float r2[64][65], r3[64][65], r4[64][65], c3[64][65], c4[64][65];
  __shared__ float red[4][4][64];
  int t = threadIdx.x;
  int i0 = blockIdx.x * 64;
  int js = blockIdx.y;
  int lo = t & 63, hi = t >> 6;
  float d5 = 0, d6 = 0, d7 = 0, d8 = 0;
  for (int jc = 0; jc < 4; jc++) {
    int j0 = js * 256 + jc * 64;
    __syncthreads();
#pragma unroll
    for (int r = 0; r < 16; r++) {
      int a = hi * 16 + r;
      r2[a][lo] = P2[(size_t)(i0 + a) * NODES + j0 + lo];
      r3[a][lo] = P3[(size_t)(i0 + a) * NODES + j0 + lo];
      r4[a][lo] = P4[(size_t)(i0 + a) * NODES + j0 + lo];
      c3[a][lo] = P3[(size_t)(j0 + a) * NODES + i0 + lo];
      c4[a][lo] = P4[(size_t)(j0 + a) * NODES + i0 + lo];
    }
    __syncthreads();
#pragma unroll
    for (int r = 0; r < 16; r++) {
      int jj = hi * 16 + r;
      float p3c = c3[jj][lo], p4c = c4[jj][lo];
      d5 += r2[lo][jj] * p3c;
      d6 += r3[lo][jj] * p3c;
      d7 += r3[lo][jj] * p4c;
      d8 += r4[lo][jj] * p4c;
    }
  }
  red[0][hi][lo] = d5; red[1][hi][lo] = d6; red[2][hi][lo] = d7; red[3][hi][lo] = d8;
  __syncthreads();
  if (hi == 0) {
    int i = i0 + lo;
#pragma unroll
    for (int v = 0; v < 4; v++) {
      float s = red[v][0][lo] + red[v][1][lo] + red[v][2][lo] + red[v][3][lo];
      pbuf[((size_t)js * NODES + i) * 4 + v] = s;
    }
  }
}

__global__ void diag_reduce(const float* __restrict__ pbuf, float* __restrict__ rwse) {
  int i = blockIdx.x * 256 + threadIdx.x;
  if (i >= NODES) return;
#pragma unroll
  for (int v = 0; v < 4; v++) {
    float s = 0.f;
    for (int js = 0; js < 8; js++) s += pbuf[((size_t)js * NODES + i) * 4 + v];
    rwse[(size_t)i * 8 + 4 + v] = s;
  }
}

// ================= weight packing: frag-tile order =================
// W [K][N] row-major -> u16 idx:
//  (((ktile*(N/64)+ntile)*8 + j*2 + ks)*64 + g*16 + lr)*8 + e
//  ktile=k>>6, ks=(k>>5)&1, g=(k>>3)&3, e=k&7; ntile=n>>6, j=(n>>4)&3, lr=n&15
struct PackArgs {
  const float* src[13];
  u64 off[13];
  u64 cum[14];
  int N[13];
};

__global__ __launch_bounds__(256) void pack_all(PackArgs pa, u16* __restrict__ Bh,
                                                u16* __restrict__ Bl) {
  u64 total = pa.cum[13];
  for (u64 idx = (u64)blockIdx.x * 256 + threadIdx.x; idx < total;
       idx += (u64)gridDim.x * 256) {
    int s = 0;
    while (idx >= pa.cum[s + 1]) s++;
    u64 rel = idx - pa.cum[s];
    int N = pa.N[s];
    u32 k = (u32)(rel / (u32)N);
    u32 n = (u32)(rel - (u64)k * N);
    float v = pa.src[s][rel];
    u64 fi = pa.off[s] +
             ((((u64)(k >> 6) * (N >> 6) + (n >> 6)) * 8 + ((n >> 4) & 3) * 2 +
               ((k >> 5) & 1)) * 64 + ((k >> 3) & 3) * 16 + (n & 15)) * 8 + (k & 7);
    u16 h = f2bf(v);
    Bh[fi] = h;
    Bl[fi] = f2bf(v - bf2f(h));
  }
}

// ================= split-bf16 MFMA GEMM, fp32 A =================
// C[M][N] = split(A fp32)[M][K] @ packedB(hi/lo)[K][N], 3-product split.
// 64x64 tile, BK=64, 4 waves, frag-contiguous LDS, reg prefetch, XCD swizzle.
__device__ __forceinline__ void splitA8(const float* __restrict__ p, short8& h8,
                                        short8& l8) {
  float4 v0 = *(const float4*)p;
  float4 v1 = *(const float4*)(p + 4);
  float v[8] = {v0.x, v0.y, v0.z, v0.w, v1.x, v1.y, v1.z, v1.w};
#pragma unroll
  for (int i = 0; i < 8; i++) {
    u16 h = f2bf(v[i]);
    h8[i] = (short)h;
    l8[i] = (short)f2bf(v[i] - bf2f(h));
  }
}

__global__ __launch_bounds__(256) void gemm_af(
    const float* __restrict__ A, const float* __restrict__ A2, int Ksplit,
    const u16* __restrict__ Bh, const u16* __restrict__ Bl,
    float* __restrict__ C, const float* __restrict__ bias,
    int M, int K, int N, int act) {
  __shared__ __align__(16) u16 LA[2][4096];
  __shared__ __align__(16) u16 LB[2][4096];
  int gn = N >> 6;
  int nwg = (M >> 6) * gn;
  int q = nwg >> 3;
  int flat = blockIdx.x;
  int virt = (flat & 7) * q + (flat >> 3);     // bijective XCD-contiguous remap
  int bm = (virt / gn) << 6, bn = (virt % gn) << 6;
  int t = threadIdx.x;
  int lane = t & 63, w = t >> 6;
  int wm = (w >> 1) << 5, wn = (w & 1) << 5;
  // staging units u = t, t+256: row r=u>>3, colbase c8=(u&7)*8
  int r0 = t >> 3, r1 = r0 + 32;
  int c8 = (t & 7) << 3;
  int ks_s = (t >> 2) & 1, g_s = t & 3;
  int da0 = (((r0 >> 4) * 2 + ks_s) << 9) + (((r0 & 15) * 4 + g_s) << 3);
  int da1 = ((((r1 >> 4)) * 2 + ks_s) << 9) + (((r1 & 15) * 4 + g_s) << 3);
  int db0 = t * 8, db1 = (t + 256) * 8;
  int A2stride = K - Ksplit;
  size_t btile = (size_t)(bn >> 6) * 4096;
  size_t bstep = (size_t)gn * 4096;

  short8 pah0, pal0, pah1, pal1, pbh0, pbl0, pbh1, pbl1;
  auto loadA = [&](int kt, int r, short8& h, short8& l) {
    int k = kt + c8;
    int row = bm + r;
    const float* p = (k < Ksplit) ? A + (size_t)row * Ksplit + k
                                  : A2 + (size_t)row * A2stride + (k - Ksplit);
    splitA8(p, h, l);
  };
  loadA(0, r0, pah0, pal0);
  loadA(0, r1, pah1, pal1);
  pbh0 = *(const short8*)(Bh + btile + db0);
  pbl0 = *(const short8*)(Bl + btile + db0);
  pbh1 = *(const short8*)(Bh + btile + db1);
  pbl1 = *(const short8*)(Bl + btile + db1);

  f32x4 acc[2][2] = {};
  int lr = lane & 15, lg = lane >> 4;
  int raoff = (lr * 4 + lg) << 3;
  int rboff = lane << 3;

  for (int kt = 0; kt < K; kt += 64) {
    __syncthreads();
    *(short8*)&LA[0][da0] = pah0;
    *(short8*)&LA[1][da0] = pal0;
    *(short8*)&LA[0][da1] = pah1;
    *(short8*)&LA[1][da1] = pal1;
    *(short8*)&LB[0][db0] = pbh0;
    *(short8*)&LB[1][db0] = pbl0;
    *(short8*)&LB[0][db1] = pbh1;
    *(short8*)&LB[1][db1] = pbl1;
    __syncthreads();
    if (kt + 64 < K) {
      btile += bstep;
      loadA(kt + 64, r0, pah0, pal0);
      loadA(kt + 64, r1, pah1, pal1);
      pbh0 = *(const short8*)(Bh + btile + db0);
      pbl0 = *(const short8*)(Bl + btile + db0);
      pbh1 = *(const short8*)(Bh + btile + db1);
      pbl1 = *(const short8*)(Bl + btile + db1);
    }
#pragma unroll
    for (int ks = 0; ks < 2; ks++) {
      short8 ah[2], al[2], bh[2], bl[2];
#pragma unroll
      for (int i = 0; i < 2; i++) {
        int ba = ((((wm >> 4) + i) * 2 + ks) << 9) + raoff;
        ah[i] = *(const short8*)&LA[0][ba];
        al[i] = *(const short8*)&LA[1][ba];
        int bb = ((((wn >> 4) + i) * 2 + ks) << 9) + rboff;
        bh[i] = *(const short8*)&LB[0][bb];
        bl[i] = *(const short8*)&LB[1][bb];
      }
#pragma unroll
      for (int i = 0; i < 2; i++)
#pragma unroll
        for (int j = 0; j < 2; j++) {
          acc[i][j] = __builtin_amdgcn_mfma_f32_16x16x32_bf16(ah[i], bh[j], acc[i][j], 0, 0, 0);
          acc[i][j] = __builtin_amdgcn_mfma_f32_16x16x32_bf16(ah[i], bl[j], acc[i][j], 0, 0, 0);
          acc[i][j] = __builtin_amdgcn_mfma_f32_16x16x32_bf16(al[i], bh[j], acc[i][j], 0, 0, 0);
        }
    }
  }
  int row0 = (lane >> 4) * 4;
#pragma unroll
  for (int i = 0; i < 2; i++)
#pragma unroll
    for (int j = 0; j < 2; j++) {
      int n = bn + wn + j * 16 + lr;
      float bv = bias ? bias[n] : 0.f;
#pragma unroll
      for (int r = 0; r < 4; r++) {
        int m = bm + wm + i * 16 + row0 + r;
        float v = acc[i][j][r] + bv;
        if (act) v = gelu_f(v);
        C[(size_t)m * N + n] = v;
      }
    }
}

// ================= small fused kernels =================
__global__ __launch_bounds__(128) void rwse_proj(const float* __restrict__ rwse,
                                                 const float* __restrict__ W,
                                                 const float* __restrict__ bb,
                                                 const float* __restrict__ g,
                                                 const float* __restrict__ bt,
                                                 float* __restrict__ r) {
  int i = blockIdx.x, j = threadIdx.x;
  float s = bb[j];
#pragma unroll
  for (int k = 0; k < 8; k++) s += rwse[(size_t)i * 8 + k] * W[k * H4C + j];
  __shared__ float sh[8];
  float sum = blk_sum(s, sh);
  float mu = sum * (1.f / 128.f);
  float d = s - mu;
  float var = blk_sum(d * d, sh) * (1.f / 128.f);
  r[(size_t)i * H4C + j] = gelu_f(d * rsqrtf(var + 1e-5f) * g[j] + bt[j]);
}

__global__ __launch_bounds__(256) void ln512(const float* __restrict__ x,
                                             const float* __restrict__ res,
                                             const float* __restrict__ g,
                                             const float* __restrict__ b,
                                             float* __restrict__ y, int do_gelu) {
  int i = blockIdx.x, t = threadIdx.x;
  size_t base = (size_t)i * 512;
  float v0 = x[base + t], v1 = x[base + 256 + t];
  if (res) { v0 += res[base + t]; v1 += res[base + 256 + t]; }
  __shared__ float sh[8];
  float s = blk_sum(v0 + v1, sh);
  float mu = s * (1.f / 512.f);
  float d0 = v0 - mu, d1 = v1 - mu;
  float var = blk_sum(d0 * d0 + d1 * d1, sh) * (1.f / 512.f);
  float rstd = rsqrtf(var + 1e-5f);
  float o0 = d0 * rstd * g[t] + b[t];
  float o1 = d1 * rstd * g[t + 256] + b[t + 256];
  if (do_gelu) { o0 = gelu_f(o0); o1 = gelu_f(o1); }
  y[base + t] = o0;
  y[base + 256 + t] = o1;
}

__global__ void fill_edges(const int* __restrict__ ei, int* __restrict__ cnt,
                           int* __restrict__ elist) {
  int e = blockIdx.x * 256 + threadIdx.x;
  if (e < EDGES + NODES) {
    int d = e < EDGES ? ei[EDGES + e] : e - EDGES;
    int p = atomicAdd(&cnt[d], 1);
    if (p < ECAP) elist[(size_t)d * ECAP + p] = e;
  }
}

__global__ void ea_reduce(const float* __restrict__ ea, float* __restrict__ sums) {
  int tid = blockIdx.x * blockDim.x + threadIdx.x;
  int stride = gridDim.x * blockDim.x;
  float s0 = 0.f, s1 = 0.f;
  for (int e = tid; e < EDGES; e += stride) { s0 += ea[2 * e]; s1 += ea[2 * e + 1]; }
  s0 = wave_sum(s0);
  s1 = wave_sum(s1);
  if ((threadIdx.x & 63) == 0) { atomicAdd(&sums[0], s0); atomicAdd(&sums[1], s1); }
}

__global__ __launch_bounds__(512) void gat_kernel(
    const float* __restrict__ xl, const float* __restrict__ xr,
    const float* __restrict__ eattr, const float* __restrict__ easum,
    const float* __restrict__ We, const float* __restrict__ att,
    const float* __restrict__ bias, const int* __restrict__ cnt,
    const int* __restrict__ elist, const int* __restrict__ ei,
    float* __restrict__ out) {
  int i = blockIdx.x;
  int tid = threadIdx.x;
  int h = tid >> 6, c = tid & 63;
  int m_cnt = cnt[i];
  if (m_cnt > ECAP) m_cnt = ECAP;
  const float inv_e = 1.f / (float)EDGES;
  float we0 = We[tid], we1 = We[512 + tid];
  float attv = att[tid];
  float xrv = xr[(size_t)i * 512 + tid];
  float ea_m0 = easum[0] * inv_e, ea_m1 = easum[1] * inv_e;
  __shared__ float logits[NHEAD][ECAP];
  const int* el = elist + (size_t)i * ECAP;
  for (int e = 0; e < m_cnt; e++) {
    int eid = el[e];
    int s;
    float a0, a1;
    if (eid < EDGES) { s = ei[eid]; a0 = eattr[2 * eid]; a1 = eattr[2 * eid + 1]; }
    else { s = i; a0 = ea_m0; a1 = ea_m1; }
    float mval = xl[(size_t)s * 512 + tid] + xrv + a0 * we0 + a1 * we1;
    mval = mval > 0.f ? mval : 0.2f * mval;
    float lg = wave_sum(mval * attv);
    if (c == 0) logits[h][e] = lg;
  }
  float mx = -1e30f;
  for (int e = c; e < m_cnt; e += 64) mx = fmaxf(mx, logits[h][e]);
  mx = wave_max(mx);
  float den = 0.f;
  for (int e = c; e < m_cnt; e += 64) den += expf(logits[h][e] - mx);
  den = wave_sum(den) + 1e-16f;
  float acc = 0.f;
  for (int e = 0; e < m_cnt; e++) {
    int eid = el[e];
    int s = eid < EDGES ? ei[eid] : i;
    float alpha = expf(logits[h][e] - mx) / den;
    acc += alpha * xl[(size_t)s * 512 + tid];
  }
  out[(size_t)i * 512 + tid] = acc + bias[tid];
}

// ======= MFMA block-diag MHA (r4, validated) =======
__global__ __launch_bounds__(256) void mha_mfma(const float* __restrict__ qkv,
                                                float* __restrict__ o) {
  __shared__ __align__(16) u16 Ksh[2][256][72];
  __shared__ __align__(16) u16 Vt[2][64][264];
  int bid = blockIdx.x;
  int qq = bid & 3;
  int h = (bid >> 2) & 7;
  int b = bid >> 5;
  int t = threadIdx.x;
  int lane = t & 63, w = t >> 6;
  int lr = lane & 15, g = lane >> 4, kk = g * 8;
  size_t rowbase = (size_t)(b * SG) * 1536;
  const float* Kbase = qkv + rowbase + 512 + h * 64;
  const float* Vbase = qkv + rowbase + 1024 + h * 64;
  for (int idx = t; idx < SG * 64; idx += 256) {
    int j = idx >> 6, c = idx & 63;
    float kv = Kbase[(size_t)j * 1536 + c];
    u16 khh = f2bf(kv);
    Ksh[0][j][c] = khh;
    Ksh[1][j][c] = f2bf(kv - bf2f(khh));
    float vv = Vbase[(size_t)j * 1536 + c];
    u16 vhh = f2bf(vv);
    Vt[0][c][j] = vhh;
    Vt[1][c][j] = f2bf(vv - bf2f(vhh));
  }
  const float* Qrow = qkv + rowbase + (size_t)(qq * 64 + w * 16 + lr) * 1536 + h * 64;
  short8 qh[2], ql[2];
#pragma unroll
  for (int kt = 0; kt < 2; kt++) {
    float qv[8];
    *(float4*)&qv[0] = *(const float4*)&Qrow[kt * 32 + kk];
    *(float4*)&qv[4] = *(const float4*)&Qrow[kt * 32 + kk + 4];
#pragma unroll
    for (int i = 0; i < 8; i++) {
      u16 hh = f2bf(qv[i]);
      qh[kt][i] = hh;
      ql[kt][i] = f2bf(qv[i] - bf2f(hh));
    }
  }
  __syncthreads();
  f32x4 S[16];
#pragma unroll
  for (int j = 0; j < 16; j++) {
    f32x4 acc = {};
#pragma unroll
    for (int kt = 0; kt < 2; kt++) {
      short8 bh = *(const short8*)&Ksh[0][j * 16 + lr][kt * 32 + kk];
      short8 bl = *(const short8*)&Ksh[1][j * 16 + lr][kt * 32 + kk];
      acc = __builtin_amdgcn_mfma_f32_16x16x32_bf16(qh[kt], bh, acc, 0, 0, 0);
      acc = __builtin_amdgcn_mfma_f32_16x16x32_bf16(qh[kt], bl, acc, 0, 0, 0);
      acc = __builtin_amdgcn_mfma_f32_16x16x32_bf16(ql[kt], bh, acc, 0, 0, 0);
    }
    S[j] = acc;
  }
  float mx[4], inv[4];
#pragma unroll
  for (int r = 0; r < 4; r++) {
    float m = S[0][r];
#pragma unroll
    for (int j = 1; j < 16; j++) m = fmaxf(m, S[j][r]);
#pragma unroll
    for (int oo = 1; oo < 16; oo <<= 1) m = fmaxf(m, __shfl_xor(m, oo));
    mx[r] = m;
    float d = 0.f;
#pragma unroll
    for (int j = 0; j < 16; j++) d += __expf((S[j][r] - m) * 0.125f);
#pragma unroll
    for (int oo = 1; oo < 16; oo <<= 1) d += __shfl_xor(d, oo);
    inv[r] = 1.f / d;
  }
  __syncthreads();
  u16* Pb = &Ksh[0][0][0];
  int row0 = w * 16 + g * 4;
#pragma unroll
  for (int j = 0; j < 16; j++) {
    int key = j * 16 + lr;
#pragma unroll
    for (int r = 0; r < 4; r++) {
      float p = __expf((S[j][r] - mx[r]) * 0.125f) * inv[r];
      u16 hh = f2bf(p);
      Pb[(row0 + r) * 264 + key] = hh;
      Pb[16896 + (row0 + r) * 264 + key] = f2bf(p - bf2f(hh));
    }
  }
  __syncthreads();
  f32x4 Oacc[4] = {};
#pragma unroll
  for (int kt = 0; kt < 8; kt++) {
    short8 pah = *(const short8*)&Pb[(w * 16 + lr) * 264 + kt * 32 + kk];
    short8 pal = *(const short8*)&Pb[16896 + (w * 16 + lr) * 264 + kt * 32 + kk];
#pragma unroll
    for (int nf = 0; nf < 4; nf++) {
      short8 vh = *(const short8*)&Vt[0][nf * 16 + lr][kt * 32 + kk];
      short8 vl = *(const short8*)&Vt[1][nf * 16 + lr][kt * 32 + kk];
      Oacc[nf] = __builtin_amdgcn_mfma_f32_16x16x32_bf16(pah, vh, Oacc[nf], 0, 0, 0);
      Oacc[nf] = __builtin_amdgcn_mfma_f32_16x16x32_bf16(pah, vl, Oacc[nf], 0, 0, 0);
      Oacc[nf] = __builtin_amdgcn_mfma_f32_16x16x32_bf16(pal, vh, Oacc[nf], 0, 0, 0);
    }
  }
  float* obase = o + (size_t)(b * SG + qq * 64 + w * 16 + g * 4) * 512 + h * 64;
#pragma unroll
  for (int nf = 0; nf < 4; nf++)
#pragma unroll
    for (int r = 0; r < 4; r++)
      obase[(size_t)r * 512 + nf * 16 + lr] = Oacc[nf][r];
}

__global__ void combine_kernel(const float* __restrict__ loc, const float* __restrict__ gl,
                               const float* __restrict__ ap, int l, float* __restrict__ comb) {
  int idx = blockIdx.x * 256 + threadIdx.x;
  float a = 1.f / (1.f + expf(-ap[l]));
  comb[idx] = a * loc[idx] + (1.f - a) * gl[idx];
}

__global__ __launch_bounds__(512) void head_kernel(
    const float* __restrict__ hfin, const int* __restrict__ cni,
    const float* __restrict__ W1, const float* __restrict__ b1,
    const float* __restrict__ g, const float* __restrict__ bt,
    const float* __restrict__ W2, const float* __restrict__ b2,
    float* __restrict__ out) {
  __shared__ float emb[512];
  __shared__ float z[512];
  __shared__ float sh[8];
  __shared__ float lg[ACT_N];
  int t = threadIdx.x;
  int idx = cni[0];
  emb[t] = hfin[(size_t)idx * 512 + t];
  __syncthreads();
  float s = b1[t];
  for (int k = 0; k < 512; k++) s += emb[k] * W1[(size_t)k * 512 + t];
  float sum = blk_sum(s, sh);
  float mu = sum * (1.f / 512.f);
  float d = s - mu;
  float var = blk_sum(d * d, sh) * (1.f / 512.f);
  z[t] = gelu_f(d * rsqrtf(var + 1e-5f) * g[t] + bt[t]);
  __syncthreads();
  if (t < ACT_N) {
    float l = b2[t];
    for (int k = 0; k < 512; k++) l += z[k] * W2[k * ACT_N + t];
    lg[t] = l;
  }
  __syncthreads();
  if (t == 0) {
    float m2 = lg[0];
    for (int a = 1; a < ACT_N; a++) m2 = fmaxf(m2, lg[a]);
    float den = 0.f;
    float ex[ACT_N];
    for (int a = 0; a < ACT_N; a++) { ex[a] = expf(lg[a] - m2); den += ex[a]; }
    for (int a = 0; a < ACT_N; a++) {
      out[a] = lg[a];
      out[ACT_N + a] = ex[a] / den;
    }
  }
}

extern "C" void kernel_launch(void* const* d_in, const int* in_sizes, int n_in,
                              void* d_out, int out_size, void* d_ws, size_t ws_size,
                              hipStream_t stream) {
  const float* x        = (const float*)d_in[0];
  const float* eattr    = (const float*)d_in[1];
  const float* rwse_W   = (const float*)d_in[2];
  const float* rwse_b   = (const float*)d_in[3];
  const float* rwse_g   = (const float*)d_in[4];
  const float* rwse_bt  = (const float*)d_in[5];
  const float* np_W     = (const float*)d_in[6];
  const float* np_b     = (const float*)d_in[7];
  const float* np_g     = (const float*)d_in[8];
  const float* np_bt    = (const float*)d_in[9];
  const float* gat_Wl   = (const float*)d_in[10];
  const float* gat_bl   = (const float*)d_in[11];
  const float* gat_Wr   = (const float*)d_in[12];
  const float* gat_br   = (const float*)d_in[13];
  const float* gat_We   = (const float*)d_in[14];
  const float* gat_att  = (const float*)d_in[15];
  const float* gat_bias = (const float*)d_in[16];
  const float* n1_g = (const float*)d_in[17];
  const float* n1_b = (const float*)d_in[18];
  const float* mha_inW  = (const float*)d_in[19];
  const float* mha_inb  = (const float*)d_in[20];
  const float* mha_outW = (const float*)d_in[21];
  const float* mha_outb = (const float*)d_in[22];
  const float* alpha_p  = (const float*)d_in[23];
  const float* n2_g = (const float*)d_in[24];
  const float* n2_b = (const float*)d_in[25];
  const float* ffn_W1 = (const float*)d_in[26];
  const float* ffn_b1 = (const float*)d_in[27];
  const float* ffn_W2 = (const float*)d_in[28];
  const float* ffn_b2 = (const float*)d_in[29];
  const float* n3_g = (const float*)d_in[30];
  const float* n3_b = (const float*)d_in[31];
  const float* ah_W1 = (const float*)d_in[32];
  const float* ah_b1 = (const float*)d_in[33];
  const float* ah_g  = (const float*)d_in[34];
  const float* ah_bt = (const float*)d_in[35];
  const float* ah_W2 = (const float*)d_in[36];
  const float* ah_b2 = (const float*)d_in[37];
  const int* edge_index = (const int*)d_in[38];
  const int* cni        = (const int*)d_in[39];
  (void)in_sizes; (void)n_in; (void)out_size; (void)ws_size;

  char* wsp = (char*)d_ws;
  size_t off = 0;
  auto alloc = [&](size_t bytes) -> char* {
    char* p = wsp + off;
    off += (bytes + 255) & ~(size_t)255;
    return p;
  };
  const size_t NNb = (size_t)NODES * NODES * 4;
  char* arena = alloc(3 * NNb);
  float* P2 = (float*)arena;
  float* P3 = (float*)(arena + NNb);
  float* P4 = (float*)(arena + 2 * NNb);
  // after RWSE: part3 of arena hosts qkvb (12.6MB) / ffmid (16.8MB), disjoint lifetimes
  float* qkvb  = (float*)(arena + 2 * NNb);
  float* ffmid = (float*)(arena + 2 * NNb);
  // packed weights: 9,502,720 u16 per plane
  const u64 SEG_NP = 2162688ull;
  const u64 SEG_LAYER = 3670016ull;
  const u64 PTOT = SEG_NP + 2 * SEG_LAYER;
  u16* Bh = (u16*)alloc(PTOT * 2);
  u16* Bl = (u16*)alloc(PTOT * 2);
  float* rwse = (float*)alloc((size_t)NODES * 8 * 4);
  float* rbuf = (float*)alloc((size_t)NODES * H4C * 4);
  float* h0   = (float*)alloc((size_t)NODES * 512 * 4);
  float* h1   = (float*)alloc((size_t)NODES * 512 * 4);
  float* xl   = (float*)alloc((size_t)NODES * 512 * 4);
  float* xr   = (float*)alloc((size_t)NODES * 512 * 4);
  float* gout = (float*)alloc((size_t)NODES * 512 * 4);
  float* attO = (float*)alloc((size_t)NODES * 512 * 4);
  float* gbuf = (float*)alloc((size_t)NODES * 512 * 4);
  float* comb = (float*)alloc((size_t)NODES * 512 * 4);
  u32* bits  = (u32*)alloc((size_t)NODES * 64 * 4);
  int* scnt  = (int*)alloc((size_t)NODES * 4);
  int* slist = (int*)alloc((size_t)NODES * SCAP * 4);
  int* cnt   = (int*)alloc((size_t)NODES * 4);
  int* elist = (int*)alloc((size_t)NODES * ECAP * 4);
  float* easum = (float*)alloc(8);
  float* pbuf  = (float*)alloc((size_t)8 * NODES * 4 * 4);
  float* ffb = xl;

  // ---- RWSE sparse path ----
  hipMemsetAsync(bits, 0, (size_t)NODES * 64 * 4, stream);
  hipMemsetAsync(scnt, 0, NODES * 4, stream);
  build_csr<<<EDGES / 256, 256, 0, stream>>>(edge_index, bits, scnt, slist);
  diag_T<<<NODES / 256, 256, 0, stream>>>(bits, scnt, rwse);
  spmm_sq<<<NODES, 256, 0, stream>>>(scnt, slist, P2);
  diag_copy<<<NODES / 256, 256, 0, stream>>>(P2, rwse, 1);
  spmm_gather<<<NODES, 256, 0, stream>>>(scnt, slist, P2, P3);
  diag_copy<<<NODES / 256, 256, 0, stream>>>(P3, rwse, 2);
  spmm_gather<<<NODES, 256, 0, stream>>>(scnt, slist, P3, P4);
  diag_copy<<<NODES / 256, 256, 0, stream>>>(P4, rwse, 3);
  diag_tiled<<<dim3(NODES / 64, 8), 256, 0, stream>>>(P2, P3, P4, pbuf);
  diag_reduce<<<NODES / 256, 256, 0, stream>>>(pbuf, rwse);
  rwse_proj<<<NODES, 128, 0, stream>>>(rwse, rwse_W, rwse_b, rwse_g, rwse_bt, rbuf);

  // ---- pack all weights (once) ----
  PackArgs pa;
  u64 c = 0;
  int si = 0;
  auto seg = [&](const float* src, int K, int N) {
    pa.src[si] = src; pa.off[si] = c; pa.cum[si] = c; pa.N[si] = N;
    c += (u64)K * N; si++;
  };
  seg(np_W, 4224, 512);
  for (int l = 0; l < LLAY; l++) {
    seg(gat_Wl + (size_t)l * 512 * 512, 512, 512);
    seg(gat_Wr + (size_t)l * 512 * 512, 512, 512);
    seg(mha_inW + (size_t)l * 512 * 1536, 512, 1536);
    seg(mha_outW + (size_t)l * 512 * 512, 512, 512);
    seg(ffn_W1 + (size_t)l * 512 * 2048, 512, 2048);
    seg(ffn_W2 + (size_t)l * 2048 * 512, 2048, 512);
  }
  pa.cum[13] = c;
  pack_all<<<8192, 256, 0, stream>>>(pa, Bh, Bl);

  // ---- node projection: h = gelu(LN([x | rbuf] @ np_W + np_b)) ----
  gemm_af<<<256, 256, 0, stream>>>(x, rbuf, 4096, Bh, Bl, h0, np_b, NODES, 4224, 512, 0);
  ln512<<<NODES, 256, 0, stream>>>(h0, nullptr, np_g, np_bt, h1, 1);

  // ---- GAT CSR + edge-attr mean ----
  hipMemsetAsync(cnt, 0, NODES * 4, stream);
  fill_edges<<<(EDGES + NODES) / 256, 256, 0, stream>>>(edge_index, cnt, elist);
  hipMemsetAsync(easum, 0, 8, stream);
  ea_reduce<<<64, 256, 0, stream>>>(eattr, easum);

  float* hin = h1;
  float* hout = h0;
  for (int l = 0; l < LLAY; l++) {
    u64 lb = SEG_NP + (u64)l * SEG_LAYER;
    u16* BWl = Bh + lb,           *LWl = Bl + lb;
    u16* BWr = Bh + lb + 262144,  *LWr = Bl + lb + 262144;
    u16* Bqkv = Bh + lb + 524288, *Lqkv = Bl + lb + 524288;
    u16* Bout = Bh + lb + 1310720,*Lout = Bl + lb + 1310720;
    u16* BW1 = Bh + lb + 1572864, *LW1 = Bl + lb + 1572864;
    u16* BW2 = Bh + lb + 2621440, *LW2 = Bl + lb + 2621440;

    gemm_af<<<256, 256, 0, stream>>>(hin, hin, 512, BWl, LWl, xl, gat_bl + l * 512,
                                     NODES, 512, 512, 0);
    gemm_af<<<256, 256, 0, stream>>>(hin, hin, 512, BWr, LWr, xr, gat_br + l * 512,
                                     NODES, 512, 512, 0);
    gemm_af<<<768, 256, 0, stream>>>(hin, hin, 512, Bqkv, Lqkv, qkvb, mha_inb + l * 1536,
                                     NODES, 512, 1536, 0);

    gat_kernel<<<NODES, 512, 0, stream>>>(xl, xr, eattr, easum, gat_We + l * 1024,
                                          gat_att + l * 512, gat_bias + l * 512,
                                          cnt, elist, edge_index, gout);
    ln512<<<NODES, 256, 0, stream>>>(gout, nullptr, n1_g + l * 512, n1_b + l * 512, gout, 0);

    mha_mfma<<<BG * NHEAD * 4, 256, 0, stream>>>(qkvb, attO);
    gemm_af<<<256, 256, 0, stream>>>(attO, attO, 512, Bout, Lout, gbuf, mha_outb + l * 512,
                                     NODES, 512, 512, 0);
    ln512<<<NODES, 256, 0, stream>>>(gbuf, nullptr, n2_g + l * 512, n2_b + l * 512, gbuf, 0);

    combine_kernel<<<NODES * 512 / 256, 256, 0, stream>>>(gout, gbuf, alpha_p, l, comb);

    gemm_af<<<1024, 256, 0, stream>>>(comb, comb, 512, BW1, LW1, ffmid, ffn_b1 + l * 2048,
                                      NODES, 512, 2048, 1);
    gemm_af<<<256, 256, 0, stream>>>(ffmid, ffmid, 2048, BW2, LW2, ffb, ffn_b2 + l * 512,
                                     NODES, 2048, 512, 0);
    ln512<<<NODES, 256, 0, stream>>>(ffb, comb, n3_g + l * 512, n3_b + l * 512, hout, 0);
    float* tmp = hin; hin = hout; hout = tmp;
  }

  head_kernel<<<1, 512, 0, stream>>>(hin, cni, ah_W1, ah_b1, ah_g, ah_bt, ah_W2,
                                     ah_b2, (float*)d_out);
}

// Round 6
// 612.663 us; speedup vs baseline: 3.9825x; 1.2317x over previous
//
#include <hip/hip_runtime.h>
#include <math.h>

constexpr int NODES = 2048;
constexpr int BG = 8;
constexpr int SG = 256;
constexpr int DIN = 4096;
constexpr int NHEAD = 8;
constexpr int EDGES = 32768;
constexpr int LLAY = 2;
constexpr int ACT_N = 5;
constexpr int H4C = 128;
constexpr int ECAP = 192;   // per-dst edge list capacity (GAT)
constexpr int SCAP = 96;    // per-src dedup'd neighbor capacity (RWSE)
constexpr int QS = 2560;    // merged hidden stride: [xl 512 | xr 512 | qkv 1536]

typedef unsigned short u16;
typedef unsigned int u32;
typedef unsigned long long u64;
typedef short short8 __attribute__((ext_vector_type(8)));
typedef float f32x4 __attribute__((ext_vector_type(4)));

__device__ __forceinline__ float wave_sum(float v) {
#pragma unroll
  for (int o = 32; o; o >>= 1) v += __shfl_xor(v, o);
  return v;
}
__device__ __forceinline__ float wave_max(float v) {
#pragma unroll
  for (int o = 32; o; o >>= 1) v = fmaxf(v, __shfl_xor(v, o));
  return v;
}
__device__ __forceinline__ float blk_sum(float v, float* sh) {
  v = wave_sum(v);
  int nw = blockDim.x >> 6;
  __syncthreads();
  if ((threadIdx.x & 63) == 0) sh[threadIdx.x >> 6] = v;
  __syncthreads();
  float s = 0.f;
  for (int k = 0; k < nw; k++) s += sh[k];
  return s;
}
__device__ __forceinline__ float gelu_f(float x) {
  return 0.5f * x * (1.f + erff(x * 0.70710678118654752f));
}
__device__ __forceinline__ u16 f2bf(float x) {  // round-to-nearest-even bf16
  u32 u = __float_as_uint(x);
  return (u16)((u + 0x7FFFu + ((u >> 16) & 1u)) >> 16);
}
__device__ __forceinline__ float bf2f(u16 h) { return __uint_as_float(((u32)h) << 16); }

// ================= RWSE (sparse path) =================
__global__ void build_csr(const int* __restrict__ ei, u32* __restrict__ bits,
                          int* __restrict__ scnt, int* __restrict__ slist) {
  int e = blockIdx.x * 256 + threadIdx.x;
  if (e < EDGES) {
    int s = ei[e], d = ei[EDGES + e];
    u32 m = 1u << (d & 31);
    u32 old = atomicOr(&bits[s * 64 + (d >> 5)], m);
    if (!(old & m)) {
      int p = atomicAdd(&scnt[s], 1);
      if (p < SCAP) slist[s * SCAP + p] = d;
    }
  }
}

__global__ void diag_T(const u32* __restrict__ bits, const int* __restrict__ scnt,
                       float* __restrict__ rwse) {
  int i = blockIdx.x * 256 + threadIdx.x;
  if (i < NODES) {
    int deg = min(scnt[i], SCAP);
    int self = (bits[i * 64 + (i >> 5)] >> (i & 31)) & 1;
    rwse[(size_t)i * 8 + 0] = (self && deg > 0) ? 1.f / (float)deg : 0.f;
  }
}

__global__ __launch_bounds__(256) void spmm_sq(const int* __restrict__ scnt,
                                               const int* __restrict__ slist,
                                               float* __restrict__ P2) {
  int i = blockIdx.x, t = threadIdx.x;
  __shared__ float row[NODES];
  for (int c = t; c < NODES; c += 256) row[c] = 0.f;
  __syncthreads();
  int di = min(scnt[i], SCAP);
  float wi = di > 0 ? 1.f / (float)di : 0.f;
  for (int jj = 0; jj < di; jj++) {
    int j = slist[i * SCAP + jj];
    int dj = min(scnt[j], SCAP);
    if (dj == 0) continue;
    float w = wi / (float)dj;
    for (int kk = t; kk < dj; kk += 256) atomicAdd(&row[slist[j * SCAP + kk]], w);
  }
  __syncthreads();
  for (int c = t; c < NODES; c += 256) P2[(size_t)i * NODES + c] = row[c];
}

__global__ __launch_bounds__(256) void spmm_gather(const int* __restrict__ scnt,
                                                   const int* __restrict__ slist,
                                                   const float* __restrict__ P,
                                                   float* __restrict__ Q) {
  int i = blockIdx.x, t = threadIdx.x;
  __shared__ int nb[SCAP];
  int di = min(scnt[i], SCAP);
  for (int c = t; c < di; c += 256) nb[c] = slist[i * SCAP + c];
  __syncthreads();
  float wi = di > 0 ? 1.f / (float)di : 0.f;
  for (int c = t; c < NODES; c += 256) {
    float s = 0.f;
    for (int jj = 0; jj < di; jj++) s += P[(size_t)nb[jj] * NODES + c];
    Q[(size_t)i * NODES + c] = s * wi;
  }
}

__global__ void diag_copy(const float* __restrict__ P, float* __restrict__ rwse, int col) {
  int i = blockIdx.x * 256 + threadIdx.x;
  if (i < NODES) rwse[(size_t)i * 8 + col] = P[(size_t)i * (NODES + 1)];
}

// fused diag dots, tiled+coalesced
__global__ __launch_bounds__(256) void diag_tiled(const float* __restrict__ P2,
                                                  const float* __restrict__ P3,
                                                  const float* __restrict__ P4,
                                                  float* __restrict__ pbuf) {
  __shared__ float r2[64][65], r3[64][65], r4[64][65], c3[64][65], c4[64][65];
  __shared__ float red[4][4][64];
  int t = threadIdx.x;
  int i0 = blockIdx.x * 64;
  int js = blockIdx.y;
  int lo = t & 63, hi = t >> 6;
  float d5 = 0, d6 = 0, d7 = 0, d8 = 0;
  for (int jc = 0; jc < 4; jc++) {
    int j0 = js * 256 + jc * 64;
    __syncthreads();
#pragma unroll
    for (int r = 0; r < 16; r++) {
      int a = hi * 16 + r;
      r2[a][lo] = P2[(size_t)(i0 + a) * NODES + j0 + lo];
      r3[a][lo] = P3[(size_t)(i0 + a) * NODES + j0 + lo];
      r4[a][lo] = P4[(size_t)(i0 + a) * NODES + j0 + lo];
      c3[a][lo] = P3[(size_t)(j0 + a) * NODES + i0 + lo];
      c4[a][lo] = P4[(size_t)(j0 + a) * NODES + i0 + lo];
    }
    __syncthreads();
#pragma unroll
    for (int r = 0; r < 16; r++) {
      int jj = hi * 16 + r;
      float p3c = c3[jj][lo], p4c = c4[jj][lo];
      d5 += r2[lo][jj] * p3c;
      d6 += r3[lo][jj] * p3c;
      d7 += r3[lo][jj] * p4c;
      d8 += r4[lo][jj] * p4c;
    }
  }
  red[0][hi][lo] = d5; red[1][hi][lo] = d6; red[2][hi][lo] = d7; red[3][hi][lo] = d8;
  __syncthreads();
  if (hi == 0) {
    int i = i0 + lo;
#pragma unroll
    for (int v = 0; v < 4; v++) {
      float s = red[v][0][lo] + red[v][1][lo] + red[v][2][lo] + red[v][3][lo];
      pbuf[((size_t)js * NODES + i) * 4 + v] = s;
    }
  }
}

__global__ void diag_reduce(const float* __restrict__ pbuf, float* __restrict__ rwse) {
  int i = blockIdx.x * 256 + threadIdx.x;
  if (i >= NODES) return;
#pragma unroll
  for (int v = 0; v < 4; v++) {
    float s = 0.f;
    for (int js = 0; js < 8; js++) s += pbuf[((size_t)js * NODES + i) * 4 + v];
    rwse[(size_t)i * 8 + 4 + v] = s;
  }
}

// ================= weight packing: frag-tile order, fused-N support ========
// W [K][N] -> u16 idx: off + (((k>>6)*gnTot + ntOff + (n>>6))*8 + ((n>>4)&3)*2
//                      + ((k>>5)&1))*512 ... element (g*16+lr)*8 + e
struct PackArgs {
  const float* src[13];
  u64 off[13];
  u64 cum[14];
  int N[13];
  int gnTot[13];
  int ntOff[13];
};

__global__ __launch_bounds__(256) void pack_all(PackArgs pa, u16* __restrict__ Bh,
                                                u16* __restrict__ Bl) {
  u64 total = pa.cum[13];
  for (u64 idx = (u64)blockIdx.x * 256 + threadIdx.x; idx < total;
       idx += (u64)gridDim.x * 256) {
    int s = 0;
    while (idx >= pa.cum[s + 1]) s++;
    u64 rel = idx - pa.cum[s];
    int N = pa.N[s];
    u32 k = (u32)(rel / (u32)N);
    u32 n = (u32)(rel - (u64)k * N);
    float v = pa.src[s][rel];
    u64 fi = pa.off[s] +
             ((((u64)(k >> 6) * pa.gnTot[s] + pa.ntOff[s] + (n >> 6)) * 8 +
               ((n >> 4) & 3) * 2 + ((k >> 5) & 1)) * 64 +
              ((k >> 3) & 3) * 16 + (n & 15)) * 8 + (k & 7);
    u16 h = f2bf(v);
    Bh[fi] = h;
    Bl[fi] = f2bf(v - bf2f(h));
  }
}

// ================= split-bf16 MFMA GEMM, fp32 A, optional split-K ==========
__device__ __forceinline__ void splitA8(const float* __restrict__ p, short8& h8,
                                        short8& l8) {
  float4 v0 = *(const float4*)p;
  float4 v1 = *(const float4*)(p + 4);
  float v[8] = {v0.x, v0.y, v0.z, v0.w, v1.x, v1.y, v1.z, v1.w};
#pragma unroll
  for (int i = 0; i < 8; i++) {
    u16 h = f2bf(v[i]);
    h8[i] = (short)h;
    l8[i] = (short)f2bf(v[i] - bf2f(h));
  }
}

// A LDS slot XOR-swizzle: read lane (lr,g) and staged (row,g,ks) both map via
// slot = ((r&15) + (g<<4)) ^ (g | (ks<<2))  -> 8 distinct bank groups / phase
__global__ __launch_bounds__(256) void gemm_af(
    const float* __restrict__ A, const float* __restrict__ A2, int Ksplit,
    const u16* __restrict__ Bh, const u16* __restrict__ Bl,
    float* __restrict__ C, const float* __restrict__ bias,
    int M, int K, int N, int act, int Kslice, float* __restrict__ part) {
  __shared__ __align__(16) u16 LA[2][4096];
  __shared__ __align__(16) u16 LB[2][4096];
  int gn = N >> 6;
  int nwg = (M >> 6) * gn;
  int q = nwg >> 3;
  int flat = blockIdx.x;
  int virt = (flat & 7) * q + (flat >> 3);     // bijective XCD-contiguous remap
  int bm = (virt / gn) << 6, bn = (virt % gn) << 6;
  int kb = blockIdx.y;
  int kstart = kb * Kslice;
  int kend = min(K, kstart + Kslice);
  int t = threadIdx.x;
  int lane = t & 63, w = t >> 6;
  int wm = (w >> 1) << 5, wn = (w & 1) << 5;
  int r0 = t >> 3, r1 = r0 + 32;
  int c8 = (t & 7) << 3;
  int ks_s = (t >> 2) & 1, g_s = t & 3;
  int slotA = (((r0 & 15) + (g_s << 4)) ^ (g_s | (ks_s << 2)));
  int da0 = ((((r0 >> 4) << 1) + ks_s) << 9) + (slotA << 3);
  int da1 = ((((r1 >> 4) << 1) + ks_s) << 9) + (slotA << 3);
  int db0 = t * 8, db1 = (t + 256) * 8;
  int A2stride = K - Ksplit;
  size_t btile = ((size_t)(kstart >> 6) * gn + (bn >> 6)) * 4096;
  size_t bstep = (size_t)gn * 4096;

  short8 pah0, pal0, pah1, pal1, pbh0, pbl0, pbh1, pbl1;
  auto loadA = [&](int kt, int r, short8& h, short8& l) {
    int k = kt + c8;
    int row = bm + r;
    const float* p = (k < Ksplit) ? A + (size_t)row * Ksplit + k
                                  : A2 + (size_t)row * A2stride + (k - Ksplit);
    splitA8(p, h, l);
  };
  loadA(kstart, r0, pah0, pal0);
  loadA(kstart, r1, pah1, pal1);
  pbh0 = *(const short8*)(Bh + btile + db0);
  pbl0 = *(const short8*)(Bl + btile + db0);
  pbh1 = *(const short8*)(Bh + btile + db1);
  pbl1 = *(const short8*)(Bl + btile + db1);

  f32x4 acc[2][2] = {};
  int lr = lane & 15, lg = lane >> 4;
  int rboff = lane << 3;

  for (int kt = kstart; kt < kend; kt += 64) {
    __syncthreads();
    *(short8*)&LA[0][da0] = pah0;
    *(short8*)&LA[1][da0] = pal0;
    *(short8*)&LA[0][da1] = pah1;
    *(short8*)&LA[1][da1] = pal1;
    *(short8*)&LB[0][db0] = pbh0;
    *(short8*)&LB[1][db0] = pbl0;
    *(short8*)&LB[0][db1] = pbh1;
    *(short8*)&LB[1][db1] = pbl1;
    __syncthreads();
    if (kt + 64 < kend) {
      btile += bstep;
      loadA(kt + 64, r0, pah0, pal0);
      loadA(kt + 64, r1, pah1, pal1);
      pbh0 = *(const short8*)(Bh + btile + db0);
      pbl0 = *(const short8*)(Bl + btile + db0);
      pbh1 = *(const short8*)(Bh + btile + db1);
      pbl1 = *(const short8*)(Bl + btile + db1);
    }
#pragma unroll
    for (int ks = 0; ks < 2; ks++) {
      short8 ah[2], al[2], bh[2], bl[2];
      int slr = ((lr + (lg << 4)) ^ (lg | (ks << 2))) << 3;
#pragma unroll
      for (int i = 0; i < 2; i++) {
        int ba = ((((wm >> 4) + i) * 2 + ks) << 9) + slr;
        ah[i] = *(const short8*)&LA[0][ba];
        al[i] = *(const short8*)&LA[1][ba];
        int bb = ((((wn >> 4) + i) * 2 + ks) << 9) + rboff;
        bh[i] = *(const short8*)&LB[0][bb];
        bl[i] = *(const short8*)&LB[1][bb];
      }
#pragma unroll
      for (int i = 0; i < 2; i++)
#pragma unroll
        for (int j = 0; j < 2; j++) {
          acc[i][j] = __builtin_amdgcn_mfma_f32_16x16x32_bf16(ah[i], bh[j], acc[i][j], 0, 0, 0);
          acc[i][j] = __builtin_amdgcn_mfma_f32_16x16x32_bf16(ah[i], bl[j], acc[i][j], 0, 0, 0);
          acc[i][j] = __builtin_amdgcn_mfma_f32_16x16x32_bf16(al[i], bh[j], acc[i][j], 0, 0, 0);
        }
    }
  }
  int row0 = (lane >> 4) * 4;
  if (part) {
    size_t pbase = (size_t)kb * (size_t)M * N;
#pragma unroll
    for (int i = 0; i < 2; i++)
#pragma unroll
      for (int j = 0; j < 2; j++) {
        int n = bn + wn + j * 16 + lr;
#pragma unroll
        for (int r = 0; r < 4; r++) {
          int m = bm + wm + i * 16 + row0 + r;
          part[pbase + (size_t)m * N + n] = acc[i][j][r];
        }
      }
    return;
  }
#pragma unroll
  for (int i = 0; i < 2; i++)
#pragma unroll
    for (int j = 0; j < 2; j++) {
      int n = bn + wn + j * 16 + lr;
      float bv = bias ? bias[n] : 0.f;
#pragma unroll
      for (int r = 0; r < 4; r++) {
        int m = bm + wm + i * 16 + row0 + r;
        float v = acc[i][j][r] + bv;
        if (act) v = gelu_f(v);
        C[(size_t)m * N + n] = v;
      }
    }
}

// ================= small fused kernels =================
__global__ __launch_bounds__(128) void rwse_proj(const float* __restrict__ rwse,
                                                 const float* __restrict__ W,
                                                 const float* __restrict__ bb,
                                                 const float* __restrict__ g,
                                                 const float* __restrict__ bt,
                                                 float* __restrict__ r) {
  int i = blockIdx.x, j = threadIdx.x;
  float s = bb[j];
#pragma unroll
  for (int k = 0; k < 8; k++) s += rwse[(size_t)i * 8 + k] * W[k * H4C + j];
  __shared__ float sh[8];
  float sum = blk_sum(s, sh);
  float mu = sum * (1.f / 128.f);
  float d = s - mu;
  float var = blk_sum(d * d, sh) * (1.f / 128.f);
  r[(size_t)i * H4C + j] = gelu_f(d * rsqrtf(var + 1e-5f) * g[j] + bt[j]);
}

// ln512 v2: reduce SK fp32 partials (+gemm bias) (+residual) -> LN -> (gelu)
// -> optional mix: y = a*mix + (1-a)*LNout, a = sigmoid(ap[l])
__global__ __launch_bounds__(256) void ln512(const float* __restrict__ x, int sk,
                                             const float* __restrict__ gbias,
                                             const float* __restrict__ res,
                                             const float* __restrict__ mix,
                                             const float* __restrict__ ap, int l,
                                             const float* __restrict__ g,
                                             const float* __restrict__ b,
                                             float* __restrict__ y, int do_gelu) {
  const size_t MN = (size_t)NODES * 512;
  int i = blockIdx.x, t = threadIdx.x;
  size_t base = (size_t)i * 512;
  float v0 = x[base + t], v1 = x[base + 256 + t];
  for (int s = 1; s < sk; s++) {
    v0 += x[(size_t)s * MN + base + t];
    v1 += x[(size_t)s * MN + base + 256 + t];
  }
  if (gbias) { v0 += gbias[t]; v1 += gbias[t + 256]; }
  if (res) { v0 += res[base + t]; v1 += res[base + 256 + t]; }
  __shared__ float sh[8];
  float s = blk_sum(v0 + v1, sh);
  float mu = s * (1.f / 512.f);
  float d0 = v0 - mu, d1 = v1 - mu;
  float var = blk_sum(d0 * d0 + d1 * d1, sh) * (1.f / 512.f);
  float rstd = rsqrtf(var + 1e-5f);
  float o0 = d0 * rstd * g[t] + b[t];
  float o1 = d1 * rstd * g[t + 256] + b[t + 256];
  if (do_gelu) { o0 = gelu_f(o0); o1 = gelu_f(o1); }
  if (mix) {
    float a = 1.f / (1.f + expf(-ap[l]));
    o0 = a * mix[base + t] + (1.f - a) * o0;
    o1 = a * mix[base + 256 + t] + (1.f - a) * o1;
  }
  y[base + t] = o0;
  y[base + 256 + t] = o1;
}

__global__ void build_cbias(const float* __restrict__ bl, const float* __restrict__ br,
                            const float* __restrict__ inb, float* __restrict__ cb) {
  int i = blockIdx.x * 256 + threadIdx.x;
  if (i >= QS) return;
  cb[i] = i < 512 ? bl[i] : (i < 1024 ? br[i - 512] : inb[i - 1024]);
}

__global__ void fill_edges(const int* __restrict__ ei, int* __restrict__ cnt,
                           int* __restrict__ elist) {
  int e = blockIdx.x * 256 + threadIdx.x;
  if (e < EDGES + NODES) {
    int d = e < EDGES ? ei[EDGES + e] : e - EDGES;
    int p = atomicAdd(&cnt[d], 1);
    if (p < ECAP) elist[(size_t)d * ECAP + p] = e;
  }
}

__global__ void ea_reduce(const float* __restrict__ ea, float* __restrict__ sums) {
  int tid = blockIdx.x * blockDim.x + threadIdx.x;
  int stride = gridDim.x * blockDim.x;
  float s0 = 0.f, s1 = 0.f;
  for (int e = tid; e < EDGES; e += stride) { s0 += ea[2 * e]; s1 += ea[2 * e + 1]; }
  s0 = wave_sum(s0);
  s1 = wave_sum(s1);
  if ((threadIdx.x & 63) == 0) { atomicAdd(&sums[0], s0); atomicAdd(&sums[1], s1); }
}

// xl/xr live in the merged hidden buffer at stride QS
__global__ __launch_bounds__(512) void gat_kernel(
    const float* __restrict__ hb,
    const float* __restrict__ eattr, const float* __restrict__ easum,
    const float* __restrict__ We, const float* __restrict__ att,
    const float* __restrict__ bias, const int* __restrict__ cnt,
    const int* __restrict__ elist, const int* __restrict__ ei,
    float* __restrict__ out) {
  int i = blockIdx.x;
  int tid = threadIdx.x;
  int h = tid >> 6, c = tid & 63;
  int m_cnt = cnt[i];
  if (m_cnt > ECAP) m_cnt = ECAP;
  const float inv_e = 1.f / (float)EDGES;
  float we0 = We[tid], we1 = We[512 + tid];
  float attv = att[tid];
  float xrv = hb[(size_t)i * QS + 512 + tid];
  float ea_m0 = easum[0] * inv_e, ea_m1 = easum[1] * inv_e;
  __shared__ float logits[NHEAD][ECAP];
  const int* el = elist + (size_t)i * ECAP;
  for (int e = 0; e < m_cnt; e++) {
    int eid = el[e];
    int s;
    float a0, a1;
    if (eid < EDGES) { s = ei[eid]; a0 = eattr[2 * eid]; a1 = eattr[2 * eid + 1]; }
    else { s = i; a0 = ea_m0; a1 = ea_m1; }
    float mval = hb[(size_t)s * QS + tid] + xrv + a0 * we0 + a1 * we1;
    mval = mval > 0.f ? mval : 0.2f * mval;
    float lg = wave_sum(mval * attv);
    if (c == 0) logits[h][e] = lg;
  }
  float mx = -1e30f;
  for (int e = c; e < m_cnt; e += 64) mx = fmaxf(mx, logits[h][e]);
  mx = wave_max(mx);
  float den = 0.f;
  for (int e = c; e < m_cnt; e += 64) den += expf(logits[h][e] - mx);
  den = wave_sum(den) + 1e-16f;
  float acc = 0.f;
  for (int e = 0; e < m_cnt; e++) {
    int eid = el[e];
    int s = eid < EDGES ? ei[eid] : i;
    float alpha = expf(logits[h][e] - mx) / den;
    acc += alpha * hb[(size_t)s * QS + tid];
  }
  out[(size_t)i * 512 + tid] = acc + bias[tid];
}

// ======= MFMA block-diag MHA; qkv = merged buffer + 1024, stride QS =======
__global__ __launch_bounds__(256) void mha_mfma(const float* __restrict__ qkv,
                                                float* __restrict__ o) {
  __shared__ __align__(16) u16 Ksh[2][256][72];
  __shared__ __align__(16) u16 Vt[2][64][264];
  int bid = blockIdx.x;
  int qq = bid & 3;
  int h = (bid >> 2) & 7;
  int b = bid >> 5;
  int t = threadIdx.x;
  int lane = t & 63, w = t >> 6;
  int lr = lane & 15, g = lane >> 4, kk = g * 8;
  size_t rowbase = (size_t)(b * SG) * QS;
  const float* Kbase = qkv + rowbase + 512 + h * 64;
  const float* Vbase = qkv + rowbase + 1024 + h * 64;
  for (int idx = t; idx < SG * 64; idx += 256) {
    int j = idx >> 6, c = idx & 63;
    float kv = Kbase[(size_t)j * QS + c];
    u16 khh = f2bf(kv);
    Ksh[0][j][c] = khh;
    Ksh[1][j][c] = f2bf(kv - bf2f(khh));
    float vv = Vbase[(size_t)j * QS + c];
    u16 vhh = f2bf(vv);
    Vt[0][c][j] = vhh;
    Vt[1][c][j] = f2bf(vv - bf2f(vhh));
  }
  const float* Qrow = qkv + rowbase + (size_t)(qq * 64 + w * 16 + lr) * QS + h * 64;
  short8 qh[2], ql[2];
#pragma unroll
  for (int kt = 0; kt < 2; kt++) {
    float qv[8];
    *(float4*)&qv[0] = *(const float4*)&Qrow[kt * 32 + kk];
    *(float4*)&qv[4] = *(const float4*)&Qrow[kt * 32 + kk + 4];
#pragma unroll
    for (int i = 0; i < 8; i++) {
      u16 hh = f2bf(qv[i]);
      qh[kt][i] = hh;
      ql[kt][i] = f2bf(qv[i] - bf2f(hh));
    }
  }
  __syncthreads();
  f32x4 S[16];
#pragma unroll
  for (int j = 0; j < 16; j++) {
    f32x4 acc = {};
#pragma unroll
    for (int kt = 0; kt < 2; kt++) {
      short8 bh = *(const short8*)&Ksh[0][j * 16 + lr][kt * 32 + kk];
      short8 bl = *(const short8*)&Ksh[1][j * 16 + lr][kt * 32 + kk];
      acc = __builtin_amdgcn_mfma_f32_16x16x32_bf16(qh[kt], bh, acc, 0, 0, 0);
      acc = __builtin_amdgcn_mfma_f32_16x16x32_bf16(qh[kt], bl, acc, 0, 0, 0);
      acc = __builtin_amdgcn_mfma_f32_16x16x32_bf16(ql[kt], bh, acc, 0, 0, 0);
    }
    S[j] = acc;
  }
  float mx[4], inv[4];
#pragma unroll
  for (int r = 0; r < 4; r++) {
    float m = S[0][r];
#pragma unroll
    for (int j = 1; j < 16; j++) m = fmaxf(m, S[j][r]);
#pragma unroll
    for (int oo = 1; oo < 16; oo <<= 1) m = fmaxf(m, __shfl_xor(m, oo));
    mx[r] = m;
    float d = 0.f;
#pragma unroll
    for (int j = 0; j < 16; j++) d += __expf((S[j][r] - m) * 0.125f);
#pragma unroll
    for (int oo = 1; oo < 16; oo <<= 1) d += __shfl_xor(d, oo);
    inv[r] = 1.f / d;
  }
  __syncthreads();
  u16* Pb = &Ksh[0][0][0];
  int row0 = w * 16 + g * 4;
#pragma unroll
  for (int j = 0; j < 16; j++) {
    int key = j * 16 + lr;
#pragma unroll
    for (int r = 0; r < 4; r++) {
      float p = __expf((S[j][r] - mx[r]) * 0.125f) * inv[r];
      u16 hh = f2bf(p);
      Pb[(row0 + r) * 264 + key] = hh;
      Pb[16896 + (row0 + r) * 264 + key] = f2bf(p - bf2f(hh));
    }
  }
  __syncthreads();
  f32x4 Oacc[4] = {};
#pragma unroll
  for (int kt = 0; kt < 8; kt++) {
    short8 pah = *(const short8*)&Pb[(w * 16 + lr) * 264 + kt * 32 + kk];
    short8 pal = *(const short8*)&Pb[16896 + (w * 16 + lr) * 264 + kt * 32 + kk];
#pragma unroll
    for (int nf = 0; nf < 4; nf++) {
      short8 vh = *(const short8*)&Vt[0][nf * 16 + lr][kt * 32 + kk];
      short8 vl = *(const short8*)&Vt[1][nf * 16 + lr][kt * 32 + kk];
      Oacc[nf] = __builtin_amdgcn_mfma_f32_16x16x32_bf16(pah, vh, Oacc[nf], 0, 0, 0);
      Oacc[nf] = __builtin_amdgcn_mfma_f32_16x16x32_bf16(pah, vl, Oacc[nf], 0, 0, 0);
      Oacc[nf] = __builtin_amdgcn_mfma_f32_16x16x32_bf16(pal, vh, Oacc[nf], 0, 0, 0);
    }
  }
  float* obase = o + (size_t)(b * SG + qq * 64 + w * 16 + g * 4) * 512 + h * 64;
#pragma unroll
  for (int nf = 0; nf < 4; nf++)
#pragma unroll
    for (int r = 0; r < 4; r++)
      obase[(size_t)r * 512 + nf * 16 + lr] = Oacc[nf][r];
}

__global__ __launch_bounds__(512) void head_kernel(
    const float* __restrict__ hfin, const int* __restrict__ cni,
    const float* __restrict__ W1, const float* __restrict__ b1,
    const float* __restrict__ g, const float* __restrict__ bt,
    const float* __restrict__ W2, const float* __restrict__ b2,
    float* __restrict__ out) {
  __shared__ float emb[512];
  __shared__ float z[512];
  __shared__ float sh[8];
  __shared__ float lg[ACT_N];
  int t = threadIdx.x;
  int idx = cni[0];
  emb[t] = hfin[(size_t)idx * 512 + t];
  __syncthreads();
  float s = b1[t];
  for (int k = 0; k < 512; k++) s += emb[k] * W1[(size_t)k * 512 + t];
  float sum = blk_sum(s, sh);
  float mu = sum * (1.f / 512.f);
  float d = s - mu;
  float var = blk_sum(d * d, sh) * (1.f / 512.f);
  z[t] = gelu_f(d * rsqrtf(var + 1e-5f) * g[t] + bt[t]);
  __syncthreads();
  if (t < ACT_N) {
    float l = b2[t];
    for (int k = 0; k < 512; k++) l += z[k] * W2[k * ACT_N + t];
    lg[t] = l;
  }
  __syncthreads();
  if (t == 0) {
    float m2 = lg[0];
    for (int a = 1; a < ACT_N; a++) m2 = fmaxf(m2, lg[a]);
    float den = 0.f;
    float ex[ACT_N];
    for (int a = 0; a < ACT_N; a++) { ex[a] = expf(lg[a] - m2); den += ex[a]; }
    for (int a = 0; a < ACT_N; a++) {
      out[a] = lg[a];
      out[ACT_N + a] = ex[a] / den;
    }
  }
}

extern "C" void kernel_launch(void* const* d_in, const int* in_sizes, int n_in,
                              void* d_out, int out_size, void* d_ws, size_t ws_size,
                              hipStream_t stream) {
  const float* x        = (const float*)d_in[0];
  const float* eattr    = (const float*)d_in[1];
  const float* rwse_W   = (const float*)d_in[2];
  const float* rwse_b   = (const float*)d_in[3];
  const float* rwse_g   = (const float*)d_in[4];
  const float* rwse_bt  = (const float*)d_in[5];
  const float* np_W     = (const float*)d_in[6];
  const float* np_b     = (const float*)d_in[7];
  const float* np_g     = (const float*)d_in[8];
  const float* np_bt    = (const float*)d_in[9];
  const float* gat_Wl   = (const float*)d_in[10];
  const float* gat_bl   = (const float*)d_in[11];
  const float* gat_Wr   = (const float*)d_in[12];
  const float* gat_br   = (const float*)d_in[13];
  const float* gat_We   = (const float*)d_in[14];
  const float* gat_att  = (const float*)d_in[15];
  const float* gat_bias = (const float*)d_in[16];
  const float* n1_g = (const float*)d_in[17];
  const float* n1_b = (const float*)d_in[18];
  const float* mha_inW  = (const float*)d_in[19];
  const float* mha_inb  = (const float*)d_in[20];
  const float* mha_outW = (const float*)d_in[21];
  const float* mha_outb = (const float*)d_in[22];
  const float* alpha_p  = (const float*)d_in[23];
  const float* n2_g = (const float*)d_in[24];
  const float* n2_b = (const float*)d_in[25];
  const float* ffn_W1 = (const float*)d_in[26];
  const float* ffn_b1 = (const float*)d_in[27];
  const float* ffn_W2 = (const float*)d_in[28];
  const float* ffn_b2 = (const float*)d_in[29];
  const float* n3_g = (const float*)d_in[30];
  const float* n3_b = (const float*)d_in[31];
  const float* ah_W1 = (const float*)d_in[32];
  const float* ah_b1 = (const float*)d_in[33];
  const float* ah_g  = (const float*)d_in[34];
  const float* ah_bt = (const float*)d_in[35];
  const float* ah_W2 = (const float*)d_in[36];
  const float* ah_b2 = (const float*)d_in[37];
  const int* edge_index = (const int*)d_in[38];
  const int* cni        = (const int*)d_in[39];
  (void)in_sizes; (void)n_in; (void)out_size; (void)ws_size;

  char* wsp = (char*)d_ws;
  size_t off = 0;
  auto alloc = [&](size_t bytes) -> char* {
    char* p = wsp + off;
    off += (bytes + 255) & ~(size_t)255;
    return p;
  };
  const size_t NNb = (size_t)NODES * NODES * 4;
  char* arena = alloc(3 * NNb);
  float* P2 = (float*)arena;
  float* P3 = (float*)(arena + NNb);
  float* P4 = (float*)(arena + 2 * NNb);
  // post-RWSE arena reuse (disjoint lifetimes):
  //   part/hbig @ arena+0  (np partials 16.8MB -> hbig 21MB -> outproj/W2 partials)
  //   ffmid     @ arena+21MB (16.8MB)
  float* part  = (float*)arena;
  float* hbig  = (float*)arena;
  float* ffmid = (float*)(arena + 20971520);
  const u64 SEG_NP = 2162688ull;
  const u64 SEG_LAYER = 3670016ull;
  const u64 PTOT = SEG_NP + 2 * SEG_LAYER;
  u16* Bh = (u16*)alloc(PTOT * 2);
  u16* Bl = (u16*)alloc(PTOT * 2);
  float* rwse = (float*)alloc((size_t)NODES * 8 * 4);
  float* rbuf = (float*)alloc((size_t)NODES * H4C * 4);
  float* h0   = (float*)alloc((size_t)NODES * 512 * 4);
  float* h1   = (float*)alloc((size_t)NODES * 512 * 4);
  float* gout = (float*)alloc((size_t)NODES * 512 * 4);
  float* attO = (float*)alloc((size_t)NODES * 512 * 4);
  float* comb = (float*)alloc((size_t)NODES * 512 * 4);
  float* cb   = (float*)alloc((size_t)LLAY * QS * 4);
  u32* bits  = (u32*)alloc((size_t)NODES * 64 * 4);
  int* scnt  = (int*)alloc((size_t)NODES * 4);
  int* slist = (int*)alloc((size_t)NODES * SCAP * 4);
  int* cnt   = (int*)alloc((size_t)NODES * 4);
  int* elist = (int*)alloc((size_t)NODES * ECAP * 4);
  float* easum = (float*)alloc(8);
  float* pbuf  = (float*)alloc((size_t)8 * NODES * 4 * 4);

  // ---- RWSE sparse path ----
  hipMemsetAsync(bits, 0, (size_t)NODES * 64 * 4, stream);
  hipMemsetAsync(scnt, 0, NODES * 4, stream);
  build_csr<<<EDGES / 256, 256, 0, stream>>>(edge_index, bits, scnt, slist);
  diag_T<<<NODES / 256, 256, 0, stream>>>(bits, scnt, rwse);
  spmm_sq<<<NODES, 256, 0, stream>>>(scnt, slist, P2);
  diag_copy<<<NODES / 256, 256, 0, stream>>>(P2, rwse, 1);
  spmm_gather<<<NODES, 256, 0, stream>>>(scnt, slist, P2, P3);
  diag_copy<<<NODES / 256, 256, 0, stream>>>(P3, rwse, 2);
  spmm_gather<<<NODES, 256, 0, stream>>>(scnt, slist, P3, P4);
  diag_copy<<<NODES / 256, 256, 0, stream>>>(P4, rwse, 3);
  diag_tiled<<<dim3(NODES / 64, 8), 256, 0, stream>>>(P2, P3, P4, pbuf);
  diag_reduce<<<NODES / 256, 256, 0, stream>>>(pbuf, rwse);
  rwse_proj<<<NODES, 128, 0, stream>>>(rwse, rwse_W, rwse_b, rwse_g, rwse_bt, rbuf);

  // ---- pack all weights (once); merged hin layout [Wl|Wr|inW] gnTot=40 ----
  PackArgs pa;
  u64 c = 0;
  int si = 0;
  auto seg = [&](const float* src, int K, int N, u64 offset, int gnTot, int ntOff) {
    pa.src[si] = src; pa.off[si] = offset; pa.cum[si] = c; pa.N[si] = N;
    pa.gnTot[si] = gnTot; pa.ntOff[si] = ntOff;
    c += (u64)K * N; si++;
  };
  seg(np_W, 4224, 512, 0, 8, 0);
  for (int l = 0; l < LLAY; l++) {
    u64 lb = SEG_NP + (u64)l * SEG_LAYER;
    seg(gat_Wl + (size_t)l * 512 * 512, 512, 512, lb, 40, 0);
    seg(gat_Wr + (size_t)l * 512 * 512, 512, 512, lb, 40, 8);
    seg(mha_inW + (size_t)l * 512 * 1536, 512, 1536, lb, 40, 16);
    seg(mha_outW + (size_t)l * 512 * 512, 512, 512, lb + 1310720, 8, 0);
    seg(ffn_W1 + (size_t)l * 512 * 2048, 512, 2048, lb + 1572864, 32, 0);
    seg(ffn_W2 + (size_t)l * 2048 * 512, 2048, 512, lb + 2621440, 8, 0);
  }
  pa.cum[13] = c;
  pack_all<<<8192, 256, 0, stream>>>(pa, Bh, Bl);
  build_cbias<<<(QS + 255) / 256, 256, 0, stream>>>(gat_bl, gat_br, mha_inb, cb);
  build_cbias<<<(QS + 255) / 256, 256, 0, stream>>>(gat_bl + 512, gat_br + 512,
                                                    mha_inb + 1536, cb + QS);

  // ---- np projection: split-K4 partials -> fused reduce+bias+LN+gelu ----
  gemm_af<<<dim3(256, 4), 256, 0, stream>>>(x, rbuf, 4096, Bh, Bl, nullptr, nullptr,
                                            NODES, 4224, 512, 0, 1088, part);
  ln512<<<NODES, 256, 0, stream>>>(part, 4, np_b, nullptr, nullptr, nullptr, 0,
                                   np_g, np_bt, h1, 1);

  // ---- GAT CSR + edge-attr mean ----
  hipMemsetAsync(cnt, 0, NODES * 4, stream);
  fill_edges<<<(EDGES + NODES) / 256, 256, 0, stream>>>(edge_index, cnt, elist);
  hipMemsetAsync(easum, 0, 8, stream);
  ea_reduce<<<64, 256, 0, stream>>>(eattr, easum);

  float* hin = h1;
  float* hout = h0;
  for (int l = 0; l < LLAY; l++) {
    u64 lb = SEG_NP + (u64)l * SEG_LAYER;
    // merged [Wl|Wr|QKV]: hbig[2048][2560]
    gemm_af<<<dim3(1280), 256, 0, stream>>>(hin, hin, 512, Bh + lb, Bl + lb, hbig,
                                            cb + (size_t)l * QS, NODES, 512, QS, 0,
                                            512, nullptr);
    gat_kernel<<<NODES, 512, 0, stream>>>(hbig, eattr, easum, gat_We + l * 1024,
                                          gat_att + l * 512, gat_bias + l * 512,
                                          cnt, elist, edge_index, gout);
    ln512<<<NODES, 256, 0, stream>>>(gout, 1, nullptr, nullptr, nullptr, nullptr, 0,
                                     n1_g + l * 512, n1_b + l * 512, gout, 0);
    mha_mfma<<<BG * NHEAD * 4, 256, 0, stream>>>(hbig + 1024, attO);
    // out-proj split-K2 (partials overwrite hbig; gat+mha already consumed it)
    gemm_af<<<dim3(256, 2), 256, 0, stream>>>(attO, attO, 512, Bh + lb + 1310720,
                                              Bl + lb + 1310720, nullptr, nullptr,
                                              NODES, 512, 512, 0, 256, part);
    // fused: reduce + bias + LN(n2) + combine(mix=gout) -> comb
    ln512<<<NODES, 256, 0, stream>>>(part, 2, mha_outb + l * 512, nullptr, gout,
                                     alpha_p, l, n2_g + l * 512, n2_b + l * 512,
                                     comb, 0);
    // FFN
    gemm_af<<<dim3(1024), 256, 0, stream>>>(comb, comb, 512, Bh + lb + 1572864,
                                            Bl + lb + 1572864, ffmid,
                                            ffn_b1 + l * 2048, NODES, 512, 2048, 1,
                                            512, nullptr);
    gemm_af<<<dim3(256, 4), 256, 0, stream>>>(ffmid, ffmid, 2048, Bh + lb + 2621440,
                                              Bl + lb + 2621440, nullptr, nullptr,
                                              NODES, 2048, 512, 0, 512, part);
    // fused: reduce + bias + residual(comb) + LN(n3) -> hout
    ln512<<<NODES, 256, 0, stream>>>(part, 4, ffn_b2 + l * 512, comb, nullptr,
                                     nullptr, 0, n3_g + l * 512, n3_b + l * 512,
                                     hout, 0);
    float* tmp = hin; hin = hout; hout = tmp;
  }

  head_kernel<<<1, 512, 0, stream>>>(hin, cni, ah_W1, ah_b1, ah_g, ah_bt, ah_W2,
                                     ah_b2, (float*)d_out);
}